// Round 2
// baseline (2551.352 us; speedup 1.0000x reference)
//
#include <hip/hip_runtime.h>
#include <float.h>

#define BATCH 16
#define NPTS  2048
#define NS0   256
#define NS1   128
#define KK    32
#define EPSV  1e-5f

// exact numpy-order squared distance: ((dx*dx + dy*dy) + dz*dz), no FMA contraction
__device__ __forceinline__ float sqdist(float ax,float ay,float az,float bx,float by,float bz){
  float dx=__fsub_rn(ax,bx), dy=__fsub_rn(ay,by), dz=__fsub_rn(az,bz);
  return __fadd_rn(__fadd_rn(__fmul_rn(dx,dx),__fmul_rn(dy,dy)),__fmul_rn(dz,dz));
}

// ---- embed layer 1: transpose x [B,3,N] -> coords [B,N,3], t1 = coords @ w1^T  ([B,N,64])
__global__ void k_embed1(const float* __restrict__ x, const float* __restrict__ w1,
                         float* __restrict__ coords, float* __restrict__ t1){
  __shared__ float w[64*3];
  int tid = threadIdx.x;
  if (tid < 192) w[tid] = w1[tid];
  __syncthreads();
  int gid = blockIdx.x*blockDim.x + tid;
  if (gid >= BATCH*NPTS) return;
  int b = gid / NPTS, n = gid % NPTS;
  float cx = x[(b*3+0)*NPTS + n];
  float cy = x[(b*3+1)*NPTS + n];
  float cz = x[(b*3+2)*NPTS + n];
  coords[gid*3+0]=cx; coords[gid*3+1]=cy; coords[gid*3+2]=cz;
  float* o = t1 + (size_t)gid*64;
  #pragma unroll
  for(int j=0;j<64;j++) o[j] = cx*w[j*3+0] + cy*w[j*3+1] + cz*w[j*3+2];
}

// ---- per-channel mean/rstd over M rows of [M][C]
__global__ void k_stats(const float* __restrict__ t, int M, int C,
                        float* __restrict__ mean, float* __restrict__ rstd){
  int c = blockIdx.x, tid = threadIdx.x;
  float s=0.f, s2=0.f;
  for(int r=tid; r<M; r+=blockDim.x){ float v = t[(size_t)r*C+c]; s+=v; s2+=v*v; }
  __shared__ float bs[256], bq[256];
  bs[tid]=s; bq[tid]=s2; __syncthreads();
  for(int st=128; st>0; st>>=1){ if(tid<st){ bs[tid]+=bs[tid+st]; bq[tid]+=bq[tid+st]; } __syncthreads(); }
  if(tid==0){
    float m = bs[0]/M;
    float v = bq[0]/M - m*m; if(v<0.f) v=0.f;
    mean[c]=m; rstd[c]=rsqrtf(v+EPSV);
  }
}

// ---- embed layer 2: t2 = relu(bn(t1)) @ w2^T  (64x64), 64 points per block
__global__ void k_embed2(const float* __restrict__ t1, const float* __restrict__ w2,
                         const float* __restrict__ mean1, const float* __restrict__ rstd1,
                         const float* __restrict__ g1, const float* __restrict__ b1,
                         float* __restrict__ t2){
  __shared__ __align__(16) float fin[64][64];
  __shared__ float sm[64], sr[64], sg[64], sb[64];
  int tid = threadIdx.x;
  if (tid<64){ sm[tid]=mean1[tid]; sr[tid]=rstd1[tid]; sg[tid]=g1[tid]; sb[tid]=b1[tid]; }
  __syncthreads();
  int base = blockIdx.x*64;
  for(int i=tid;i<4096;i+=256){
    int p=i>>6, c=i&63;
    float v = t1[(size_t)(base+p)*64 + c];
    v = (v - sm[c])*sr[c]*sg[c] + sb[c];
    fin[p][c] = v>0.f ? v : 0.f;
  }
  __syncthreads();
  int o = tid & 63, p0 = tid>>6;
  float acc[16];
  #pragma unroll
  for(int i=0;i<16;i++) acc[i]=0.f;
  for(int cc=0; cc<64; cc+=4){
    float4 wv = *(const float4*)(w2 + o*64 + cc);     // global, L1-cached
    #pragma unroll
    for(int i=0;i<16;i++){
      float4 f4 = *(const float4*)&fin[p0 + i*4][cc]; // broadcast read
      acc[i] += f4.x*wv.x + f4.y*wv.y + f4.z*wv.z + f4.w*wv.w;
    }
  }
  #pragma unroll
  for(int i=0;i<16;i++) t2[(size_t)(base+p0+i*4)*64 + o] = acc[i];
}

// ---- elementwise bn+relu in place
__global__ void k_bnrelu(float* __restrict__ t, int total, int C,
                         const float* __restrict__ mean, const float* __restrict__ rstd,
                         const float* __restrict__ g, const float* __restrict__ b){
  int i = blockIdx.x*blockDim.x + threadIdx.x;
  if(i>=total) return;
  int c = i % C;
  float v = t[i];
  v = (v-mean[c])*rstd[c]*g[c] + b[c];
  t[i] = v>0.f ? v : 0.f;
}

// ---- farthest point sampling, one block per batch. Emits idx + gathered coords.
template<int P, int S, int T>
__global__ void k_fps(const float* __restrict__ pts, int* __restrict__ outIdx,
                      float* __restrict__ outXyz){
  constexpr int PPT = P/T;
  int b = blockIdx.x, tid = threadIdx.x;
  const float* p = pts + (size_t)b*P*3;
  float px[PPT], py[PPT], pz[PPT], dist[PPT];
  #pragma unroll
  for(int i=0;i<PPT;i++){
    int n = tid*PPT + i;
    px[i]=p[n*3]; py[i]=p[n*3+1]; pz[i]=p[n*3+2];
    dist[i]=1e10f;
  }
  __shared__ float rv[T/64];
  __shared__ int   ri[T/64];
  __shared__ int   curs;
  int cur = 0;
  for(int s=0;s<S;s++){
    if(tid==0){
      outIdx[b*S+s]=cur;
      outXyz[((size_t)b*S+s)*3+0]=p[cur*3+0];
      outXyz[((size_t)b*S+s)*3+1]=p[cur*3+1];
      outXyz[((size_t)b*S+s)*3+2]=p[cur*3+2];
    }
    if(s==S-1) break;
    float cx=p[cur*3], cy=p[cur*3+1], cz=p[cur*3+2];
    float bv=-FLT_MAX; int bi=0;
    #pragma unroll
    for(int i=0;i<PPT;i++){
      float d = sqdist(px[i],py[i],pz[i],cx,cy,cz);
      float nd = fminf(dist[i], d);
      dist[i]=nd;
      if(nd>bv){ bv=nd; bi=tid*PPT+i; }   // ascending n => strict '>' keeps lowest idx on tie
    }
    #pragma unroll
    for(int off=32; off>0; off>>=1){
      float ov=__shfl_down(bv,off);
      int   oi=__shfl_down(bi,off);
      if(ov>bv || (ov==bv && oi<bi)){ bv=ov; bi=oi; }
    }
    if((tid&63)==0){ rv[tid>>6]=bv; ri[tid>>6]=bi; }
    __syncthreads();
    if(tid==0){
      float xv=rv[0]; int xi=ri[0];
      for(int w=1;w<T/64;w++) if(rv[w]>xv || (rv[w]==xv && ri[w]<xi)){ xv=rv[w]; xi=ri[w]; }
      curs=xi;
    }
    __syncthreads();
    cur=curs;
  }
}

// ---- exact 32-NN per query via iterative argmin; tie -> lowest index (matches stable top_k set)
template<int P, int T>
__global__ void k_knn(const float* __restrict__ pts, const float* __restrict__ q,
                      int S, int* __restrict__ knn){
  int bq = blockIdx.x, tid = threadIdx.x;
  int b = bq / S;
  __shared__ float d2[P];
  __shared__ float rv[T/64];
  __shared__ int   ri[T/64];
  __shared__ int   sel;
  const float* p = pts + (size_t)b*P*3;
  float qx=q[(size_t)bq*3], qy=q[(size_t)bq*3+1], qz=q[(size_t)bq*3+2];
  for(int n=tid;n<P;n+=T) d2[n] = sqdist(qx,qy,qz,p[n*3],p[n*3+1],p[n*3+2]);
  __syncthreads();
  for(int j=0;j<KK;j++){
    float bv=FLT_MAX; int bi=P;
    for(int n=tid;n<P;n+=T){ float v=d2[n]; if(v<bv){ bv=v; bi=n; } }
    #pragma unroll
    for(int off=32; off>0; off>>=1){
      float ov=__shfl_down(bv,off);
      int   oi=__shfl_down(bi,off);
      if(ov<bv || (ov==bv && oi<bi)){ bv=ov; bi=oi; }
    }
    if((tid&63)==0){ rv[tid>>6]=bv; ri[tid>>6]=bi; }
    __syncthreads();
    if(tid==0){
      float xv=rv[0]; int xi=ri[0];
      for(int w=1;w<T/64;w++) if(rv[w]<xv || (rv[w]==xv && ri[w]<xi)){ xv=rv[w]; xi=ri[w]; }
      knn[(size_t)bq*KK+j]=xi;
      sel=xi;
    }
    __syncthreads();
    d2[sel]=FLT_MAX;
    __syncthreads();
  }
}

// ---- sg-block pass1: h[k][o] = dot(g[k], w_lo[o]) + dot(c, w_hi[o]-w_lo[o]);
//      emit per-(bq,o) max/min over k and per-block channel partial sums for BN stats.
template<int C, int P>
__global__ void k_sg_pass1(const float* __restrict__ feats, const int* __restrict__ knn,
                           const int* __restrict__ fpsIdx, const float* __restrict__ w,
                           float* __restrict__ hmax, float* __restrict__ hmin,
                           float* __restrict__ part, int S){
  constexpr int O = 2*C;
  constexpr int T = O/2;              // two output channels per thread
  __shared__ __align__(16) float gf[KK][C];
  __shared__ float cf[C];
  int bq = blockIdx.x, tid = threadIdx.x;
  int b = bq / S;
  const float* fb = feats + (size_t)b*P*C;
  int ci = fpsIdx[bq];
  for(int d=tid; d<C; d+=T) cf[d] = fb[(size_t)ci*C+d];
  for(int i=tid; i<KK*C; i+=T){
    int k=i/C, d=i-k*C;
    gf[k][d] = fb[(size_t)knn[(size_t)bq*KK+k]*C + d];
  }
  __syncthreads();
  int o0=tid, o1=tid+T;
  const float* w0 = w + (size_t)o0*O;
  const float* w1 = w + (size_t)o1*O;
  float ct0=0.f, ct1=0.f;
  for(int d=0; d<C; d++){
    float cd = cf[d];
    ct0 += cd*(w0[C+d] - w0[d]);
    ct1 += cd*(w1[C+d] - w1[d]);
  }
  float2 acc[KK];
  #pragma unroll
  for(int k=0;k<KK;k++){ acc[k].x=0.f; acc[k].y=0.f; }
  for(int dc=0; dc<C; dc+=4){
    float4 a4 = *(const float4*)(w0 + dc);
    float4 c4 = *(const float4*)(w1 + dc);
    #pragma unroll
    for(int k=0;k<KK;k++){
      float4 g4 = *(const float4*)&gf[k][dc];   // broadcast, conflict-free
      acc[k].x += g4.x*a4.x + g4.y*a4.y + g4.z*a4.z + g4.w*a4.w;
      acc[k].y += g4.x*c4.x + g4.y*c4.y + g4.z*c4.z + g4.w*c4.w;
    }
  }
  float s0=0.f,q0=0.f,mx0=-FLT_MAX,mn0=FLT_MAX;
  float s1=0.f,q1=0.f,mx1=-FLT_MAX,mn1=FLT_MAX;
  #pragma unroll
  for(int k=0;k<KK;k++){
    float h0=acc[k].x+ct0, h1=acc[k].y+ct1;
    s0+=h0; q0+=h0*h0; mx0=fmaxf(mx0,h0); mn0=fminf(mn0,h0);
    s1+=h1; q1+=h1*h1; mx1=fmaxf(mx1,h1); mn1=fminf(mn1,h1);
  }
  size_t ob = (size_t)bq*O;
  hmax[ob+o0]=mx0; hmax[ob+o1]=mx1;
  hmin[ob+o0]=mn0; hmin[ob+o1]=mn1;
  float* pp = part + (size_t)bq*2*O;
  pp[o0]=s0; pp[o1]=s1; pp[O+o0]=q0; pp[O+o1]=q1;
}

// ---- reduce per-block partials -> per-channel mean/rstd
__global__ void k_reduce(const float* __restrict__ part, int nblk, int O, int M,
                         float* __restrict__ mean, float* __restrict__ rstd){
  int o = blockIdx.x, tid = threadIdx.x;
  float s=0.f, s2=0.f;
  for(int i=tid;i<nblk;i+=blockDim.x){ s += part[(size_t)i*2*O + o]; s2 += part[(size_t)i*2*O + O + o]; }
  __shared__ float bs[256], bq[256];
  bs[tid]=s; bq[tid]=s2; __syncthreads();
  for(int st=128; st>0; st>>=1){ if(tid<st){ bs[tid]+=bs[tid+st]; bq[tid]+=bq[tid+st]; } __syncthreads(); }
  if(tid==0){
    float m = bs[0]/M;
    float v = bq[0]/M - m*m; if(v<0.f) v=0.f;
    mean[o]=m; rstd[o]=rsqrtf(v+EPSV);
  }
}

// ---- epilogue: max_k relu(bn(h)) = relu(bn(slope>=0 ? hmax : hmin)); fp32 out, same layout
__global__ void k_postmax(const float* __restrict__ hmax, const float* __restrict__ hmin,
                          const float* __restrict__ mean, const float* __restrict__ rstd,
                          const float* __restrict__ g, const float* __restrict__ bb,
                          int O, int total, float* __restrict__ out){
  int i = blockIdx.x*blockDim.x + threadIdx.x;
  if(i>=total) return;
  int o = i % O;
  float sc = rstd[o]*g[o];
  float h = (sc>=0.f) ? hmax[i] : hmin[i];
  float v = (h-mean[o])*sc + bb[o];
  out[i] = v>0.f ? v : 0.f;
}

// ---- final epilogue with [B,S1,256] -> [B,256,S1] transpose, fp32 out
__global__ void k_postmax_out(const float* __restrict__ hmax, const float* __restrict__ hmin,
                              const float* __restrict__ mean, const float* __restrict__ rstd,
                              const float* __restrict__ g, const float* __restrict__ bb,
                              float* __restrict__ out){
  int i = blockIdx.x*blockDim.x + threadIdx.x;
  if(i >= BATCH*NS1*256) return;
  int o = i & 255;
  int s = (i>>8) & (NS1-1);
  int b = i >> 15;
  float sc = rstd[o]*g[o];
  float h = (sc>=0.f) ? hmax[i] : hmin[i];
  float v = (h-mean[o])*sc + bb[o];
  v = v>0.f ? v : 0.f;
  out[((size_t)b*256 + o)*NS1 + s] = v;
}

extern "C" void kernel_launch(void* const* d_in, const int* in_sizes, int n_in,
                              void* d_out, int out_size, void* d_ws, size_t ws_size,
                              hipStream_t stream){
  // reference dtypes are ALL float32 -> cast to const float* (NOT bf16)
  const float* x    = (const float*)d_in[0];
  const float* w1   = (const float*)d_in[1];
  const float* g1   = (const float*)d_in[2];
  const float* b1   = (const float*)d_in[3];
  const float* w2   = (const float*)d_in[4];
  const float* g2   = (const float*)d_in[5];
  const float* b2   = (const float*)d_in[6];
  const float* wsg0 = (const float*)d_in[7];
  const float* gsg0 = (const float*)d_in[8];
  const float* bsg0 = (const float*)d_in[9];
  const float* wsg1 = (const float*)d_in[10];
  const float* gsg1 = (const float*)d_in[11];
  const float* bsg1 = (const float*)d_in[12];
  float* out = (float*)d_out;

  // workspace carve-up (fp32 elements); total ~37 MB
  float* wsf = (float*)d_ws;
  float* coords = wsf;                    wsf += BATCH*NPTS*3;
  float* t1     = wsf;                    wsf += BATCH*NPTS*64;
  float* t2     = wsf;                    wsf += BATCH*NPTS*64;
  float* mean1=wsf;  wsf+=64;  float* rstd1=wsf;  wsf+=64;
  float* mean2=wsf;  wsf+=64;  float* rstd2=wsf;  wsf+=64;
  float* meanS0=wsf; wsf+=128; float* rstdS0=wsf; wsf+=128;
  float* meanS1=wsf; wsf+=256; float* rstdS1=wsf; wsf+=256;
  int*   fps0 = (int*)wsf;                wsf += BATCH*NS0;
  float* xyz0 = wsf;                      wsf += BATCH*NS0*3;
  int*   knn0 = (int*)wsf;                wsf += BATCH*NS0*KK;
  float* hmax0= wsf;                      wsf += BATCH*NS0*128;
  float* hmin0= wsf;                      wsf += BATCH*NS0*128;
  float* part0= wsf;                      wsf += BATCH*NS0*2*128;
  float* f1   = wsf;                      wsf += BATCH*NS0*128;
  int*   fps1 = (int*)wsf;                wsf += BATCH*NS1;
  float* xyz1 = wsf;                      wsf += BATCH*NS1*3;
  int*   knn1 = (int*)wsf;                wsf += BATCH*NS1*KK;
  float* hmax1= wsf;                      wsf += BATCH*NS1*256;
  float* hmin1= wsf;                      wsf += BATCH*NS1*256;
  float* part1= wsf;                      wsf += BATCH*NS1*2*256;

  // embed MLP (two 1x1 convs with training-mode BN)
  k_embed1<<<dim3(128), dim3(256), 0, stream>>>(x, w1, coords, t1);
  k_stats <<<dim3(64),  dim3(256), 0, stream>>>(t1, BATCH*NPTS, 64, mean1, rstd1);
  k_embed2<<<dim3(512), dim3(256), 0, stream>>>(t1, w2, mean1, rstd1, g1, b1, t2);
  k_stats <<<dim3(64),  dim3(256), 0, stream>>>(t2, BATCH*NPTS, 64, mean2, rstd2);
  k_bnrelu<<<dim3(8192),dim3(256), 0, stream>>>(t2, BATCH*NPTS*64, 64, mean2, rstd2, g2, b2);

  // SG block 0: N=2048 -> S0=256, C=64 -> O=128
  k_fps<NPTS,NS0,256><<<dim3(BATCH),     dim3(256), 0, stream>>>(coords, fps0, xyz0);
  k_knn<NPTS,256>    <<<dim3(BATCH*NS0), dim3(256), 0, stream>>>(coords, xyz0, NS0, knn0);
  k_sg_pass1<64,NPTS><<<dim3(BATCH*NS0), dim3(64),  0, stream>>>(t2, knn0, fps0, wsg0, hmax0, hmin0, part0, NS0);
  k_reduce           <<<dim3(128),       dim3(256), 0, stream>>>(part0, BATCH*NS0, 128, BATCH*NS0*KK, meanS0, rstdS0);
  k_postmax          <<<dim3(2048),      dim3(256), 0, stream>>>(hmax0, hmin0, meanS0, rstdS0, gsg0, bsg0,
                                                                 128, BATCH*NS0*128, f1);

  // SG block 1: S0=256 -> S1=128, C=128 -> O=256
  k_fps<NS0,NS1,256> <<<dim3(BATCH),     dim3(256), 0, stream>>>(xyz0, fps1, xyz1);
  k_knn<NS0,256>     <<<dim3(BATCH*NS1), dim3(256), 0, stream>>>(xyz0, xyz1, NS1, knn1);
  k_sg_pass1<128,NS0><<<dim3(BATCH*NS1), dim3(128), 0, stream>>>(f1, knn1, fps1, wsg1, hmax1, hmin1, part1, NS1);
  k_reduce           <<<dim3(256),       dim3(256), 0, stream>>>(part1, BATCH*NS1, 256, BATCH*NS1*KK, meanS1, rstdS1);
  k_postmax_out      <<<dim3(2048),      dim3(256), 0, stream>>>(hmax1, hmin1, meanS1, rstdS1, gsg1, bsg1, out);
}

// Round 3
// 1388.895 us; speedup vs baseline: 1.8370x; 1.8370x over previous
//
#include <hip/hip_runtime.h>
#include <float.h>

#define BATCH 16
#define NPTS  2048
#define NS0   256
#define NS1   128
#define KK    32
#define EPSV  1e-5f

// exact numpy-order squared distance: ((dx*dx + dy*dy) + dz*dz), no FMA contraction
__device__ __forceinline__ float sqdist(float ax,float ay,float az,float bx,float by,float bz){
  float dx=__fsub_rn(ax,bx), dy=__fsub_rn(ay,by), dz=__fsub_rn(az,bz);
  return __fadd_rn(__fadd_rn(__fmul_rn(dx,dx),__fmul_rn(dy,dy)),__fmul_rn(dz,dz));
}

// ---- embed layer 1: transpose x [B,3,N] -> coords [B,N,3], t1 = coords @ w1^T  ([B,N,64])
__global__ void k_embed1(const float* __restrict__ x, const float* __restrict__ w1,
                         float* __restrict__ coords, float* __restrict__ t1){
  __shared__ float w[64*3];
  int tid = threadIdx.x;
  if (tid < 192) w[tid] = w1[tid];
  __syncthreads();
  int gid = blockIdx.x*blockDim.x + tid;
  if (gid >= BATCH*NPTS) return;
  int b = gid / NPTS, n = gid % NPTS;
  float cx = x[(b*3+0)*NPTS + n];
  float cy = x[(b*3+1)*NPTS + n];
  float cz = x[(b*3+2)*NPTS + n];
  coords[gid*3+0]=cx; coords[gid*3+1]=cy; coords[gid*3+2]=cz;
  float* o = t1 + (size_t)gid*64;
  #pragma unroll
  for(int j=0;j<64;j++) o[j] = cx*w[j*3+0] + cy*w[j*3+1] + cz*w[j*3+2];
}

// ---- per-channel mean/rstd over M rows of [M][C]
__global__ void k_stats(const float* __restrict__ t, int M, int C,
                        float* __restrict__ mean, float* __restrict__ rstd){
  int c = blockIdx.x, tid = threadIdx.x;
  float s=0.f, s2=0.f;
  for(int r=tid; r<M; r+=blockDim.x){ float v = t[(size_t)r*C+c]; s+=v; s2+=v*v; }
  __shared__ float bs[256], bq[256];
  bs[tid]=s; bq[tid]=s2; __syncthreads();
  for(int st=128; st>0; st>>=1){ if(tid<st){ bs[tid]+=bs[tid+st]; bq[tid]+=bq[tid+st]; } __syncthreads(); }
  if(tid==0){
    float m = bs[0]/M;
    float v = bq[0]/M - m*m; if(v<0.f) v=0.f;
    mean[c]=m; rstd[c]=rsqrtf(v+EPSV);
  }
}

// ---- embed layer 2: t2 = relu(bn(t1)) @ w2^T  (64x64), 64 points per block
__global__ void k_embed2(const float* __restrict__ t1, const float* __restrict__ w2,
                         const float* __restrict__ mean1, const float* __restrict__ rstd1,
                         const float* __restrict__ g1, const float* __restrict__ b1,
                         float* __restrict__ t2){
  __shared__ __align__(16) float fin[64][64];
  __shared__ float sm[64], sr[64], sg[64], sb[64];
  int tid = threadIdx.x;
  if (tid<64){ sm[tid]=mean1[tid]; sr[tid]=rstd1[tid]; sg[tid]=g1[tid]; sb[tid]=b1[tid]; }
  __syncthreads();
  int base = blockIdx.x*64;
  for(int i=tid;i<4096;i+=256){
    int p=i>>6, c=i&63;
    float v = t1[(size_t)(base+p)*64 + c];
    v = (v - sm[c])*sr[c]*sg[c] + sb[c];
    fin[p][c] = v>0.f ? v : 0.f;
  }
  __syncthreads();
  int o = tid & 63, p0 = tid>>6;
  float acc[16];
  #pragma unroll
  for(int i=0;i<16;i++) acc[i]=0.f;
  for(int cc=0; cc<64; cc+=4){
    float4 wv = *(const float4*)(w2 + o*64 + cc);     // global, L1-cached
    #pragma unroll
    for(int i=0;i<16;i++){
      float4 f4 = *(const float4*)&fin[p0 + i*4][cc]; // broadcast read
      acc[i] += f4.x*wv.x + f4.y*wv.y + f4.z*wv.z + f4.w*wv.w;
    }
  }
  #pragma unroll
  for(int i=0;i<16;i++) t2[(size_t)(base+p0+i*4)*64 + o] = acc[i];
}

// ---- elementwise bn+relu in place
__global__ void k_bnrelu(float* __restrict__ t, int total, int C,
                         const float* __restrict__ mean, const float* __restrict__ rstd,
                         const float* __restrict__ g, const float* __restrict__ b){
  int i = blockIdx.x*blockDim.x + threadIdx.x;
  if(i>=total) return;
  int c = i % C;
  float v = t[i];
  v = (v-mean[c])*rstd[c]*g[c] + b[c];
  t[i] = v>0.f ? v : 0.f;
}

// ---- farthest point sampling, one block per batch. Emits idx + gathered coords.
template<int P, int S, int T>
__global__ void k_fps(const float* __restrict__ pts, int* __restrict__ outIdx,
                      float* __restrict__ outXyz){
  constexpr int PPT = P/T;
  int b = blockIdx.x, tid = threadIdx.x;
  const float* p = pts + (size_t)b*P*3;
  float px[PPT], py[PPT], pz[PPT], dist[PPT];
  #pragma unroll
  for(int i=0;i<PPT;i++){
    int n = tid*PPT + i;
    px[i]=p[n*3]; py[i]=p[n*3+1]; pz[i]=p[n*3+2];
    dist[i]=1e10f;
  }
  __shared__ float rv[T/64];
  __shared__ int   ri[T/64];
  __shared__ int   curs;
  int cur = 0;
  for(int s=0;s<S;s++){
    if(tid==0){
      outIdx[b*S+s]=cur;
      outXyz[((size_t)b*S+s)*3+0]=p[cur*3+0];
      outXyz[((size_t)b*S+s)*3+1]=p[cur*3+1];
      outXyz[((size_t)b*S+s)*3+2]=p[cur*3+2];
    }
    if(s==S-1) break;
    float cx=p[cur*3], cy=p[cur*3+1], cz=p[cur*3+2];
    float bv=-FLT_MAX; int bi=0;
    #pragma unroll
    for(int i=0;i<PPT;i++){
      float d = sqdist(px[i],py[i],pz[i],cx,cy,cz);
      float nd = fminf(dist[i], d);
      dist[i]=nd;
      if(nd>bv){ bv=nd; bi=tid*PPT+i; }   // ascending n => strict '>' keeps lowest idx on tie
    }
    #pragma unroll
    for(int off=32; off>0; off>>=1){
      float ov=__shfl_down(bv,off);
      int   oi=__shfl_down(bi,off);
      if(ov>bv || (ov==bv && oi<bi)){ bv=ov; bi=oi; }
    }
    if((tid&63)==0){ rv[tid>>6]=bv; ri[tid>>6]=bi; }
    __syncthreads();
    if(tid==0){
      float xv=rv[0]; int xi=ri[0];
      for(int w=1;w<T/64;w++) if(rv[w]>xv || (rv[w]==xv && ri[w]<xi)){ xv=rv[w]; xi=ri[w]; }
      curs=xi;
    }
    __syncthreads();
    cur=curs;
  }
}

// ---- exact 32-NN per query via iterative argmin; tie -> lowest index (matches stable top_k set)
template<int P, int T>
__global__ void k_knn(const float* __restrict__ pts, const float* __restrict__ q,
                      int S, int* __restrict__ knn){
  int bq = blockIdx.x, tid = threadIdx.x;
  int b = bq / S;
  __shared__ float d2[P];
  __shared__ float rv[T/64];
  __shared__ int   ri[T/64];
  __shared__ int   sel;
  const float* p = pts + (size_t)b*P*3;
  float qx=q[(size_t)bq*3], qy=q[(size_t)bq*3+1], qz=q[(size_t)bq*3+2];
  for(int n=tid;n<P;n+=T) d2[n] = sqdist(qx,qy,qz,p[n*3],p[n*3+1],p[n*3+2]);
  __syncthreads();
  for(int j=0;j<KK;j++){
    float bv=FLT_MAX; int bi=P;
    for(int n=tid;n<P;n+=T){ float v=d2[n]; if(v<bv){ bv=v; bi=n; } }
    #pragma unroll
    for(int off=32; off>0; off>>=1){
      float ov=__shfl_down(bv,off);
      int   oi=__shfl_down(bi,off);
      if(ov<bv || (ov==bv && oi<bi)){ bv=ov; bi=oi; }
    }
    if((tid&63)==0){ rv[tid>>6]=bv; ri[tid>>6]=bi; }
    __syncthreads();
    if(tid==0){
      float xv=rv[0]; int xi=ri[0];
      for(int w=1;w<T/64;w++) if(rv[w]<xv || (rv[w]==xv && ri[w]<xi)){ xv=rv[w]; xi=ri[w]; }
      knn[(size_t)bq*KK+j]=xi;
      sel=xi;
    }
    __syncthreads();
    d2[sel]=FLT_MAX;
    __syncthreads();
  }
}

// ---- sg-block pass1, spill-free: one output channel per thread (T=O), k chunked by 8.
//      h[k][o] = dot(g[k], w_lo[o]) + dot(c, w_hi[o]-w_lo[o]);
//      emit per-(bq,o) max/min over k and per-(bq,o) sum/sumsq for BN stats.
template<int C, int P>
__global__ void k_sg_pass1(const float* __restrict__ feats, const int* __restrict__ knn,
                           const int* __restrict__ fpsIdx, const float* __restrict__ w,
                           float* __restrict__ hmax, float* __restrict__ hmin,
                           float* __restrict__ part, int S){
  constexpr int O = 2*C;
  constexpr int T = O;              // one output channel per thread
  constexpr int C4 = C/4;
  __shared__ __align__(16) float gf[KK][C];
  __shared__ __align__(16) float cf[C];
  int bq = blockIdx.x, tid = threadIdx.x;
  int b = bq / S;
  const float* fb = feats + (size_t)b*P*C;
  int ci = fpsIdx[bq];
  if (tid < C) cf[tid] = fb[(size_t)ci*C + tid];
  for(int i=tid; i<KK*C4; i+=T){
    int k = i/C4, d4 = i - k*C4;
    ((float4*)gf[k])[d4] = ((const float4*)(fb + (size_t)knn[(size_t)bq*KK+k]*C))[d4];
  }
  __syncthreads();
  int o = tid;
  const float* wr = w + (size_t)o*O;
  float ct = 0.f;
  for(int dc=0; dc<C; dc+=4){
    float4 wl = *(const float4*)(wr + dc);
    float4 wh = *(const float4*)(wr + C + dc);
    float4 c4 = *(const float4*)&cf[dc];
    ct += c4.x*(wh.x-wl.x) + c4.y*(wh.y-wl.y) + c4.z*(wh.z-wl.z) + c4.w*(wh.w-wl.w);
  }
  float s=0.f, q=0.f, mx=-FLT_MAX, mn=FLT_MAX;
  for(int kc=0; kc<KK; kc+=8){
    float acc[8];
    #pragma unroll
    for(int j=0;j<8;j++) acc[j]=0.f;
    for(int dc=0; dc<C; dc+=4){
      float4 wv = *(const float4*)(wr + dc);          // L1/L2-hot weight row
      #pragma unroll
      for(int j=0;j<8;j++){
        float4 g4 = *(const float4*)&gf[kc+j][dc];    // LDS broadcast, conflict-free
        acc[j] += g4.x*wv.x + g4.y*wv.y + g4.z*wv.z + g4.w*wv.w;
      }
    }
    #pragma unroll
    for(int j=0;j<8;j++){
      float h = acc[j] + ct;
      s += h; q += h*h; mx = fmaxf(mx,h); mn = fminf(mn,h);
    }
  }
  size_t ob = (size_t)bq*O;
  hmax[ob+o]=mx; hmin[ob+o]=mn;
  float* pp = part + (size_t)bq*2*O;
  pp[o]=s; pp[O+o]=q;
}

// ---- reduce per-block partials -> per-channel mean/rstd
__global__ void k_reduce(const float* __restrict__ part, int nblk, int O, int M,
                         float* __restrict__ mean, float* __restrict__ rstd){
  int o = blockIdx.x, tid = threadIdx.x;
  float s=0.f, s2=0.f;
  for(int i=tid;i<nblk;i+=blockDim.x){ s += part[(size_t)i*2*O + o]; s2 += part[(size_t)i*2*O + O + o]; }
  __shared__ float bs[256], bq[256];
  bs[tid]=s; bq[tid]=s2; __syncthreads();
  for(int st=128; st>0; st>>=1){ if(tid<st){ bs[tid]+=bs[tid+st]; bq[tid]+=bq[tid+st]; } __syncthreads(); }
  if(tid==0){
    float m = bs[0]/M;
    float v = bq[0]/M - m*m; if(v<0.f) v=0.f;
    mean[o]=m; rstd[o]=rsqrtf(v+EPSV);
  }
}

// ---- epilogue: max_k relu(bn(h)) = relu(bn(slope>=0 ? hmax : hmin)); fp32 out, same layout
__global__ void k_postmax(const float* __restrict__ hmax, const float* __restrict__ hmin,
                          const float* __restrict__ mean, const float* __restrict__ rstd,
                          const float* __restrict__ g, const float* __restrict__ bb,
                          int O, int total, float* __restrict__ out){
  int i = blockIdx.x*blockDim.x + threadIdx.x;
  if(i>=total) return;
  int o = i % O;
  float sc = rstd[o]*g[o];
  float h = (sc>=0.f) ? hmax[i] : hmin[i];
  float v = (h-mean[o])*sc + bb[o];
  out[i] = v>0.f ? v : 0.f;
}

// ---- final epilogue with [B,S1,256] -> [B,256,S1] transpose, fp32 out
__global__ void k_postmax_out(const float* __restrict__ hmax, const float* __restrict__ hmin,
                              const float* __restrict__ mean, const float* __restrict__ rstd,
                              const float* __restrict__ g, const float* __restrict__ bb,
                              float* __restrict__ out){
  int i = blockIdx.x*blockDim.x + threadIdx.x;
  if(i >= BATCH*NS1*256) return;
  int o = i & 255;
  int s = (i>>8) & (NS1-1);
  int b = i >> 15;
  float sc = rstd[o]*g[o];
  float h = (sc>=0.f) ? hmax[i] : hmin[i];
  float v = (h-mean[o])*sc + bb[o];
  v = v>0.f ? v : 0.f;
  out[((size_t)b*256 + o)*NS1 + s] = v;
}

extern "C" void kernel_launch(void* const* d_in, const int* in_sizes, int n_in,
                              void* d_out, int out_size, void* d_ws, size_t ws_size,
                              hipStream_t stream){
  const float* x    = (const float*)d_in[0];
  const float* w1   = (const float*)d_in[1];
  const float* g1   = (const float*)d_in[2];
  const float* b1   = (const float*)d_in[3];
  const float* w2   = (const float*)d_in[4];
  const float* g2   = (const float*)d_in[5];
  const float* b2   = (const float*)d_in[6];
  const float* wsg0 = (const float*)d_in[7];
  const float* gsg0 = (const float*)d_in[8];
  const float* bsg0 = (const float*)d_in[9];
  const float* wsg1 = (const float*)d_in[10];
  const float* gsg1 = (const float*)d_in[11];
  const float* bsg1 = (const float*)d_in[12];
  float* out = (float*)d_out;

  // workspace carve-up (fp32 elements); total ~37 MB
  float* wsf = (float*)d_ws;
  float* coords = wsf;                    wsf += BATCH*NPTS*3;
  float* t1     = wsf;                    wsf += BATCH*NPTS*64;
  float* t2     = wsf;                    wsf += BATCH*NPTS*64;
  float* mean1=wsf;  wsf+=64;  float* rstd1=wsf;  wsf+=64;
  float* mean2=wsf;  wsf+=64;  float* rstd2=wsf;  wsf+=64;
  float* meanS0=wsf; wsf+=128; float* rstdS0=wsf; wsf+=128;
  float* meanS1=wsf; wsf+=256; float* rstdS1=wsf; wsf+=256;
  int*   fps0 = (int*)wsf;                wsf += BATCH*NS0;
  float* xyz0 = wsf;                      wsf += BATCH*NS0*3;
  int*   knn0 = (int*)wsf;                wsf += BATCH*NS0*KK;
  float* hmax0= wsf;                      wsf += BATCH*NS0*128;
  float* hmin0= wsf;                      wsf += BATCH*NS0*128;
  float* part0= wsf;                      wsf += BATCH*NS0*2*128;
  float* f1   = wsf;                      wsf += BATCH*NS0*128;
  int*   fps1 = (int*)wsf;                wsf += BATCH*NS1;
  float* xyz1 = wsf;                      wsf += BATCH*NS1*3;
  int*   knn1 = (int*)wsf;                wsf += BATCH*NS1*KK;
  float* hmax1= wsf;                      wsf += BATCH*NS1*256;
  float* hmin1= wsf;                      wsf += BATCH*NS1*256;
  float* part1= wsf;                      wsf += BATCH*NS1*2*256;

  // embed MLP (two 1x1 convs with training-mode BN)
  k_embed1<<<dim3(128), dim3(256), 0, stream>>>(x, w1, coords, t1);
  k_stats <<<dim3(64),  dim3(256), 0, stream>>>(t1, BATCH*NPTS, 64, mean1, rstd1);
  k_embed2<<<dim3(512), dim3(256), 0, stream>>>(t1, w2, mean1, rstd1, g1, b1, t2);
  k_stats <<<dim3(64),  dim3(256), 0, stream>>>(t2, BATCH*NPTS, 64, mean2, rstd2);
  k_bnrelu<<<dim3(8192),dim3(256), 0, stream>>>(t2, BATCH*NPTS*64, 64, mean2, rstd2, g2, b2);

  // SG block 0: N=2048 -> S0=256, C=64 -> O=128
  k_fps<NPTS,NS0,256><<<dim3(BATCH),     dim3(256), 0, stream>>>(coords, fps0, xyz0);
  k_knn<NPTS,256>    <<<dim3(BATCH*NS0), dim3(256), 0, stream>>>(coords, xyz0, NS0, knn0);
  k_sg_pass1<64,NPTS><<<dim3(BATCH*NS0), dim3(128), 0, stream>>>(t2, knn0, fps0, wsg0, hmax0, hmin0, part0, NS0);
  k_reduce           <<<dim3(128),       dim3(256), 0, stream>>>(part0, BATCH*NS0, 128, BATCH*NS0*KK, meanS0, rstdS0);
  k_postmax          <<<dim3(2048),      dim3(256), 0, stream>>>(hmax0, hmin0, meanS0, rstdS0, gsg0, bsg0,
                                                                 128, BATCH*NS0*128, f1);

  // SG block 1: S0=256 -> S1=128, C=128 -> O=256
  k_fps<NS0,NS1,256> <<<dim3(BATCH),     dim3(256), 0, stream>>>(xyz0, fps1, xyz1);
  k_knn<NS0,256>     <<<dim3(BATCH*NS1), dim3(256), 0, stream>>>(xyz0, xyz1, NS1, knn1);
  k_sg_pass1<128,NS0><<<dim3(BATCH*NS1), dim3(256), 0, stream>>>(f1, knn1, fps1, wsg1, hmax1, hmin1, part1, NS1);
  k_reduce           <<<dim3(256),       dim3(256), 0, stream>>>(part1, BATCH*NS1, 256, BATCH*NS1*KK, meanS1, rstdS1);
  k_postmax_out      <<<dim3(2048),      dim3(256), 0, stream>>>(hmax1, hmin1, meanS1, rstdS1, gsg1, bsg1, out);
}

// Round 4
// 1204.092 us; speedup vs baseline: 2.1189x; 1.1535x over previous
//
#include <hip/hip_runtime.h>
#include <float.h>

#define BATCH 16
#define NPTS  2048
#define NS0   256
#define NS1   128
#define KK    32
#define EPSV  1e-5f

// exact numpy-order squared distance: ((dx*dx + dy*dy) + dz*dz), no FMA contraction
__device__ __forceinline__ float sqdist(float ax,float ay,float az,float bx,float by,float bz){
  float dx=__fsub_rn(ax,bx), dy=__fsub_rn(ay,by), dz=__fsub_rn(az,bz);
  return __fadd_rn(__fadd_rn(__fmul_rn(dx,dx),__fmul_rn(dy,dy)),__fmul_rn(dz,dz));
}

// ---- embed layer 1: transpose x [B,3,N] -> coords [B,N,3], t1 = coords @ w1^T  ([B,N,64])
__global__ __launch_bounds__(256) void k_embed1(const float* __restrict__ x, const float* __restrict__ w1,
                         float* __restrict__ coords, float* __restrict__ t1){
  __shared__ float w[64*3];
  int tid = threadIdx.x;
  if (tid < 192) w[tid] = w1[tid];
  __syncthreads();
  int gid = blockIdx.x*blockDim.x + tid;
  if (gid >= BATCH*NPTS) return;
  int b = gid / NPTS, n = gid % NPTS;
  float cx = x[(b*3+0)*NPTS + n];
  float cy = x[(b*3+1)*NPTS + n];
  float cz = x[(b*3+2)*NPTS + n];
  coords[gid*3+0]=cx; coords[gid*3+1]=cy; coords[gid*3+2]=cz;
  float* o = t1 + (size_t)gid*64;
  #pragma unroll
  for(int j=0;j<64;j++) o[j] = cx*w[j*3+0] + cy*w[j*3+1] + cz*w[j*3+2];
}

// ---- per-channel mean/rstd over M rows of [M][C]
__global__ __launch_bounds__(256) void k_stats(const float* __restrict__ t, int M, int C,
                        float* __restrict__ mean, float* __restrict__ rstd){
  int c = blockIdx.x, tid = threadIdx.x;
  float s=0.f, s2=0.f;
  for(int r=tid; r<M; r+=blockDim.x){ float v = t[(size_t)r*C+c]; s+=v; s2+=v*v; }
  __shared__ float bs[256], bq[256];
  bs[tid]=s; bq[tid]=s2; __syncthreads();
  for(int st=128; st>0; st>>=1){ if(tid<st){ bs[tid]+=bs[tid+st]; bq[tid]+=bq[tid+st]; } __syncthreads(); }
  if(tid==0){
    float m = bs[0]/M;
    float v = bq[0]/M - m*m; if(v<0.f) v=0.f;
    mean[c]=m; rstd[c]=rsqrtf(v+EPSV);
  }
}

// ---- embed layer 2: t2 = relu(bn(t1)) @ w2^T  (64x64), 64 points per block
__global__ __launch_bounds__(256, 1) void k_embed2(const float* __restrict__ t1, const float* __restrict__ w2,
                         const float* __restrict__ mean1, const float* __restrict__ rstd1,
                         const float* __restrict__ g1, const float* __restrict__ b1,
                         float* __restrict__ t2){
  __shared__ __align__(16) float fin[64][64];
  __shared__ float sm[64], sr[64], sg[64], sb[64];
  int tid = threadIdx.x;
  if (tid<64){ sm[tid]=mean1[tid]; sr[tid]=rstd1[tid]; sg[tid]=g1[tid]; sb[tid]=b1[tid]; }
  __syncthreads();
  int base = blockIdx.x*64;
  for(int i=tid;i<4096;i+=256){
    int p=i>>6, c=i&63;
    float v = t1[(size_t)(base+p)*64 + c];
    v = (v - sm[c])*sr[c]*sg[c] + sb[c];
    fin[p][c] = v>0.f ? v : 0.f;
  }
  __syncthreads();
  int o = tid & 63, p0 = tid>>6;
  float acc[16];
  #pragma unroll
  for(int i=0;i<16;i++) acc[i]=0.f;
  for(int cc=0; cc<64; cc+=4){
    float4 wv = *(const float4*)(w2 + o*64 + cc);     // global, L1-cached
    #pragma unroll
    for(int i=0;i<16;i++){
      float4 f4 = *(const float4*)&fin[p0 + i*4][cc]; // broadcast read
      acc[i] += f4.x*wv.x + f4.y*wv.y + f4.z*wv.z + f4.w*wv.w;
    }
  }
  #pragma unroll
  for(int i=0;i<16;i++) t2[(size_t)(base+p0+i*4)*64 + o] = acc[i];
}

// ---- elementwise bn+relu in place
__global__ __launch_bounds__(256) void k_bnrelu(float* __restrict__ t, int total, int C,
                         const float* __restrict__ mean, const float* __restrict__ rstd,
                         const float* __restrict__ g, const float* __restrict__ b){
  int i = blockIdx.x*blockDim.x + threadIdx.x;
  if(i>=total) return;
  int c = i % C;
  float v = t[i];
  v = (v-mean[c])*rstd[c]*g[c] + b[c];
  t[i] = v>0.f ? v : 0.f;
}

// ---- farthest point sampling, one block per batch. Emits idx + gathered coords.
template<int P, int S, int T>
__global__ __launch_bounds__(256) void k_fps(const float* __restrict__ pts, int* __restrict__ outIdx,
                      float* __restrict__ outXyz){
  constexpr int PPT = P/T;
  int b = blockIdx.x, tid = threadIdx.x;
  const float* p = pts + (size_t)b*P*3;
  float px[PPT], py[PPT], pz[PPT], dist[PPT];
  #pragma unroll
  for(int i=0;i<PPT;i++){
    int n = tid*PPT + i;
    px[i]=p[n*3]; py[i]=p[n*3+1]; pz[i]=p[n*3+2];
    dist[i]=1e10f;
  }
  __shared__ float rv[T/64];
  __shared__ int   ri[T/64];
  __shared__ int   curs;
  int cur = 0;
  for(int s=0;s<S;s++){
    if(tid==0){
      outIdx[b*S+s]=cur;
      outXyz[((size_t)b*S+s)*3+0]=p[cur*3+0];
      outXyz[((size_t)b*S+s)*3+1]=p[cur*3+1];
      outXyz[((size_t)b*S+s)*3+2]=p[cur*3+2];
    }
    if(s==S-1) break;
    float cx=p[cur*3], cy=p[cur*3+1], cz=p[cur*3+2];
    float bv=-FLT_MAX; int bi=0;
    #pragma unroll
    for(int i=0;i<PPT;i++){
      float d = sqdist(px[i],py[i],pz[i],cx,cy,cz);
      float nd = fminf(dist[i], d);
      dist[i]=nd;
      if(nd>bv){ bv=nd; bi=tid*PPT+i; }   // ascending n => strict '>' keeps lowest idx on tie
    }
    #pragma unroll
    for(int off=32; off>0; off>>=1){
      float ov=__shfl_down(bv,off);
      int   oi=__shfl_down(bi,off);
      if(ov>bv || (ov==bv && oi<bi)){ bv=ov; bi=oi; }
    }
    if((tid&63)==0){ rv[tid>>6]=bv; ri[tid>>6]=bi; }
    __syncthreads();
    if(tid==0){
      float xv=rv[0]; int xi=ri[0];
      for(int w=1;w<T/64;w++) if(rv[w]>xv || (rv[w]==xv && ri[w]<xi)){ xv=rv[w]; xi=ri[w]; }
      curs=xi;
    }
    __syncthreads();
    cur=curs;
  }
}

// ---- exact 32-NN per query via iterative argmin; tie -> lowest index (matches stable top_k set)
template<int P, int T>
__global__ __launch_bounds__(256) void k_knn(const float* __restrict__ pts, const float* __restrict__ q,
                      int S, int* __restrict__ knn){
  int bq = blockIdx.x, tid = threadIdx.x;
  int b = bq / S;
  __shared__ float d2[P];
  __shared__ float rv[T/64];
  __shared__ int   ri[T/64];
  __shared__ int   sel;
  const float* p = pts + (size_t)b*P*3;
  float qx=q[(size_t)bq*3], qy=q[(size_t)bq*3+1], qz=q[(size_t)bq*3+2];
  for(int n=tid;n<P;n+=T) d2[n] = sqdist(qx,qy,qz,p[n*3],p[n*3+1],p[n*3+2]);
  __syncthreads();
  for(int j=0;j<KK;j++){
    float bv=FLT_MAX; int bi=P;
    for(int n=tid;n<P;n+=T){ float v=d2[n]; if(v<bv){ bv=v; bi=n; } }
    #pragma unroll
    for(int off=32; off>0; off>>=1){
      float ov=__shfl_down(bv,off);
      int   oi=__shfl_down(bi,off);
      if(ov<bv || (ov==bv && oi<bi)){ bv=ov; bi=oi; }
    }
    if((tid&63)==0){ rv[tid>>6]=bv; ri[tid>>6]=bi; }
    __syncthreads();
    if(tid==0){
      float xv=rv[0]; int xi=ri[0];
      for(int w=1;w<T/64;w++) if(rv[w]<xv || (rv[w]==xv && ri[w]<xi)){ xv=rv[w]; xi=ri[w]; }
      knn[(size_t)bq*KK+j]=xi;
      sel=xi;
    }
    __syncthreads();
    d2[sel]=FLT_MAX;
    __syncthreads();
  }
}

// ---- sg-block pass1, spill-free: one output channel per thread (T=O), k chunked by 16.
//      __launch_bounds__(T,1) lifts the default 64-VGPR cap that was forcing scratch spills.
template<int C, int P>
__global__ __launch_bounds__(2*C, 1) void k_sg_pass1(
                           const float* __restrict__ feats, const int* __restrict__ knn,
                           const int* __restrict__ fpsIdx, const float* __restrict__ w,
                           float* __restrict__ hmax, float* __restrict__ hmin,
                           float* __restrict__ part, int S){
  constexpr int O = 2*C;
  constexpr int T = O;              // one output channel per thread
  constexpr int C4 = C/4;
  __shared__ __align__(16) float gf[KK][C];
  __shared__ __align__(16) float cf[C];
  int bq = blockIdx.x, tid = threadIdx.x;
  int b = bq / S;
  const float* fb = feats + (size_t)b*P*C;
  int ci = fpsIdx[bq];
  if (tid < C) cf[tid] = fb[(size_t)ci*C + tid];
  for(int i=tid; i<KK*C4; i+=T){
    int k = i/C4, d4 = i - k*C4;
    ((float4*)gf[k])[d4] = ((const float4*)(fb + (size_t)knn[(size_t)bq*KK+k]*C))[d4];
  }
  __syncthreads();
  int o = tid;
  const float* wr = w + (size_t)o*O;
  float ct = 0.f;
  for(int dc=0; dc<C; dc+=4){
    float4 wl = *(const float4*)(wr + dc);
    float4 wh = *(const float4*)(wr + C + dc);
    float4 c4 = *(const float4*)&cf[dc];
    ct += c4.x*(wh.x-wl.x) + c4.y*(wh.y-wl.y) + c4.z*(wh.z-wl.z) + c4.w*(wh.w-wl.w);
  }
  float s=0.f, q=0.f, mx=-FLT_MAX, mn=FLT_MAX;
  for(int kc=0; kc<KK; kc+=16){
    float acc[16];
    #pragma unroll
    for(int j=0;j<16;j++) acc[j]=0.f;
    for(int dc=0; dc<C; dc+=4){
      float4 wv = *(const float4*)(wr + dc);          // L1/L2-hot weight row
      #pragma unroll
      for(int j=0;j<16;j++){
        float4 g4 = *(const float4*)&gf[kc+j][dc];    // LDS wave-uniform broadcast
        acc[j] += g4.x*wv.x + g4.y*wv.y + g4.z*wv.z + g4.w*wv.w;
      }
    }
    #pragma unroll
    for(int j=0;j<16;j++){
      float h = acc[j] + ct;
      s += h; q += h*h; mx = fmaxf(mx,h); mn = fminf(mn,h);
    }
  }
  size_t ob = (size_t)bq*O;
  hmax[ob+o]=mx; hmin[ob+o]=mn;
  float* pp = part + (size_t)bq*2*O;
  pp[o]=s; pp[O+o]=q;
}

// ---- reduce per-block partials -> per-channel mean/rstd
__global__ __launch_bounds__(256) void k_reduce(const float* __restrict__ part, int nblk, int O, int M,
                         float* __restrict__ mean, float* __restrict__ rstd){
  int o = blockIdx.x, tid = threadIdx.x;
  float s=0.f, s2=0.f;
  for(int i=tid;i<nblk;i+=blockDim.x){ s += part[(size_t)i*2*O + o]; s2 += part[(size_t)i*2*O + O + o]; }
  __shared__ float bs[256], bq[256];
  bs[tid]=s; bq[tid]=s2; __syncthreads();
  for(int st=128; st>0; st>>=1){ if(tid<st){ bs[tid]+=bs[tid+st]; bq[tid]+=bq[tid+st]; } __syncthreads(); }
  if(tid==0){
    float m = bs[0]/M;
    float v = bq[0]/M - m*m; if(v<0.f) v=0.f;
    mean[o]=m; rstd[o]=rsqrtf(v+EPSV);
  }
}

// ---- epilogue: max_k relu(bn(h)) = relu(bn(slope>=0 ? hmax : hmin)); fp32 out, same layout
__global__ __launch_bounds__(256) void k_postmax(const float* __restrict__ hmax, const float* __restrict__ hmin,
                          const float* __restrict__ mean, const float* __restrict__ rstd,
                          const float* __restrict__ g, const float* __restrict__ bb,
                          int O, int total, float* __restrict__ out){
  int i = blockIdx.x*blockDim.x + threadIdx.x;
  if(i>=total) return;
  int o = i % O;
  float sc = rstd[o]*g[o];
  float h = (sc>=0.f) ? hmax[i] : hmin[i];
  float v = (h-mean[o])*sc + bb[o];
  out[i] = v>0.f ? v : 0.f;
}

// ---- final epilogue with [B,S1,256] -> [B,256,S1] transpose, fp32 out
__global__ __launch_bounds__(256) void k_postmax_out(const float* __restrict__ hmax, const float* __restrict__ hmin,
                              const float* __restrict__ mean, const float* __restrict__ rstd,
                              const float* __restrict__ g, const float* __restrict__ bb,
                              float* __restrict__ out){
  int i = blockIdx.x*blockDim.x + threadIdx.x;
  if(i >= BATCH*NS1*256) return;
  int o = i & 255;
  int s = (i>>8) & (NS1-1);
  int b = i >> 15;
  float sc = rstd[o]*g[o];
  float h = (sc>=0.f) ? hmax[i] : hmin[i];
  float v = (h-mean[o])*sc + bb[o];
  v = v>0.f ? v : 0.f;
  out[((size_t)b*256 + o)*NS1 + s] = v;
}

extern "C" void kernel_launch(void* const* d_in, const int* in_sizes, int n_in,
                              void* d_out, int out_size, void* d_ws, size_t ws_size,
                              hipStream_t stream){
  const float* x    = (const float*)d_in[0];
  const float* w1   = (const float*)d_in[1];
  const float* g1   = (const float*)d_in[2];
  const float* b1   = (const float*)d_in[3];
  const float* w2   = (const float*)d_in[4];
  const float* g2   = (const float*)d_in[5];
  const float* b2   = (const float*)d_in[6];
  const float* wsg0 = (const float*)d_in[7];
  const float* gsg0 = (const float*)d_in[8];
  const float* bsg0 = (const float*)d_in[9];
  const float* wsg1 = (const float*)d_in[10];
  const float* gsg1 = (const float*)d_in[11];
  const float* bsg1 = (const float*)d_in[12];
  float* out = (float*)d_out;

  // workspace carve-up (fp32 elements); total ~37 MB
  float* wsf = (float*)d_ws;
  float* coords = wsf;                    wsf += BATCH*NPTS*3;
  float* t1     = wsf;                    wsf += BATCH*NPTS*64;
  float* t2     = wsf;                    wsf += BATCH*NPTS*64;
  float* mean1=wsf;  wsf+=64;  float* rstd1=wsf;  wsf+=64;
  float* mean2=wsf;  wsf+=64;  float* rstd2=wsf;  wsf+=64;
  float* meanS0=wsf; wsf+=128; float* rstdS0=wsf; wsf+=128;
  float* meanS1=wsf; wsf+=256; float* rstdS1=wsf; wsf+=256;
  int*   fps0 = (int*)wsf;                wsf += BATCH*NS0;
  float* xyz0 = wsf;                      wsf += BATCH*NS0*3;
  int*   knn0 = (int*)wsf;                wsf += BATCH*NS0*KK;
  float* hmax0= wsf;                      wsf += BATCH*NS0*128;
  float* hmin0= wsf;                      wsf += BATCH*NS0*128;
  float* part0= wsf;                      wsf += BATCH*NS0*2*128;
  float* f1   = wsf;                      wsf += BATCH*NS0*128;
  int*   fps1 = (int*)wsf;                wsf += BATCH*NS1;
  float* xyz1 = wsf;                      wsf += BATCH*NS1*3;
  int*   knn1 = (int*)wsf;                wsf += BATCH*NS1*KK;
  float* hmax1= wsf;                      wsf += BATCH*NS1*256;
  float* hmin1= wsf;                      wsf += BATCH*NS1*256;
  float* part1= wsf;                      wsf += BATCH*NS1*2*256;

  // embed MLP (two 1x1 convs with training-mode BN)
  k_embed1<<<dim3(128), dim3(256), 0, stream>>>(x, w1, coords, t1);
  k_stats <<<dim3(64),  dim3(256), 0, stream>>>(t1, BATCH*NPTS, 64, mean1, rstd1);
  k_embed2<<<dim3(512), dim3(256), 0, stream>>>(t1, w2, mean1, rstd1, g1, b1, t2);
  k_stats <<<dim3(64),  dim3(256), 0, stream>>>(t2, BATCH*NPTS, 64, mean2, rstd2);
  k_bnrelu<<<dim3(8192),dim3(256), 0, stream>>>(t2, BATCH*NPTS*64, 64, mean2, rstd2, g2, b2);

  // SG block 0: N=2048 -> S0=256, C=64 -> O=128
  k_fps<NPTS,NS0,256><<<dim3(BATCH),     dim3(256), 0, stream>>>(coords, fps0, xyz0);
  k_knn<NPTS,256>    <<<dim3(BATCH*NS0), dim3(256), 0, stream>>>(coords, xyz0, NS0, knn0);
  k_sg_pass1<64,NPTS><<<dim3(BATCH*NS0), dim3(128), 0, stream>>>(t2, knn0, fps0, wsg0, hmax0, hmin0, part0, NS0);
  k_reduce           <<<dim3(128),       dim3(256), 0, stream>>>(part0, BATCH*NS0, 128, BATCH*NS0*KK, meanS0, rstdS0);
  k_postmax          <<<dim3(2048),      dim3(256), 0, stream>>>(hmax0, hmin0, meanS0, rstdS0, gsg0, bsg0,
                                                                 128, BATCH*NS0*128, f1);

  // SG block 1: S0=256 -> S1=128, C=128 -> O=256
  k_fps<NS0,NS1,256> <<<dim3(BATCH),     dim3(256), 0, stream>>>(xyz0, fps1, xyz1);
  k_knn<NS0,256>     <<<dim3(BATCH*NS1), dim3(256), 0, stream>>>(xyz0, xyz1, NS1, knn1);
  k_sg_pass1<128,NS0><<<dim3(BATCH*NS1), dim3(256), 0, stream>>>(f1, knn1, fps1, wsg1, hmax1, hmin1, part1, NS1);
  k_reduce           <<<dim3(256),       dim3(256), 0, stream>>>(part1, BATCH*NS1, 256, BATCH*NS1*KK, meanS1, rstdS1);
  k_postmax_out      <<<dim3(2048),      dim3(256), 0, stream>>>(hmax1, hmin1, meanS1, rstdS1, gsg1, bsg1, out);
}

// Round 5
// 847.031 us; speedup vs baseline: 3.0121x; 1.4215x over previous
//
#include <hip/hip_runtime.h>
#include <float.h>

#define BATCH 16
#define NPTS  2048
#define NS0   256
#define NS1   128
#define KK    32
#define EPSV  1e-5f

// exact numpy-order squared distance: ((dx*dx + dy*dy) + dz*dz), no FMA contraction
__device__ __forceinline__ float sqdist(float ax,float ay,float az,float bx,float by,float bz){
  float dx=__fsub_rn(ax,bx), dy=__fsub_rn(ay,by), dz=__fsub_rn(az,bz);
  return __fadd_rn(__fadd_rn(__fmul_rn(dx,dx),__fmul_rn(dy,dy)),__fmul_rn(dz,dz));
}

// ---- embed layer 1: transpose x [B,3,N] -> coords [B,N,3], t1 = coords @ w1^T  ([B,N,64])
__global__ __launch_bounds__(256) void k_embed1(const float* __restrict__ x, const float* __restrict__ w1,
                         float* __restrict__ coords, float* __restrict__ t1){
  __shared__ float w[64*3];
  int tid = threadIdx.x;
  if (tid < 192) w[tid] = w1[tid];
  __syncthreads();
  int gid = blockIdx.x*blockDim.x + tid;
  if (gid >= BATCH*NPTS) return;
  int b = gid / NPTS, n = gid % NPTS;
  float cx = x[(b*3+0)*NPTS + n];
  float cy = x[(b*3+1)*NPTS + n];
  float cz = x[(b*3+2)*NPTS + n];
  coords[gid*3+0]=cx; coords[gid*3+1]=cy; coords[gid*3+2]=cz;
  float* o = t1 + (size_t)gid*64;
  #pragma unroll
  for(int j=0;j<64;j++) o[j] = cx*w[j*3+0] + cy*w[j*3+1] + cz*w[j*3+2];
}

// ---- per-channel mean/rstd over M rows of [M][C]
__global__ __launch_bounds__(256) void k_stats(const float* __restrict__ t, int M, int C,
                        float* __restrict__ mean, float* __restrict__ rstd){
  int c = blockIdx.x, tid = threadIdx.x;
  float s=0.f, s2=0.f;
  for(int r=tid; r<M; r+=blockDim.x){ float v = t[(size_t)r*C+c]; s+=v; s2+=v*v; }
  __shared__ float bs[256], bq[256];
  bs[tid]=s; bq[tid]=s2; __syncthreads();
  for(int st=128; st>0; st>>=1){ if(tid<st){ bs[tid]+=bs[tid+st]; bq[tid]+=bq[tid+st]; } __syncthreads(); }
  if(tid==0){
    float m = bs[0]/M;
    float v = bq[0]/M - m*m; if(v<0.f) v=0.f;
    mean[c]=m; rstd[c]=rsqrtf(v+EPSV);
  }
}

// ---- embed layer 2: t2 = relu(bn(t1)) @ w2^T  (64x64), 64 points per block
__global__ __launch_bounds__(256, 1) void k_embed2(const float* __restrict__ t1, const float* __restrict__ w2,
                         const float* __restrict__ mean1, const float* __restrict__ rstd1,
                         const float* __restrict__ g1, const float* __restrict__ b1,
                         float* __restrict__ t2){
  __shared__ __align__(16) float fin[64][64];
  __shared__ float sm[64], sr[64], sg[64], sb[64];
  int tid = threadIdx.x;
  if (tid<64){ sm[tid]=mean1[tid]; sr[tid]=rstd1[tid]; sg[tid]=g1[tid]; sb[tid]=b1[tid]; }
  __syncthreads();
  int base = blockIdx.x*64;
  for(int i=tid;i<4096;i+=256){
    int p=i>>6, c=i&63;
    float v = t1[(size_t)(base+p)*64 + c];
    v = (v - sm[c])*sr[c]*sg[c] + sb[c];
    fin[p][c] = v>0.f ? v : 0.f;
  }
  __syncthreads();
  int o = tid & 63, p0 = tid>>6;
  float acc[16];
  #pragma unroll
  for(int i=0;i<16;i++) acc[i]=0.f;
  for(int cc=0; cc<64; cc+=4){
    float4 wv = *(const float4*)(w2 + o*64 + cc);
    #pragma unroll
    for(int i=0;i<16;i++){
      float4 f4 = *(const float4*)&fin[p0 + i*4][cc];
      acc[i] += f4.x*wv.x + f4.y*wv.y + f4.z*wv.z + f4.w*wv.w;
    }
  }
  #pragma unroll
  for(int i=0;i<16;i++) t2[(size_t)(base+p0+i*4)*64 + o] = acc[i];
}

// ---- elementwise bn+relu in place
__global__ __launch_bounds__(256) void k_bnrelu(float* __restrict__ t, int total, int C,
                         const float* __restrict__ mean, const float* __restrict__ rstd,
                         const float* __restrict__ g, const float* __restrict__ b){
  int i = blockIdx.x*blockDim.x + threadIdx.x;
  if(i>=total) return;
  int c = i % C;
  float v = t[i];
  v = (v-mean[c])*rstd[c]*g[c] + b[c];
  t[i] = v>0.f ? v : 0.f;
}

// ---- weight transpose: wt[c][o] = w[o][c], square OxO
__global__ __launch_bounds__(256) void k_wt(const float* __restrict__ w, float* __restrict__ wt, int O){
  int gid = blockIdx.x*blockDim.x + threadIdx.x;
  if(gid >= O*O) return;
  int o = gid % O, c = gid / O;
  wt[gid] = w[o*O + c];
}

// ---- farthest point sampling, one block per batch; 1 barrier/iter via double-buffered partials
template<int P, int S, int T>
__global__ __launch_bounds__(T) void k_fps(const float* __restrict__ pts, int* __restrict__ outIdx,
                      float* __restrict__ outXyz){
  constexpr int PPT = P/T;
  constexpr int NW = T/64;
  int b = blockIdx.x, tid = threadIdx.x;
  const float* p = pts + (size_t)b*P*3;
  float px[PPT], py[PPT], pz[PPT], dist[PPT];
  #pragma unroll
  for(int i=0;i<PPT;i++){
    int n = tid*PPT + i;
    px[i]=p[n*3]; py[i]=p[n*3+1]; pz[i]=p[n*3+2];
    dist[i]=1e10f;
  }
  __shared__ float rv[2][NW];
  __shared__ int   ri[2][NW];
  int cur = 0;
  for(int s=0;s<S;s++){
    if(tid==0){
      outIdx[b*S+s]=cur;
      outXyz[((size_t)b*S+s)*3+0]=p[cur*3+0];
      outXyz[((size_t)b*S+s)*3+1]=p[cur*3+1];
      outXyz[((size_t)b*S+s)*3+2]=p[cur*3+2];
    }
    if(s==S-1) break;
    float cx=p[cur*3], cy=p[cur*3+1], cz=p[cur*3+2];
    float bv=-FLT_MAX; int bi=0;
    #pragma unroll
    for(int i=0;i<PPT;i++){
      float d = sqdist(px[i],py[i],pz[i],cx,cy,cz);
      float nd = fminf(dist[i], d);
      dist[i]=nd;
      if(nd>bv){ bv=nd; bi=tid*PPT+i; }   // ascending n => strict '>' keeps lowest idx on tie
    }
    #pragma unroll
    for(int off=32; off>0; off>>=1){
      float ov=__shfl_down(bv,off);
      int   oi=__shfl_down(bi,off);
      if(ov>bv || (ov==bv && oi<bi)){ bv=ov; bi=oi; }
    }
    int sl = s & 1;
    if((tid&63)==0){ rv[sl][tid>>6]=bv; ri[sl][tid>>6]=bi; }
    __syncthreads();
    float xv=rv[sl][0]; int xi=ri[sl][0];
    #pragma unroll
    for(int w=1;w<NW;w++) if(rv[sl][w]>xv || (rv[sl][w]==xv && ri[sl][w]<xi)){ xv=rv[sl][w]; xi=ri[sl][w]; }
    cur = xi;    // computed redundantly by all threads; no second barrier
  }
}

// ---- exact 32-NN per query, one WAVE per query: barrier-light shuffle argmin
template<int P>
__global__ __launch_bounds__(64) void k_knn(const float* __restrict__ pts, const float* __restrict__ q,
                      int S, int* __restrict__ knn){
  int bq = blockIdx.x, lane = threadIdx.x;
  int b = bq / S;
  __shared__ float d2[P];
  const float* p = pts + (size_t)b*P*3;
  float qx=q[(size_t)bq*3], qy=q[(size_t)bq*3+1], qz=q[(size_t)bq*3+2];
  for(int n=lane;n<P;n+=64) d2[n] = sqdist(qx,qy,qz,p[n*3],p[n*3+1],p[n*3+2]);
  __syncthreads();
  for(int j=0;j<KK;j++){
    float bv=FLT_MAX; int bi=P;
    for(int n=lane;n<P;n+=64){ float v=d2[n]; if(v<bv){ bv=v; bi=n; } }  // ascending n => lowest idx on tie
    #pragma unroll
    for(int off=32; off>0; off>>=1){
      float ov=__shfl_down(bv,off);
      int   oi=__shfl_down(bi,off);
      if(ov<bv || (ov==bv && oi<bi)){ bv=ov; bi=oi; }
    }
    bi = __shfl(bi, 0);
    if(lane==0){ knn[(size_t)bq*KK+j]=bi; d2[bi]=FLT_MAX; }
    __syncthreads();   // single wave: cheap; orders the d2 update
  }
}

// ---- sg-block pass1 v3: register-tiled outer-product GEMM on transposed weights.
//      Stage gd = g - c in LDS; h[k][o] = dot(gd[k], w_lo[o]) + ct[o], ct[o] = dot(c, w_hi[o]).
//      Thread tile 8k x 8o; WT is [2C][O] (c-major) so weight loads are coalesced.
template<int C, int P>
__global__ __launch_bounds__(2*C/2, 2) void k_sg_pass1(
                           const float* __restrict__ feats, const int* __restrict__ knn,
                           const int* __restrict__ fpsIdx, const float* __restrict__ WT,
                           float* __restrict__ hmax, float* __restrict__ hmin,
                           float* __restrict__ part, int S){
  constexpr int O   = 2*C;
  constexpr int TPB = O/2;           // 64 (C=64) or 128 (C=128)
  constexpr int C4  = C/4;
  constexpr int OG  = O/8;           // # of o-groups
  constexpr int LDC = C+4;           // padded LDS row
  __shared__ __align__(16) float gfp[KK*LDC];
  __shared__ __align__(16) float cf[C];
  __shared__ float sct[O];
  __shared__ float smx[4][O], smn[4][O], ssm[4][O], ssq[4][O];
  int bq = blockIdx.x, tid = threadIdx.x;
  int b = bq / S;
  const float* fb = feats + (size_t)b*P*C;
  int ci = fpsIdx[bq];
  const float* cfg = fb + (size_t)ci*C;
  cf[tid % C] = cfg[tid % C];                       // TPB >= C; duplicate writes OK (same value)
  for(int i=tid; i<KK*C4; i+=TPB){
    int k = i/C4, d4 = i - k*C4;
    float4 g = ((const float4*)(fb + (size_t)knn[(size_t)bq*KK+k]*C))[d4];
    float4 c = ((const float4*)cfg)[d4];
    float4 r; r.x=g.x-c.x; r.y=g.y-c.y; r.z=g.z-c.z; r.w=g.w-c.w;
    *(float4*)&gfp[k*LDC + d4*4] = r;
  }
  __syncthreads();
  // ct[o] = dot(cf, w_hi[o]) for 2 o's per thread (coalesced float2 on WT hi rows)
  {
    int o2 = tid*2;
    float ct0=0.f, ct1=0.f;
    for(int c=0;c<C;c+=4){
      float4 c4 = *(const float4*)&cf[c];
      #pragma unroll
      for(int t=0;t<4;t++){
        float cv = ((const float*)&c4)[t];
        float2 wh = *(const float2*)&WT[(size_t)(C+c+t)*O + o2];
        ct0 += cv*wh.x; ct1 += cv*wh.y;
      }
    }
    sct[o2]=ct0; sct[o2+1]=ct1;
  }
  __syncthreads();
  // main GEMM: thread (kg, og) computes acc[8k][8o]
  int kg = tid / OG;                 // 0..3
  int og = tid % OG;                 // 0..OG-1
  float acc[8][8];
  #pragma unroll
  for(int a=0;a<8;a++)
    #pragma unroll
    for(int bb2=0;bb2<8;bb2++) acc[a][bb2]=0.f;
  for(int dc=0; dc<C4; dc++){
    float4 g4[8];
    #pragma unroll
    for(int jk=0;jk<8;jk++) g4[jk] = *(const float4*)&gfp[(kg*8+jk)*LDC + dc*4];
    #pragma unroll
    for(int t=0;t<4;t++){
      const float* wrow = WT + (size_t)(dc*4+t)*O + og*8;
      float4 wa = *(const float4*)wrow;
      float4 wb = *(const float4*)(wrow+4);
      #pragma unroll
      for(int jk=0;jk<8;jk++){
        float gs = ((const float*)&g4[jk])[t];
        acc[jk][0] += gs*wa.x; acc[jk][1] += gs*wa.y; acc[jk][2] += gs*wa.z; acc[jk][3] += gs*wa.w;
        acc[jk][4] += gs*wb.x; acc[jk][5] += gs*wb.y; acc[jk][6] += gs*wb.z; acc[jk][7] += gs*wb.w;
      }
    }
  }
  // per-kg partial stats
  #pragma unroll
  for(int jo=0;jo<8;jo++){
    int o = og*8+jo;
    float ct = sct[o];
    float s=0.f,q=0.f,mx=-FLT_MAX,mn=FLT_MAX;
    #pragma unroll
    for(int jk=0;jk<8;jk++){
      float h = acc[jk][jo] + ct;
      s+=h; q+=h*h; mx=fmaxf(mx,h); mn=fminf(mn,h);
    }
    smx[kg][o]=mx; smn[kg][o]=mn; ssm[kg][o]=s; ssq[kg][o]=q;
  }
  __syncthreads();
  // finalize 2 o's per thread
  #pragma unroll
  for(int oo=0;oo<2;oo++){
    int o = tid*2+oo;
    float mx=smx[0][o], mn=smn[0][o], s=ssm[0][o], q=ssq[0][o];
    #pragma unroll
    for(int g=1;g<4;g++){
      mx=fmaxf(mx,smx[g][o]); mn=fminf(mn,smn[g][o]); s+=ssm[g][o]; q+=ssq[g][o];
    }
    hmax[(size_t)bq*O+o]=mx; hmin[(size_t)bq*O+o]=mn;
    part[(size_t)bq*2*O+o]=s; part[(size_t)bq*2*O+O+o]=q;
  }
}

// ---- reduce per-block partials -> per-channel mean/rstd
__global__ __launch_bounds__(256) void k_reduce(const float* __restrict__ part, int nblk, int O, int M,
                         float* __restrict__ mean, float* __restrict__ rstd){
  int o = blockIdx.x, tid = threadIdx.x;
  float s=0.f, s2=0.f;
  for(int i=tid;i<nblk;i+=blockDim.x){ s += part[(size_t)i*2*O + o]; s2 += part[(size_t)i*2*O + O + o]; }
  __shared__ float bs[256], bq[256];
  bs[tid]=s; bq[tid]=s2; __syncthreads();
  for(int st=128; st>0; st>>=1){ if(tid<st){ bs[tid]+=bs[tid+st]; bq[tid]+=bq[tid+st]; } __syncthreads(); }
  if(tid==0){
    float m = bs[0]/M;
    float v = bq[0]/M - m*m; if(v<0.f) v=0.f;
    mean[o]=m; rstd[o]=rsqrtf(v+EPSV);
  }
}

// ---- epilogue: max_k relu(bn(h)) = relu(bn(slope>=0 ? hmax : hmin)); fp32 out, same layout
__global__ __launch_bounds__(256) void k_postmax(const float* __restrict__ hmax, const float* __restrict__ hmin,
                          const float* __restrict__ mean, const float* __restrict__ rstd,
                          const float* __restrict__ g, const float* __restrict__ bb,
                          int O, int total, float* __restrict__ out){
  int i = blockIdx.x*blockDim.x + threadIdx.x;
  if(i>=total) return;
  int o = i % O;
  float sc = rstd[o]*g[o];
  float h = (sc>=0.f) ? hmax[i] : hmin[i];
  float v = (h-mean[o])*sc + bb[o];
  out[i] = v>0.f ? v : 0.f;
}

// ---- final epilogue with [B,S1,256] -> [B,256,S1] transpose, fp32 out
__global__ __launch_bounds__(256) void k_postmax_out(const float* __restrict__ hmax, const float* __restrict__ hmin,
                              const float* __restrict__ mean, const float* __restrict__ rstd,
                              const float* __restrict__ g, const float* __restrict__ bb,
                              float* __restrict__ out){
  int i = blockIdx.x*blockDim.x + threadIdx.x;
  if(i >= BATCH*NS1*256) return;
  int o = i & 255;
  int s = (i>>8) & (NS1-1);
  int b = i >> 15;
  float sc = rstd[o]*g[o];
  float h = (sc>=0.f) ? hmax[i] : hmin[i];
  float v = (h-mean[o])*sc + bb[o];
  v = v>0.f ? v : 0.f;
  out[((size_t)b*256 + o)*NS1 + s] = v;
}

extern "C" void kernel_launch(void* const* d_in, const int* in_sizes, int n_in,
                              void* d_out, int out_size, void* d_ws, size_t ws_size,
                              hipStream_t stream){
  const float* x    = (const float*)d_in[0];
  const float* w1   = (const float*)d_in[1];
  const float* g1   = (const float*)d_in[2];
  const float* b1   = (const float*)d_in[3];
  const float* w2   = (const float*)d_in[4];
  const float* g2   = (const float*)d_in[5];
  const float* b2   = (const float*)d_in[6];
  const float* wsg0 = (const float*)d_in[7];
  const float* gsg0 = (const float*)d_in[8];
  const float* bsg0 = (const float*)d_in[9];
  const float* wsg1 = (const float*)d_in[10];
  const float* gsg1 = (const float*)d_in[11];
  const float* bsg1 = (const float*)d_in[12];
  float* out = (float*)d_out;

  float* wsf = (float*)d_ws;
  float* coords = wsf;                    wsf += BATCH*NPTS*3;
  float* t1     = wsf;                    wsf += BATCH*NPTS*64;
  float* t2     = wsf;                    wsf += BATCH*NPTS*64;
  float* mean1=wsf;  wsf+=64;  float* rstd1=wsf;  wsf+=64;
  float* mean2=wsf;  wsf+=64;  float* rstd2=wsf;  wsf+=64;
  float* meanS0=wsf; wsf+=128; float* rstdS0=wsf; wsf+=128;
  float* meanS1=wsf; wsf+=256; float* rstdS1=wsf; wsf+=256;
  int*   fps0 = (int*)wsf;                wsf += BATCH*NS0;
  float* xyz0 = wsf;                      wsf += BATCH*NS0*3;
  int*   knn0 = (int*)wsf;                wsf += BATCH*NS0*KK;
  float* hmax0= wsf;                      wsf += BATCH*NS0*128;
  float* hmin0= wsf;                      wsf += BATCH*NS0*128;
  float* part0= wsf;                      wsf += BATCH*NS0*2*128;
  float* f1   = wsf;                      wsf += BATCH*NS0*128;
  int*   fps1 = (int*)wsf;                wsf += BATCH*NS1;
  float* xyz1 = wsf;                      wsf += BATCH*NS1*3;
  int*   knn1 = (int*)wsf;                wsf += BATCH*NS1*KK;
  float* hmax1= wsf;                      wsf += BATCH*NS1*256;
  float* hmin1= wsf;                      wsf += BATCH*NS1*256;
  float* part1= wsf;                      wsf += BATCH*NS1*2*256;
  float* wt0  = wsf;                      wsf += 128*128;
  float* wt1  = wsf;                      wsf += 256*256;

  // weight transposes (no deps; run first)
  k_wt<<<dim3((128*128+255)/256), dim3(256), 0, stream>>>(wsg0, wt0, 128);
  k_wt<<<dim3((256*256+255)/256), dim3(256), 0, stream>>>(wsg1, wt1, 256);

  // embed MLP (two 1x1 convs with training-mode BN)
  k_embed1<<<dim3(128), dim3(256), 0, stream>>>(x, w1, coords, t1);
  k_stats <<<dim3(64),  dim3(256), 0, stream>>>(t1, BATCH*NPTS, 64, mean1, rstd1);
  k_embed2<<<dim3(512), dim3(256), 0, stream>>>(t1, w2, mean1, rstd1, g1, b1, t2);
  k_stats <<<dim3(64),  dim3(256), 0, stream>>>(t2, BATCH*NPTS, 64, mean2, rstd2);
  k_bnrelu<<<dim3(8192),dim3(256), 0, stream>>>(t2, BATCH*NPTS*64, 64, mean2, rstd2, g2, b2);

  // SG block 0: N=2048 -> S0=256, C=64 -> O=128
  k_fps<NPTS,NS0,256><<<dim3(BATCH),     dim3(256), 0, stream>>>(coords, fps0, xyz0);
  k_knn<NPTS>        <<<dim3(BATCH*NS0), dim3(64),  0, stream>>>(coords, xyz0, NS0, knn0);
  k_sg_pass1<64,NPTS><<<dim3(BATCH*NS0), dim3(64),  0, stream>>>(t2, knn0, fps0, wt0, hmax0, hmin0, part0, NS0);
  k_reduce           <<<dim3(128),       dim3(256), 0, stream>>>(part0, BATCH*NS0, 128, BATCH*NS0*KK, meanS0, rstdS0);
  k_postmax          <<<dim3(2048),      dim3(256), 0, stream>>>(hmax0, hmin0, meanS0, rstdS0, gsg0, bsg0,
                                                                 128, BATCH*NS0*128, f1);

  // SG block 1: S0=256 -> S1=128, C=128 -> O=256
  k_fps<NS0,NS1,256> <<<dim3(BATCH),     dim3(256), 0, stream>>>(xyz0, fps1, xyz1);
  k_knn<NS0>         <<<dim3(BATCH*NS1), dim3(64),  0, stream>>>(xyz0, xyz1, NS1, knn1);
  k_sg_pass1<128,NS0><<<dim3(BATCH*NS1), dim3(128), 0, stream>>>(f1, knn1, fps1, wt1, hmax1, hmin1, part1, NS1);
  k_reduce           <<<dim3(256),       dim3(256), 0, stream>>>(part1, BATCH*NS1, 256, BATCH*NS1*KK, meanS1, rstdS1);
  k_postmax_out      <<<dim3(2048),      dim3(256), 0, stream>>>(hmax1, hmin1, meanS1, rstdS1, gsg1, bsg1, out);
}

// Round 6
// 820.914 us; speedup vs baseline: 3.1079x; 1.0318x over previous
//
#include <hip/hip_runtime.h>
#include <float.h>

#define BATCH 16
#define NPTS  2048
#define NS0   256
#define NS1   128
#define KK    32
#define EPSV  1e-5f

// exact numpy-order squared distance: ((dx*dx + dy*dy) + dz*dz), no FMA contraction
__device__ __forceinline__ float sqdist(float ax,float ay,float az,float bx,float by,float bz){
  float dx=__fsub_rn(ax,bx), dy=__fsub_rn(ay,by), dz=__fsub_rn(az,bz);
  return __fadd_rn(__fadd_rn(__fmul_rn(dx,dx),__fmul_rn(dy,dy)),__fmul_rn(dz,dz));
}

// ---- embed layer 1: transpose x [B,3,N] -> coords [B,N,3], t1 = coords @ w1^T  ([B,N,64])
__global__ __launch_bounds__(256) void k_embed1(const float* __restrict__ x, const float* __restrict__ w1,
                         float* __restrict__ coords, float* __restrict__ t1){
  __shared__ float w[64*3];
  int tid = threadIdx.x;
  if (tid < 192) w[tid] = w1[tid];
  __syncthreads();
  int gid = blockIdx.x*blockDim.x + tid;
  if (gid >= BATCH*NPTS) return;
  int b = gid / NPTS, n = gid % NPTS;
  float cx = x[(b*3+0)*NPTS + n];
  float cy = x[(b*3+1)*NPTS + n];
  float cz = x[(b*3+2)*NPTS + n];
  coords[gid*3+0]=cx; coords[gid*3+1]=cy; coords[gid*3+2]=cz;
  float* o = t1 + (size_t)gid*64;
  #pragma unroll
  for(int j=0;j<64;j++) o[j] = cx*w[j*3+0] + cy*w[j*3+1] + cz*w[j*3+2];
}

// ---- per-channel mean/rstd over M rows of [M][C]
__global__ __launch_bounds__(256) void k_stats(const float* __restrict__ t, int M, int C,
                        float* __restrict__ mean, float* __restrict__ rstd){
  int c = blockIdx.x, tid = threadIdx.x;
  float s=0.f, s2=0.f;
  for(int r=tid; r<M; r+=blockDim.x){ float v = t[(size_t)r*C+c]; s+=v; s2+=v*v; }
  __shared__ float bs[256], bq[256];
  bs[tid]=s; bq[tid]=s2; __syncthreads();
  for(int st=128; st>0; st>>=1){ if(tid<st){ bs[tid]+=bs[tid+st]; bq[tid]+=bq[tid+st]; } __syncthreads(); }
  if(tid==0){
    float m = bs[0]/M;
    float v = bq[0]/M - m*m; if(v<0.f) v=0.f;
    mean[c]=m; rstd[c]=rsqrtf(v+EPSV);
  }
}

// ---- embed layer 2: t2 = relu(bn(t1)) @ w2^T  (64x64), 64 points per block
__global__ __launch_bounds__(256, 1) void k_embed2(const float* __restrict__ t1, const float* __restrict__ w2,
                         const float* __restrict__ mean1, const float* __restrict__ rstd1,
                         const float* __restrict__ g1, const float* __restrict__ b1,
                         float* __restrict__ t2){
  __shared__ __align__(16) float fin[64][64];
  __shared__ float sm[64], sr[64], sg[64], sb[64];
  int tid = threadIdx.x;
  if (tid<64){ sm[tid]=mean1[tid]; sr[tid]=rstd1[tid]; sg[tid]=g1[tid]; sb[tid]=b1[tid]; }
  __syncthreads();
  int base = blockIdx.x*64;
  for(int i=tid;i<4096;i+=256){
    int p=i>>6, c=i&63;
    float v = t1[(size_t)(base+p)*64 + c];
    v = (v - sm[c])*sr[c]*sg[c] + sb[c];
    fin[p][c] = v>0.f ? v : 0.f;
  }
  __syncthreads();
  int o = tid & 63, p0 = tid>>6;
  float acc[16];
  #pragma unroll
  for(int i=0;i<16;i++) acc[i]=0.f;
  for(int cc=0; cc<64; cc+=4){
    float4 wv = *(const float4*)(w2 + o*64 + cc);
    #pragma unroll
    for(int i=0;i<16;i++){
      float4 f4 = *(const float4*)&fin[p0 + i*4][cc];
      acc[i] += f4.x*wv.x + f4.y*wv.y + f4.z*wv.z + f4.w*wv.w;
    }
  }
  #pragma unroll
  for(int i=0;i<16;i++) t2[(size_t)(base+p0+i*4)*64 + o] = acc[i];
}

// ---- elementwise bn+relu in place
__global__ __launch_bounds__(256) void k_bnrelu(float* __restrict__ t, int total, int C,
                         const float* __restrict__ mean, const float* __restrict__ rstd,
                         const float* __restrict__ g, const float* __restrict__ b){
  int i = blockIdx.x*blockDim.x + threadIdx.x;
  if(i>=total) return;
  int c = i % C;
  float v = t[i];
  v = (v-mean[c])*rstd[c]*g[c] + b[c];
  t[i] = v>0.f ? v : 0.f;
}

// ---- weight transpose: wt[c][o] = w[o][c], square OxO
__global__ __launch_bounds__(256) void k_wt(const float* __restrict__ w, float* __restrict__ wt, int O){
  int gid = blockIdx.x*blockDim.x + threadIdx.x;
  if(gid >= O*O) return;
  int o = gid % O, c = gid / O;
  wt[gid] = w[o*O + c];
}

// ---- farthest point sampling v3: zero VMEM inside the serial loop.
//      Points staged in LDS; centroid fetched from LDS; outputs buffered in LDS, written once.
template<int P, int S, int T>
__global__ __launch_bounds__(T, 1) void k_fps(const float* __restrict__ pts, int* __restrict__ outIdx,
                      float* __restrict__ outXyz){
  constexpr int PPT = P/T;
  constexpr int NW  = T/64;
  __shared__ float sx[P], sy[P], sz[P];
  __shared__ float rv[2][NW];
  __shared__ int   ri[2][NW];
  __shared__ int   sidx[S];
  int b = blockIdx.x, tid = threadIdx.x;
  const float* p = pts + (size_t)b*P*3;
  float px[PPT], py[PPT], pz[PPT], dist[PPT];
  #pragma unroll
  for(int i=0;i<PPT;i++){
    int n = i*T + tid;                       // interleaved: coalesced staging
    float X=p[n*3], Y=p[n*3+1], Z=p[n*3+2];
    px[i]=X; py[i]=Y; pz[i]=Z; dist[i]=1e10f;
    sx[n]=X; sy[n]=Y; sz[n]=Z;
  }
  __syncthreads();
  int cur = 0;
  float cx=sx[0], cy=sy[0], cz=sz[0];
  for(int s=0;s<S;s++){
    if(tid==0) sidx[s]=cur;                  // LDS only; read after final barrier
    if(s==S-1) break;
    float bv=-FLT_MAX; int bi=0;
    #pragma unroll
    for(int i=0;i<PPT;i++){
      float d = sqdist(px[i],py[i],pz[i],cx,cy,cz);
      float nd = fminf(dist[i], d);
      dist[i]=nd;
      int n = i*T + tid;                     // ascending within thread => '>' keeps lowest idx
      if(nd>bv){ bv=nd; bi=n; }
    }
    #pragma unroll
    for(int off=32; off>0; off>>=1){
      float ov=__shfl_down(bv,off);
      int   oi=__shfl_down(bi,off);
      if(ov>bv || (ov==bv && oi<bi)){ bv=ov; bi=oi; }
    }
    int sl = s & 1;
    if((tid&63)==0){ rv[sl][tid>>6]=bv; ri[sl][tid>>6]=bi; }
    __syncthreads();
    float xv=rv[sl][0]; int xi=ri[sl][0];
    #pragma unroll
    for(int w=1;w<NW;w++) if(rv[sl][w]>xv || (rv[sl][w]==xv && ri[sl][w]<xi)){ xv=rv[sl][w]; xi=ri[sl][w]; }
    cur = xi;                                // redundant all-thread scan; no 2nd barrier
    cx = sx[cur]; cy = sy[cur]; cz = sz[cur];// LDS, read-only array — race-free
  }
  __syncthreads();
  for(int i=tid; i<S; i+=T){
    int id = sidx[i];
    outIdx[b*S+i] = id;
    outXyz[((size_t)b*S+i)*3+0] = sx[id];
    outXyz[((size_t)b*S+i)*3+1] = sy[id];
    outXyz[((size_t)b*S+i)*3+2] = sz[id];
  }
}

// ---- exact 32-NN per query, one WAVE per query: barrier-light shuffle argmin
template<int P>
__global__ __launch_bounds__(64) void k_knn(const float* __restrict__ pts, const float* __restrict__ q,
                      int S, int* __restrict__ knn){
  int bq = blockIdx.x, lane = threadIdx.x;
  int b = bq / S;
  __shared__ float d2[P];
  const float* p = pts + (size_t)b*P*3;
  float qx=q[(size_t)bq*3], qy=q[(size_t)bq*3+1], qz=q[(size_t)bq*3+2];
  for(int n=lane;n<P;n+=64) d2[n] = sqdist(qx,qy,qz,p[n*3],p[n*3+1],p[n*3+2]);
  __syncthreads();
  for(int j=0;j<KK;j++){
    float bv=FLT_MAX; int bi=P;
    for(int n=lane;n<P;n+=64){ float v=d2[n]; if(v<bv){ bv=v; bi=n; } }  // ascending n => lowest idx on tie
    #pragma unroll
    for(int off=32; off>0; off>>=1){
      float ov=__shfl_down(bv,off);
      int   oi=__shfl_down(bi,off);
      if(ov<bv || (ov==bv && oi<bi)){ bv=ov; bi=oi; }
    }
    bi = __shfl(bi, 0);
    if(lane==0){ knn[(size_t)bq*KK+j]=bi; d2[bi]=FLT_MAX; }
    __syncthreads();   // single wave: cheap; orders the d2 update
  }
}

// ---- sg-block pass1 v3: register-tiled outer-product GEMM on transposed weights.
template<int C, int P>
__global__ __launch_bounds__(2*C/2, 2) void k_sg_pass1(
                           const float* __restrict__ feats, const int* __restrict__ knn,
                           const int* __restrict__ fpsIdx, const float* __restrict__ WT,
                           float* __restrict__ hmax, float* __restrict__ hmin,
                           float* __restrict__ part, int S){
  constexpr int O   = 2*C;
  constexpr int TPB = O/2;           // 64 (C=64) or 128 (C=128)
  constexpr int C4  = C/4;
  constexpr int OG  = O/8;           // # of o-groups
  constexpr int LDC = C+4;           // padded LDS row
  __shared__ __align__(16) float gfp[KK*LDC];
  __shared__ __align__(16) float cf[C];
  __shared__ float sct[O];
  __shared__ float smx[4][O], smn[4][O], ssm[4][O], ssq[4][O];
  int bq = blockIdx.x, tid = threadIdx.x;
  int b = bq / S;
  const float* fb = feats + (size_t)b*P*C;
  int ci = fpsIdx[bq];
  const float* cfg = fb + (size_t)ci*C;
  cf[tid % C] = cfg[tid % C];
  for(int i=tid; i<KK*C4; i+=TPB){
    int k = i/C4, d4 = i - k*C4;
    float4 g = ((const float4*)(fb + (size_t)knn[(size_t)bq*KK+k]*C))[d4];
    float4 c = ((const float4*)cfg)[d4];
    float4 r; r.x=g.x-c.x; r.y=g.y-c.y; r.z=g.z-c.z; r.w=g.w-c.w;
    *(float4*)&gfp[k*LDC + d4*4] = r;
  }
  __syncthreads();
  {
    int o2 = tid*2;
    float ct0=0.f, ct1=0.f;
    for(int c=0;c<C;c+=4){
      float4 c4 = *(const float4*)&cf[c];
      #pragma unroll
      for(int t=0;t<4;t++){
        float cv = ((const float*)&c4)[t];
        float2 wh = *(const float2*)&WT[(size_t)(C+c+t)*O + o2];
        ct0 += cv*wh.x; ct1 += cv*wh.y;
      }
    }
    sct[o2]=ct0; sct[o2+1]=ct1;
  }
  __syncthreads();
  int kg = tid / OG;
  int og = tid % OG;
  float acc[8][8];
  #pragma unroll
  for(int a=0;a<8;a++)
    #pragma unroll
    for(int bb2=0;bb2<8;bb2++) acc[a][bb2]=0.f;
  for(int dc=0; dc<C4; dc++){
    float4 g4[8];
    #pragma unroll
    for(int jk=0;jk<8;jk++) g4[jk] = *(const float4*)&gfp[(kg*8+jk)*LDC + dc*4];
    #pragma unroll
    for(int t=0;t<4;t++){
      const float* wrow = WT + (size_t)(dc*4+t)*O + og*8;
      float4 wa = *(const float4*)wrow;
      float4 wb = *(const float4*)(wrow+4);
      #pragma unroll
      for(int jk=0;jk<8;jk++){
        float gs = ((const float*)&g4[jk])[t];
        acc[jk][0] += gs*wa.x; acc[jk][1] += gs*wa.y; acc[jk][2] += gs*wa.z; acc[jk][3] += gs*wa.w;
        acc[jk][4] += gs*wb.x; acc[jk][5] += gs*wb.y; acc[jk][6] += gs*wb.z; acc[jk][7] += gs*wb.w;
      }
    }
  }
  #pragma unroll
  for(int jo=0;jo<8;jo++){
    int o = og*8+jo;
    float ct = sct[o];
    float s=0.f,q=0.f,mx=-FLT_MAX,mn=FLT_MAX;
    #pragma unroll
    for(int jk=0;jk<8;jk++){
      float h = acc[jk][jo] + ct;
      s+=h; q+=h*h; mx=fmaxf(mx,h); mn=fminf(mn,h);
    }
    smx[kg][o]=mx; smn[kg][o]=mn; ssm[kg][o]=s; ssq[kg][o]=q;
  }
  __syncthreads();
  #pragma unroll
  for(int oo=0;oo<2;oo++){
    int o = tid*2+oo;
    float mx=smx[0][o], mn=smn[0][o], s=ssm[0][o], q=ssq[0][o];
    #pragma unroll
    for(int g=1;g<4;g++){
      mx=fmaxf(mx,smx[g][o]); mn=fminf(mn,smn[g][o]); s+=ssm[g][o]; q+=ssq[g][o];
    }
    hmax[(size_t)bq*O+o]=mx; hmin[(size_t)bq*O+o]=mn;
    part[(size_t)bq*2*O+o]=s; part[(size_t)bq*2*O+O+o]=q;
  }
}

// ---- reduce per-block partials -> per-channel mean/rstd
__global__ __launch_bounds__(256) void k_reduce(const float* __restrict__ part, int nblk, int O, int M,
                         float* __restrict__ mean, float* __restrict__ rstd){
  int o = blockIdx.x, tid = threadIdx.x;
  float s=0.f, s2=0.f;
  for(int i=tid;i<nblk;i+=blockDim.x){ s += part[(size_t)i*2*O + o]; s2 += part[(size_t)i*2*O + O + o]; }
  __shared__ float bs[256], bq[256];
  bs[tid]=s; bq[tid]=s2; __syncthreads();
  for(int st=128; st>0; st>>=1){ if(tid<st){ bs[tid]+=bs[tid+st]; bq[tid]+=bq[tid+st]; } __syncthreads(); }
  if(tid==0){
    float m = bs[0]/M;
    float v = bq[0]/M - m*m; if(v<0.f) v=0.f;
    mean[o]=m; rstd[o]=rsqrtf(v+EPSV);
  }
}

// ---- epilogue: max_k relu(bn(h)) = relu(bn(slope>=0 ? hmax : hmin)); fp32 out, same layout
__global__ __launch_bounds__(256) void k_postmax(const float* __restrict__ hmax, const float* __restrict__ hmin,
                          const float* __restrict__ mean, const float* __restrict__ rstd,
                          const float* __restrict__ g, const float* __restrict__ bb,
                          int O, int total, float* __restrict__ out){
  int i = blockIdx.x*blockDim.x + threadIdx.x;
  if(i>=total) return;
  int o = i % O;
  float sc = rstd[o]*g[o];
  float h = (sc>=0.f) ? hmax[i] : hmin[i];
  float v = (h-mean[o])*sc + bb[o];
  out[i] = v>0.f ? v : 0.f;
}

// ---- final epilogue with [B,S1,256] -> [B,256,S1] transpose, fp32 out
__global__ __launch_bounds__(256) void k_postmax_out(const float* __restrict__ hmax, const float* __restrict__ hmin,
                              const float* __restrict__ mean, const float* __restrict__ rstd,
                              const float* __restrict__ g, const float* __restrict__ bb,
                              float* __restrict__ out){
  int i = blockIdx.x*blockDim.x + threadIdx.x;
  if(i >= BATCH*NS1*256) return;
  int o = i & 255;
  int s = (i>>8) & (NS1-1);
  int b = i >> 15;
  float sc = rstd[o]*g[o];
  float h = (sc>=0.f) ? hmax[i] : hmin[i];
  float v = (h-mean[o])*sc + bb[o];
  v = v>0.f ? v : 0.f;
  out[((size_t)b*256 + o)*NS1 + s] = v;
}

extern "C" void kernel_launch(void* const* d_in, const int* in_sizes, int n_in,
                              void* d_out, int out_size, void* d_ws, size_t ws_size,
                              hipStream_t stream){
  const float* x    = (const float*)d_in[0];
  const float* w1   = (const float*)d_in[1];
  const float* g1   = (const float*)d_in[2];
  const float* b1   = (const float*)d_in[3];
  const float* w2   = (const float*)d_in[4];
  const float* g2   = (const float*)d_in[5];
  const float* b2   = (const float*)d_in[6];
  const float* wsg0 = (const float*)d_in[7];
  const float* gsg0 = (const float*)d_in[8];
  const float* bsg0 = (const float*)d_in[9];
  const float* wsg1 = (const float*)d_in[10];
  const float* gsg1 = (const float*)d_in[11];
  const float* bsg1 = (const float*)d_in[12];
  float* out = (float*)d_out;

  float* wsf = (float*)d_ws;
  float* coords = wsf;                    wsf += BATCH*NPTS*3;
  float* t1     = wsf;                    wsf += BATCH*NPTS*64;
  float* t2     = wsf;                    wsf += BATCH*NPTS*64;
  float* mean1=wsf;  wsf+=64;  float* rstd1=wsf;  wsf+=64;
  float* mean2=wsf;  wsf+=64;  float* rstd2=wsf;  wsf+=64;
  float* meanS0=wsf; wsf+=128; float* rstdS0=wsf; wsf+=128;
  float* meanS1=wsf; wsf+=256; float* rstdS1=wsf; wsf+=256;
  int*   fps0 = (int*)wsf;                wsf += BATCH*NS0;
  float* xyz0 = wsf;                      wsf += BATCH*NS0*3;
  int*   knn0 = (int*)wsf;                wsf += BATCH*NS0*KK;
  float* hmax0= wsf;                      wsf += BATCH*NS0*128;
  float* hmin0= wsf;                      wsf += BATCH*NS0*128;
  float* part0= wsf;                      wsf += BATCH*NS0*2*128;
  float* f1   = wsf;                      wsf += BATCH*NS0*128;
  int*   fps1 = (int*)wsf;                wsf += BATCH*NS1;
  float* xyz1 = wsf;                      wsf += BATCH*NS1*3;
  int*   knn1 = (int*)wsf;                wsf += BATCH*NS1*KK;
  float* hmax1= wsf;                      wsf += BATCH*NS1*256;
  float* hmin1= wsf;                      wsf += BATCH*NS1*256;
  float* part1= wsf;                      wsf += BATCH*NS1*2*256;
  float* wt0  = wsf;                      wsf += 128*128;
  float* wt1  = wsf;                      wsf += 256*256;

  // weight transposes (no deps; run first)
  k_wt<<<dim3((128*128+255)/256), dim3(256), 0, stream>>>(wsg0, wt0, 128);
  k_wt<<<dim3((256*256+255)/256), dim3(256), 0, stream>>>(wsg1, wt1, 256);

  // embed MLP (two 1x1 convs with training-mode BN)
  k_embed1<<<dim3(128), dim3(256), 0, stream>>>(x, w1, coords, t1);
  k_stats <<<dim3(64),  dim3(256), 0, stream>>>(t1, BATCH*NPTS, 64, mean1, rstd1);
  k_embed2<<<dim3(512), dim3(256), 0, stream>>>(t1, w2, mean1, rstd1, g1, b1, t2);
  k_stats <<<dim3(64),  dim3(256), 0, stream>>>(t2, BATCH*NPTS, 64, mean2, rstd2);
  k_bnrelu<<<dim3(8192),dim3(256), 0, stream>>>(t2, BATCH*NPTS*64, 64, mean2, rstd2, g2, b2);

  // SG block 0: N=2048 -> S0=256, C=64 -> O=128
  k_fps<NPTS,NS0,256><<<dim3(BATCH),     dim3(256), 0, stream>>>(coords, fps0, xyz0);
  k_knn<NPTS>        <<<dim3(BATCH*NS0), dim3(64),  0, stream>>>(coords, xyz0, NS0, knn0);
  k_sg_pass1<64,NPTS><<<dim3(BATCH*NS0), dim3(64),  0, stream>>>(t2, knn0, fps0, wt0, hmax0, hmin0, part0, NS0);
  k_reduce           <<<dim3(128),       dim3(256), 0, stream>>>(part0, BATCH*NS0, 128, BATCH*NS0*KK, meanS0, rstdS0);
  k_postmax          <<<dim3(2048),      dim3(256), 0, stream>>>(hmax0, hmin0, meanS0, rstdS0, gsg0, bsg0,
                                                                 128, BATCH*NS0*128, f1);

  // SG block 1: S0=256 -> S1=128, C=128 -> O=256
  k_fps<NS0,NS1,256> <<<dim3(BATCH),     dim3(256), 0, stream>>>(xyz0, fps1, xyz1);
  k_knn<NS0>         <<<dim3(BATCH*NS1), dim3(64),  0, stream>>>(xyz0, xyz1, NS1, knn1);
  k_sg_pass1<128,NS0><<<dim3(BATCH*NS1), dim3(128), 0, stream>>>(f1, knn1, fps1, wt1, hmax1, hmin1, part1, NS1);
  k_reduce           <<<dim3(256),       dim3(256), 0, stream>>>(part1, BATCH*NS1, 256, BATCH*NS1*KK, meanS1, rstdS1);
  k_postmax_out      <<<dim3(2048),      dim3(256), 0, stream>>>(hmax1, hmin1, meanS1, rstdS1, gsg1, bsg1, out);
}

// Round 7
// 633.590 us; speedup vs baseline: 4.0268x; 1.2957x over previous
//
#include <hip/hip_runtime.h>
#include <float.h>

#define BATCH 16
#define NPTS  2048
#define NS0   256
#define NS1   128
#define KK    32
#define EPSV  1e-5f

// exact numpy-order squared distance: ((dx*dx + dy*dy) + dz*dz), no FMA contraction
__device__ __forceinline__ float sqdist(float ax,float ay,float az,float bx,float by,float bz){
  float dx=__fsub_rn(ax,bx), dy=__fsub_rn(ay,by), dz=__fsub_rn(az,bz);
  return __fadd_rn(__fadd_rn(__fmul_rn(dx,dx),__fmul_rn(dy,dy)),__fmul_rn(dz,dz));
}

// ---- DPP wave64 reduce on packed u64 keys (VALU, no LDS). Winner lands in lane 63.
template<int CTRL, int RM>
__device__ __forceinline__ unsigned long long dpp_max_u64(unsigned long long x){
  int lo = __builtin_amdgcn_update_dpp(0, (int)(unsigned)x,        CTRL, RM, 0xf, false);
  int hi = __builtin_amdgcn_update_dpp(0, (int)(unsigned)(x>>32),  CTRL, RM, 0xf, false);
  unsigned long long m = ((unsigned long long)(unsigned)hi<<32) | (unsigned)lo;
  return m > x ? m : x;
}
template<int CTRL, int RM>
__device__ __forceinline__ unsigned long long dpp_min_u64(unsigned long long x){
  int lo = __builtin_amdgcn_update_dpp(-1, (int)(unsigned)x,       CTRL, RM, 0xf, false);
  int hi = __builtin_amdgcn_update_dpp(-1, (int)(unsigned)(x>>32), CTRL, RM, 0xf, false);
  unsigned long long m = ((unsigned long long)(unsigned)hi<<32) | (unsigned)lo;
  return m < x ? m : x;
}
__device__ __forceinline__ unsigned long long wave_max_u64(unsigned long long k){
  k = dpp_max_u64<0x111,0xf>(k);   // row_shr:1
  k = dpp_max_u64<0x112,0xf>(k);   // row_shr:2
  k = dpp_max_u64<0x114,0xf>(k);   // row_shr:4
  k = dpp_max_u64<0x118,0xf>(k);   // row_shr:8
  k = dpp_max_u64<0x142,0xa>(k);   // row_bcast15 -> rows 1,3
  k = dpp_max_u64<0x143,0xc>(k);   // row_bcast31 -> rows 2,3
  unsigned lo = (unsigned)__builtin_amdgcn_readlane((int)(unsigned)k, 63);
  unsigned hi = (unsigned)__builtin_amdgcn_readlane((int)(unsigned)(k>>32), 63);
  return ((unsigned long long)hi<<32) | lo;
}
__device__ __forceinline__ unsigned long long wave_min_u64(unsigned long long k){
  k = dpp_min_u64<0x111,0xf>(k);
  k = dpp_min_u64<0x112,0xf>(k);
  k = dpp_min_u64<0x114,0xf>(k);
  k = dpp_min_u64<0x118,0xf>(k);
  k = dpp_min_u64<0x142,0xa>(k);
  k = dpp_min_u64<0x143,0xc>(k);
  unsigned lo = (unsigned)__builtin_amdgcn_readlane((int)(unsigned)k, 63);
  unsigned hi = (unsigned)__builtin_amdgcn_readlane((int)(unsigned)(k>>32), 63);
  return ((unsigned long long)hi<<32) | lo;
}

// ---- embed layer 1: transpose x [B,3,N] -> coords [B,N,3], t1 = coords @ w1^T  ([B,N,64])
__global__ __launch_bounds__(256) void k_embed1(const float* __restrict__ x, const float* __restrict__ w1,
                         float* __restrict__ coords, float* __restrict__ t1){
  __shared__ float w[64*3];
  int tid = threadIdx.x;
  if (tid < 192) w[tid] = w1[tid];
  __syncthreads();
  int gid = blockIdx.x*blockDim.x + tid;
  if (gid >= BATCH*NPTS) return;
  int b = gid / NPTS, n = gid % NPTS;
  float cx = x[(b*3+0)*NPTS + n];
  float cy = x[(b*3+1)*NPTS + n];
  float cz = x[(b*3+2)*NPTS + n];
  coords[gid*3+0]=cx; coords[gid*3+1]=cy; coords[gid*3+2]=cz;
  float* o = t1 + (size_t)gid*64;
  #pragma unroll
  for(int j=0;j<64;j++) o[j] = cx*w[j*3+0] + cy*w[j*3+1] + cz*w[j*3+2];
}

// ---- per-channel mean/rstd over M rows of [M][C]
__global__ __launch_bounds__(256) void k_stats(const float* __restrict__ t, int M, int C,
                        float* __restrict__ mean, float* __restrict__ rstd){
  int c = blockIdx.x, tid = threadIdx.x;
  float s=0.f, s2=0.f;
  for(int r=tid; r<M; r+=blockDim.x){ float v = t[(size_t)r*C+c]; s+=v; s2+=v*v; }
  __shared__ float bs[256], bq[256];
  bs[tid]=s; bq[tid]=s2; __syncthreads();
  for(int st=128; st>0; st>>=1){ if(tid<st){ bs[tid]+=bs[tid+st]; bq[tid]+=bq[tid+st]; } __syncthreads(); }
  if(tid==0){
    float m = bs[0]/M;
    float v = bq[0]/M - m*m; if(v<0.f) v=0.f;
    mean[c]=m; rstd[c]=rsqrtf(v+EPSV);
  }
}

// ---- embed layer 2: t2 = relu(bn(t1)) @ w2^T  (64x64), 64 points per block
__global__ __launch_bounds__(256, 1) void k_embed2(const float* __restrict__ t1, const float* __restrict__ w2,
                         const float* __restrict__ mean1, const float* __restrict__ rstd1,
                         const float* __restrict__ g1, const float* __restrict__ b1,
                         float* __restrict__ t2){
  __shared__ __align__(16) float fin[64][64];
  __shared__ float sm[64], sr[64], sg[64], sb[64];
  int tid = threadIdx.x;
  if (tid<64){ sm[tid]=mean1[tid]; sr[tid]=rstd1[tid]; sg[tid]=g1[tid]; sb[tid]=b1[tid]; }
  __syncthreads();
  int base = blockIdx.x*64;
  for(int i=tid;i<4096;i+=256){
    int p=i>>6, c=i&63;
    float v = t1[(size_t)(base+p)*64 + c];
    v = (v - sm[c])*sr[c]*sg[c] + sb[c];
    fin[p][c] = v>0.f ? v : 0.f;
  }
  __syncthreads();
  int o = tid & 63, p0 = tid>>6;
  float acc[16];
  #pragma unroll
  for(int i=0;i<16;i++) acc[i]=0.f;
  for(int cc=0; cc<64; cc+=4){
    float4 wv = *(const float4*)(w2 + o*64 + cc);
    #pragma unroll
    for(int i=0;i<16;i++){
      float4 f4 = *(const float4*)&fin[p0 + i*4][cc];
      acc[i] += f4.x*wv.x + f4.y*wv.y + f4.z*wv.z + f4.w*wv.w;
    }
  }
  #pragma unroll
  for(int i=0;i<16;i++) t2[(size_t)(base+p0+i*4)*64 + o] = acc[i];
}

// ---- elementwise bn+relu in place
__global__ __launch_bounds__(256) void k_bnrelu(float* __restrict__ t, int total, int C,
                         const float* __restrict__ mean, const float* __restrict__ rstd,
                         const float* __restrict__ g, const float* __restrict__ b){
  int i = blockIdx.x*blockDim.x + threadIdx.x;
  if(i>=total) return;
  int c = i % C;
  float v = t[i];
  v = (v-mean[c])*rstd[c]*g[c] + b[c];
  t[i] = v>0.f ? v : 0.f;
}

// ---- both weight transposes in one launch: wt[c][o] = w[o][c]
__global__ __launch_bounds__(256) void k_wt2(const float* __restrict__ w0, float* __restrict__ wt0,
                                             const float* __restrict__ w1, float* __restrict__ wt1){
  int gid = blockIdx.x*blockDim.x + threadIdx.x;
  if(gid < 128*128){
    int o = gid % 128, c = gid / 128;
    wt0[gid] = w0[o*128 + c];
  } else {
    int g2 = gid - 128*128;
    if(g2 >= 256*256) return;
    int o = g2 % 256, c = g2 / 256;
    wt1[g2] = w1[o*256 + c];
  }
}

// ---- farthest point sampling v4: zero VMEM in loop + DPP argmax (no LDS shuffle chain).
template<int P, int S, int T>
__global__ __launch_bounds__(T, 1) void k_fps(const float* __restrict__ pts, int* __restrict__ outIdx,
                      float* __restrict__ outXyz){
  constexpr int PPT = P/T;
  constexpr int NW  = T/64;
  __shared__ __align__(16) float4 sp[P];
  __shared__ unsigned long long rv64[2][NW];
  __shared__ int sidx[S];
  int b = blockIdx.x, tid = threadIdx.x;
  const float* p = pts + (size_t)b*P*3;
  float px[PPT], py[PPT], pz[PPT], dist[PPT];
  #pragma unroll
  for(int i=0;i<PPT;i++){
    int n = i*T + tid;                       // interleaved: coalesced staging
    float X=p[n*3], Y=p[n*3+1], Z=p[n*3+2];
    px[i]=X; py[i]=Y; pz[i]=Z; dist[i]=1e10f;
    sp[n] = make_float4(X,Y,Z,0.f);
  }
  __syncthreads();
  int cur = 0;
  float cx=sp[0].x, cy=sp[0].y, cz=sp[0].z;
  for(int s=0;s<S;s++){
    if(tid==0) sidx[s]=cur;                  // LDS only; flushed once at the end
    if(s==S-1) break;
    float bv=-FLT_MAX; int bi=0;
    #pragma unroll
    for(int i=0;i<PPT;i++){
      float d = sqdist(px[i],py[i],pz[i],cx,cy,cz);
      float nd = fminf(dist[i], d);
      dist[i]=nd;
      int n = i*T + tid;                     // ascending within thread => '>' keeps lowest idx
      if(nd>bv){ bv=nd; bi=n; }
    }
    // packed key: max dist, tie -> lowest idx (commutative => order-free, matches np.argmax)
    unsigned long long key = ((unsigned long long)__float_as_uint(bv)<<32) | (unsigned)(~bi);
    key = wave_max_u64(key);                 // uniform per wave after readlane
    int sl = s & 1;
    if((tid&63)==0) rv64[sl][tid>>6] = key;
    __syncthreads();
    unsigned long long wk = rv64[sl][0];
    #pragma unroll
    for(int w=1;w<NW;w++){ unsigned long long o2 = rv64[sl][w]; if(o2>wk) wk=o2; }
    cur = (int)(~(unsigned)wk);              // redundant all-thread compute; no 2nd barrier
    float4 cp = sp[cur];                     // one broadcast ds_read_b128
    cx=cp.x; cy=cp.y; cz=cp.z;
  }
  __syncthreads();
  for(int i=tid; i<S; i+=T){
    int id = sidx[i];
    float4 cp = sp[id];
    outIdx[b*S+i] = id;
    outXyz[((size_t)b*S+i)*3+0] = cp.x;
    outXyz[((size_t)b*S+i)*3+1] = cp.y;
    outXyz[((size_t)b*S+i)*3+2] = cp.z;
  }
}

// ---- exact 32-NN per query, one wave per query: DPP argmin on packed keys
template<int P>
__global__ __launch_bounds__(64) void k_knn(const float* __restrict__ pts, const float* __restrict__ q,
                      int S, int* __restrict__ knn){
  int bq = blockIdx.x, lane = threadIdx.x;
  int b = bq / S;
  __shared__ float d2[P];
  const float* p = pts + (size_t)b*P*3;
  float qx=q[(size_t)bq*3], qy=q[(size_t)bq*3+1], qz=q[(size_t)bq*3+2];
  for(int n=lane;n<P;n+=64) d2[n] = sqdist(qx,qy,qz,p[n*3],p[n*3+1],p[n*3+2]);
  __syncthreads();
  for(int j=0;j<KK;j++){
    unsigned long long kmin = 0xFFFFFFFFFFFFFFFFull;
    for(int n=lane;n<P;n+=64){
      unsigned long long key = ((unsigned long long)__float_as_uint(d2[n])<<32) | (unsigned)n;
      if(key<kmin) kmin=key;                  // min dist, tie -> lowest idx
    }
    kmin = wave_min_u64(kmin);                // uniform
    int sel = (int)(unsigned)kmin;
    if(lane==0){ knn[(size_t)bq*KK+j]=sel; d2[sel]=FLT_MAX; }
    __syncthreads();   // single wave: cheap; orders the d2 update
  }
}

// ---- sg-block pass1 v3: register-tiled outer-product GEMM on transposed weights.
template<int C, int P>
__global__ __launch_bounds__(2*C/2, 2) void k_sg_pass1(
                           const float* __restrict__ feats, const int* __restrict__ knn,
                           const int* __restrict__ fpsIdx, const float* __restrict__ WT,
                           float* __restrict__ hmax, float* __restrict__ hmin,
                           float* __restrict__ part, int S){
  constexpr int O   = 2*C;
  constexpr int TPB = O/2;           // 64 (C=64) or 128 (C=128)
  constexpr int C4  = C/4;
  constexpr int OG  = O/8;           // # of o-groups
  constexpr int LDC = C+4;           // padded LDS row
  __shared__ __align__(16) float gfp[KK*LDC];
  __shared__ __align__(16) float cf[C];
  __shared__ float sct[O];
  __shared__ float smx[4][O], smn[4][O], ssm[4][O], ssq[4][O];
  int bq = blockIdx.x, tid = threadIdx.x;
  int b = bq / S;
  const float* fb = feats + (size_t)b*P*C;
  int ci = fpsIdx[bq];
  const float* cfg = fb + (size_t)ci*C;
  cf[tid % C] = cfg[tid % C];
  for(int i=tid; i<KK*C4; i+=TPB){
    int k = i/C4, d4 = i - k*C4;
    float4 g = ((const float4*)(fb + (size_t)knn[(size_t)bq*KK+k]*C))[d4];
    float4 c = ((const float4*)cfg)[d4];
    float4 r; r.x=g.x-c.x; r.y=g.y-c.y; r.z=g.z-c.z; r.w=g.w-c.w;
    *(float4*)&gfp[k*LDC + d4*4] = r;
  }
  __syncthreads();
  {
    int o2 = tid*2;
    float ct0=0.f, ct1=0.f;
    for(int c=0;c<C;c+=4){
      float4 c4 = *(const float4*)&cf[c];
      #pragma unroll
      for(int t=0;t<4;t++){
        float cv = ((const float*)&c4)[t];
        float2 wh = *(const float2*)&WT[(size_t)(C+c+t)*O + o2];
        ct0 += cv*wh.x; ct1 += cv*wh.y;
      }
    }
    sct[o2]=ct0; sct[o2+1]=ct1;
  }
  __syncthreads();
  int kg = tid / OG;
  int og = tid % OG;
  float acc[8][8];
  #pragma unroll
  for(int a=0;a<8;a++)
    #pragma unroll
    for(int bb2=0;bb2<8;bb2++) acc[a][bb2]=0.f;
  for(int dc=0; dc<C4; dc++){
    float4 g4[8];
    #pragma unroll
    for(int jk=0;jk<8;jk++) g4[jk] = *(const float4*)&gfp[(kg*8+jk)*LDC + dc*4];
    #pragma unroll
    for(int t=0;t<4;t++){
      const float* wrow = WT + (size_t)(dc*4+t)*O + og*8;
      float4 wa = *(const float4*)wrow;
      float4 wb = *(const float4*)(wrow+4);
      #pragma unroll
      for(int jk=0;jk<8;jk++){
        float gs = ((const float*)&g4[jk])[t];
        acc[jk][0] += gs*wa.x; acc[jk][1] += gs*wa.y; acc[jk][2] += gs*wa.z; acc[jk][3] += gs*wa.w;
        acc[jk][4] += gs*wb.x; acc[jk][5] += gs*wb.y; acc[jk][6] += gs*wb.z; acc[jk][7] += gs*wb.w;
      }
    }
  }
  #pragma unroll
  for(int jo=0;jo<8;jo++){
    int o = og*8+jo;
    float ct = sct[o];
    float s=0.f,q=0.f,mx=-FLT_MAX,mn=FLT_MAX;
    #pragma unroll
    for(int jk=0;jk<8;jk++){
      float h = acc[jk][jo] + ct;
      s+=h; q+=h*h; mx=fmaxf(mx,h); mn=fminf(mn,h);
    }
    smx[kg][o]=mx; smn[kg][o]=mn; ssm[kg][o]=s; ssq[kg][o]=q;
  }
  __syncthreads();
  #pragma unroll
  for(int oo=0;oo<2;oo++){
    int o = tid*2+oo;
    float mx=smx[0][o], mn=smn[0][o], s=ssm[0][o], q=ssq[0][o];
    #pragma unroll
    for(int g=1;g<4;g++){
      mx=fmaxf(mx,smx[g][o]); mn=fminf(mn,smn[g][o]); s+=ssm[g][o]; q+=ssq[g][o];
    }
    hmax[(size_t)bq*O+o]=mx; hmin[(size_t)bq*O+o]=mn;
    part[(size_t)bq*2*O+o]=s; part[(size_t)bq*2*O+O+o]=q;
  }
}

// ---- reduce per-block partials -> per-channel mean/rstd
__global__ __launch_bounds__(256) void k_reduce(const float* __restrict__ part, int nblk, int O, int M,
                         float* __restrict__ mean, float* __restrict__ rstd){
  int o = blockIdx.x, tid = threadIdx.x;
  float s=0.f, s2=0.f;
  for(int i=tid;i<nblk;i+=blockDim.x){ s += part[(size_t)i*2*O + o]; s2 += part[(size_t)i*2*O + O + o]; }
  __shared__ float bs[256], bq[256];
  bs[tid]=s; bq[tid]=s2; __syncthreads();
  for(int st=128; st>0; st>>=1){ if(tid<st){ bs[tid]+=bs[tid+st]; bq[tid]+=bq[tid+st]; } __syncthreads(); }
  if(tid==0){
    float m = bs[0]/M;
    float v = bq[0]/M - m*m; if(v<0.f) v=0.f;
    mean[o]=m; rstd[o]=rsqrtf(v+EPSV);
  }
}

// ---- epilogue: max_k relu(bn(h)) = relu(bn(slope>=0 ? hmax : hmin)); fp32 out, same layout
__global__ __launch_bounds__(256) void k_postmax(const float* __restrict__ hmax, const float* __restrict__ hmin,
                          const float* __restrict__ mean, const float* __restrict__ rstd,
                          const float* __restrict__ g, const float* __restrict__ bb,
                          int O, int total, float* __restrict__ out){
  int i = blockIdx.x*blockDim.x + threadIdx.x;
  if(i>=total) return;
  int o = i % O;
  float sc = rstd[o]*g[o];
  float h = (sc>=0.f) ? hmax[i] : hmin[i];
  float v = (h-mean[o])*sc + bb[o];
  out[i] = v>0.f ? v : 0.f;
}

// ---- final epilogue with [B,S1,256] -> [B,256,S1] transpose, fp32 out
__global__ __launch_bounds__(256) void k_postmax_out(const float* __restrict__ hmax, const float* __restrict__ hmin,
                              const float* __restrict__ mean, const float* __restrict__ rstd,
                              const float* __restrict__ g, const float* __restrict__ bb,
                              float* __restrict__ out){
  int i = blockIdx.x*blockDim.x + threadIdx.x;
  if(i >= BATCH*NS1*256) return;
  int o = i & 255;
  int s = (i>>8) & (NS1-1);
  int b = i >> 15;
  float sc = rstd[o]*g[o];
  float h = (sc>=0.f) ? hmax[i] : hmin[i];
  float v = (h-mean[o])*sc + bb[o];
  v = v>0.f ? v : 0.f;
  out[((size_t)b*256 + o)*NS1 + s] = v;
}

extern "C" void kernel_launch(void* const* d_in, const int* in_sizes, int n_in,
                              void* d_out, int out_size, void* d_ws, size_t ws_size,
                              hipStream_t stream){
  const float* x    = (const float*)d_in[0];
  const float* w1   = (const float*)d_in[1];
  const float* g1   = (const float*)d_in[2];
  const float* b1   = (const float*)d_in[3];
  const float* w2   = (const float*)d_in[4];
  const float* g2   = (const float*)d_in[5];
  const float* b2   = (const float*)d_in[6];
  const float* wsg0 = (const float*)d_in[7];
  const float* gsg0 = (const float*)d_in[8];
  const float* bsg0 = (const float*)d_in[9];
  const float* wsg1 = (const float*)d_in[10];
  const float* gsg1 = (const float*)d_in[11];
  const float* bsg1 = (const float*)d_in[12];
  float* out = (float*)d_out;

  float* wsf = (float*)d_ws;
  float* coords = wsf;                    wsf += BATCH*NPTS*3;
  float* t1     = wsf;                    wsf += BATCH*NPTS*64;
  float* t2     = wsf;                    wsf += BATCH*NPTS*64;
  float* mean1=wsf;  wsf+=64;  float* rstd1=wsf;  wsf+=64;
  float* mean2=wsf;  wsf+=64;  float* rstd2=wsf;  wsf+=64;
  float* meanS0=wsf; wsf+=128; float* rstdS0=wsf; wsf+=128;
  float* meanS1=wsf; wsf+=256; float* rstdS1=wsf; wsf+=256;
  int*   fps0 = (int*)wsf;                wsf += BATCH*NS0;
  float* xyz0 = wsf;                      wsf += BATCH*NS0*3;
  int*   knn0 = (int*)wsf;                wsf += BATCH*NS0*KK;
  float* hmax0= wsf;                      wsf += BATCH*NS0*128;
  float* hmin0= wsf;                      wsf += BATCH*NS0*128;
  float* part0= wsf;                      wsf += BATCH*NS0*2*128;
  float* f1   = wsf;                      wsf += BATCH*NS0*128;
  int*   fps1 = (int*)wsf;                wsf += BATCH*NS1;
  float* xyz1 = wsf;                      wsf += BATCH*NS1*3;
  int*   knn1 = (int*)wsf;                wsf += BATCH*NS1*KK;
  float* hmax1= wsf;                      wsf += BATCH*NS1*256;
  float* hmin1= wsf;                      wsf += BATCH*NS1*256;
  float* part1= wsf;                      wsf += BATCH*NS1*2*256;
  float* wt0  = wsf;                      wsf += 128*128;
  float* wt1  = wsf;                      wsf += 256*256;

  // both weight transposes, one launch (no deps; run first)
  k_wt2<<<dim3((128*128+256*256+255)/256), dim3(256), 0, stream>>>(wsg0, wt0, wsg1, wt1);

  // embed MLP (two 1x1 convs with training-mode BN)
  k_embed1<<<dim3(128), dim3(256), 0, stream>>>(x, w1, coords, t1);
  k_stats <<<dim3(64),  dim3(256), 0, stream>>>(t1, BATCH*NPTS, 64, mean1, rstd1);
  k_embed2<<<dim3(512), dim3(256), 0, stream>>>(t1, w2, mean1, rstd1, g1, b1, t2);
  k_stats <<<dim3(64),  dim3(256), 0, stream>>>(t2, BATCH*NPTS, 64, mean2, rstd2);
  k_bnrelu<<<dim3(8192),dim3(256), 0, stream>>>(t2, BATCH*NPTS*64, 64, mean2, rstd2, g2, b2);

  // SG block 0: N=2048 -> S0=256, C=64 -> O=128
  k_fps<NPTS,NS0,256><<<dim3(BATCH),     dim3(256), 0, stream>>>(coords, fps0, xyz0);
  k_knn<NPTS>        <<<dim3(BATCH*NS0), dim3(64),  0, stream>>>(coords, xyz0, NS0, knn0);
  k_sg_pass1<64,NPTS><<<dim3(BATCH*NS0), dim3(64),  0, stream>>>(t2, knn0, fps0, wt0, hmax0, hmin0, part0, NS0);
  k_reduce           <<<dim3(128),       dim3(256), 0, stream>>>(part0, BATCH*NS0, 128, BATCH*NS0*KK, meanS0, rstdS0);
  k_postmax          <<<dim3(2048),      dim3(256), 0, stream>>>(hmax0, hmin0, meanS0, rstdS0, gsg0, bsg0,
                                                                 128, BATCH*NS0*128, f1);

  // SG block 1: S0=256 -> S1=128, C=128 -> O=256
  k_fps<NS0,NS1,256> <<<dim3(BATCH),     dim3(256), 0, stream>>>(xyz0, fps1, xyz1);
  k_knn<NS0>         <<<dim3(BATCH*NS1), dim3(64),  0, stream>>>(xyz0, xyz1, NS1, knn1);
  k_sg_pass1<128,NS0><<<dim3(BATCH*NS1), dim3(128), 0, stream>>>(f1, knn1, fps1, wt1, hmax1, hmin1, part1, NS1);
  k_reduce           <<<dim3(256),       dim3(256), 0, stream>>>(part1, BATCH*NS1, 256, BATCH*NS1*KK, meanS1, rstdS1);
  k_postmax_out      <<<dim3(2048),      dim3(256), 0, stream>>>(hmax1, hmin1, meanS1, rstdS1, gsg1, bsg1, out);
}

// Round 8
// 583.699 us; speedup vs baseline: 4.3710x; 1.0855x over previous
//
#include <hip/hip_runtime.h>
#include <float.h>

#define BATCH 16
#define NPTS  2048
#define NS0   256
#define NS1   128
#define KK    32
#define EPSV  1e-5f

// exact numpy-order squared distance: ((dx*dx + dy*dy) + dz*dz), no FMA contraction
__device__ __forceinline__ float sqdist(float ax,float ay,float az,float bx,float by,float bz){
  float dx=__fsub_rn(ax,bx), dy=__fsub_rn(ay,by), dz=__fsub_rn(az,bz);
  return __fadd_rn(__fadd_rn(__fmul_rn(dx,dx),__fmul_rn(dy,dy)),__fmul_rn(dz,dz));
}

// ---- DPP wave64 reduce on packed u64 keys (VALU, no LDS). Winner broadcast via readlane 63.
template<int CTRL, int RM>
__device__ __forceinline__ unsigned long long dpp_max_u64(unsigned long long x){
  int lo = __builtin_amdgcn_update_dpp(0, (int)(unsigned)x,        CTRL, RM, 0xf, false);
  int hi = __builtin_amdgcn_update_dpp(0, (int)(unsigned)(x>>32),  CTRL, RM, 0xf, false);
  unsigned long long m = ((unsigned long long)(unsigned)hi<<32) | (unsigned)lo;
  return m > x ? m : x;
}
template<int CTRL, int RM>
__device__ __forceinline__ unsigned long long dpp_min_u64(unsigned long long x){
  int lo = __builtin_amdgcn_update_dpp(-1, (int)(unsigned)x,       CTRL, RM, 0xf, false);
  int hi = __builtin_amdgcn_update_dpp(-1, (int)(unsigned)(x>>32), CTRL, RM, 0xf, false);
  unsigned long long m = ((unsigned long long)(unsigned)hi<<32) | (unsigned)lo;
  return m < x ? m : x;
}
__device__ __forceinline__ unsigned long long wave_max_u64(unsigned long long k){
  k = dpp_max_u64<0x111,0xf>(k);   // row_shr:1
  k = dpp_max_u64<0x112,0xf>(k);   // row_shr:2
  k = dpp_max_u64<0x114,0xf>(k);   // row_shr:4
  k = dpp_max_u64<0x118,0xf>(k);   // row_shr:8
  k = dpp_max_u64<0x142,0xa>(k);   // row_bcast15 -> rows 1,3
  k = dpp_max_u64<0x143,0xc>(k);   // row_bcast31 -> rows 2,3
  unsigned lo = (unsigned)__builtin_amdgcn_readlane((int)(unsigned)k, 63);
  unsigned hi = (unsigned)__builtin_amdgcn_readlane((int)(unsigned)(k>>32), 63);
  return ((unsigned long long)hi<<32) | lo;
}
__device__ __forceinline__ unsigned long long wave_min_u64(unsigned long long k){
  k = dpp_min_u64<0x111,0xf>(k);
  k = dpp_min_u64<0x112,0xf>(k);
  k = dpp_min_u64<0x114,0xf>(k);
  k = dpp_min_u64<0x118,0xf>(k);
  k = dpp_min_u64<0x142,0xa>(k);
  k = dpp_min_u64<0x143,0xc>(k);
  unsigned lo = (unsigned)__builtin_amdgcn_readlane((int)(unsigned)k, 63);
  unsigned hi = (unsigned)__builtin_amdgcn_readlane((int)(unsigned)(k>>32), 63);
  return ((unsigned long long)hi<<32) | lo;
}

// ================= device bodies (shared by fused kernels) =================

// embed layer 1 body: one block of 256 thr handles 256 points of [B,3,N] -> coords, t1
__device__ void embed1_body(int bid, const float* __restrict__ x, const float* __restrict__ w1,
                            float* __restrict__ coords, float* __restrict__ t1){
  __shared__ float w[64*3];
  int tid = threadIdx.x;
  if (tid < 192) w[tid] = w1[tid];
  __syncthreads();
  int gid = bid*256 + tid;
  int b = gid / NPTS, n = gid % NPTS;
  float cx = x[(b*3+0)*NPTS + n];
  float cy = x[(b*3+1)*NPTS + n];
  float cz = x[(b*3+2)*NPTS + n];
  coords[gid*3+0]=cx; coords[gid*3+1]=cy; coords[gid*3+2]=cz;
  float* o = t1 + (size_t)gid*64;
  #pragma unroll
  for(int j=0;j<64;j++) o[j] = cx*w[j*3+0] + cy*w[j*3+1] + cz*w[j*3+2];
}

// weight transpose body: gid over 128*128 + 256*256 elements
__device__ void wt_body(int gid, const float* __restrict__ w0, float* __restrict__ wt0,
                        const float* __restrict__ w1, float* __restrict__ wt1){
  if(gid < 128*128){
    int o = gid % 128, c = gid / 128;
    wt0[gid] = w0[o*128 + c];
  } else {
    int g2 = gid - 128*128;
    if(g2 >= 256*256) return;
    int o = g2 % 256, c = g2 / 256;
    wt1[g2] = w1[o*256 + c];
  }
}

// embed layer 2 body: 64 points per block (256 thr)
__device__ void embed2_body(int bid, const float* __restrict__ t1, const float* __restrict__ w2,
                            const float* __restrict__ mean1, const float* __restrict__ rstd1,
                            const float* __restrict__ g1, const float* __restrict__ b1,
                            float* __restrict__ t2){
  __shared__ __align__(16) float fin[64][64];
  __shared__ float sm[64], sr[64], sg[64], sb[64];
  int tid = threadIdx.x;
  if (tid<64){ sm[tid]=mean1[tid]; sr[tid]=rstd1[tid]; sg[tid]=g1[tid]; sb[tid]=b1[tid]; }
  __syncthreads();
  int base = bid*64;
  for(int i=tid;i<4096;i+=256){
    int p=i>>6, c=i&63;
    float v = t1[(size_t)(base+p)*64 + c];
    v = (v - sm[c])*sr[c]*sg[c] + sb[c];
    fin[p][c] = v>0.f ? v : 0.f;
  }
  __syncthreads();
  int o = tid & 63, p0 = tid>>6;
  float acc[16];
  #pragma unroll
  for(int i=0;i<16;i++) acc[i]=0.f;
  for(int cc=0; cc<64; cc+=4){
    float4 wv = *(const float4*)(w2 + o*64 + cc);
    #pragma unroll
    for(int i=0;i<16;i++){
      float4 f4 = *(const float4*)&fin[p0 + i*4][cc];
      acc[i] += f4.x*wv.x + f4.y*wv.y + f4.z*wv.z + f4.w*wv.w;
    }
  }
  #pragma unroll
  for(int i=0;i<16;i++) t2[(size_t)(base+p0+i*4)*64 + o] = acc[i];
}

// FPS body (multi-wave, T=256): reads x [B][3][NPTS] directly (no dependency on coords).
template<int P, int S, int T>
__device__ void fps_body(int b, const float* __restrict__ x, int* __restrict__ outIdx,
                         float* __restrict__ outXyz){
  constexpr int PPT = P/T;
  constexpr int NW  = T/64;
  __shared__ __align__(16) float4 sp[P];
  __shared__ unsigned long long rv64[2][NW];
  __shared__ int sidx[S];
  int tid = threadIdx.x;
  const float* xb = x + (size_t)b*3*P;
  float px[PPT], py[PPT], pz[PPT], dist[PPT];
  #pragma unroll
  for(int i=0;i<PPT;i++){
    int n = i*T + tid;                       // interleaved: coalesced staging from x layout
    float X=xb[n], Y=xb[P+n], Z=xb[2*P+n];
    px[i]=X; py[i]=Y; pz[i]=Z; dist[i]=1e10f;
    sp[n] = make_float4(X,Y,Z,0.f);
  }
  __syncthreads();
  int cur = 0;
  float cx=sp[0].x, cy=sp[0].y, cz=sp[0].z;
  for(int s=0;s<S;s++){
    if(tid==0) sidx[s]=cur;
    if(s==S-1) break;
    float bv=-FLT_MAX; int bi=0;
    #pragma unroll
    for(int i=0;i<PPT;i++){
      float d = sqdist(px[i],py[i],pz[i],cx,cy,cz);
      float nd = fminf(dist[i], d);
      dist[i]=nd;
      int n = i*T + tid;                     // ascending within thread => '>' keeps lowest idx
      if(nd>bv){ bv=nd; bi=n; }
    }
    unsigned long long key = ((unsigned long long)__float_as_uint(bv)<<32) | (unsigned)(~bi);
    key = wave_max_u64(key);
    int sl = s & 1;
    if((tid&63)==0) rv64[sl][tid>>6] = key;
    __syncthreads();
    unsigned long long wk = rv64[sl][0];
    #pragma unroll
    for(int w=1;w<NW;w++){ unsigned long long o2 = rv64[sl][w]; if(o2>wk) wk=o2; }
    cur = (int)(~(unsigned)wk);
    float4 cp = sp[cur];
    cx=cp.x; cy=cp.y; cz=cp.z;
  }
  __syncthreads();
  for(int i=tid; i<S; i+=T){
    int id = sidx[i];
    float4 cp = sp[id];
    outIdx[b*S+i] = id;
    outXyz[((size_t)b*S+i)*3+0] = cp.x;
    outXyz[((size_t)b*S+i)*3+1] = cp.y;
    outXyz[((size_t)b*S+i)*3+2] = cp.z;
  }
}

// FPS body, single-wave (64 thr): zero barriers in the loop. pts is [b][P][3] packed.
template<int P, int S>
__device__ void fps_wave_body(int b, const float* __restrict__ pts, int* __restrict__ outIdx,
                              float* __restrict__ outXyz){
  constexpr int PPT = P/64;
  __shared__ __align__(16) float4 sp[P];
  __shared__ int sidx[S];
  int lane = threadIdx.x;
  const float* p = pts + (size_t)b*P*3;
  float px[PPT], py[PPT], pz[PPT], dist[PPT];
  #pragma unroll
  for(int i=0;i<PPT;i++){
    int n = i*64 + lane;
    float X=p[n*3], Y=p[n*3+1], Z=p[n*3+2];
    px[i]=X; py[i]=Y; pz[i]=Z; dist[i]=1e10f;
    sp[n] = make_float4(X,Y,Z,0.f);
  }
  __syncthreads();                           // order LDS staging vs reads (cheap: 1 wave)
  int cur = 0;
  float cx=sp[0].x, cy=sp[0].y, cz=sp[0].z;
  for(int s=0;s<S;s++){
    if(lane==0) sidx[s]=cur;
    if(s==S-1) break;
    float bv=-FLT_MAX; int bi=0;
    #pragma unroll
    for(int i=0;i<PPT;i++){
      float d = sqdist(px[i],py[i],pz[i],cx,cy,cz);
      float nd = fminf(dist[i], d);
      dist[i]=nd;
      int n = i*64 + lane;
      if(nd>bv){ bv=nd; bi=n; }
    }
    unsigned long long key = ((unsigned long long)__float_as_uint(bv)<<32) | (unsigned)(~bi);
    key = wave_max_u64(key);                 // uniform after readlane
    cur = (int)(~(unsigned)key);
    float4 cp = sp[cur];                     // broadcast LDS read
    cx=cp.x; cy=cp.y; cz=cp.z;
  }
  __syncthreads();
  for(int i=lane; i<S; i+=64){
    int id = sidx[i];
    float4 cp = sp[id];
    outIdx[b*S+i] = id;
    outXyz[((size_t)b*S+i)*3+0] = cp.x;
    outXyz[((size_t)b*S+i)*3+1] = cp.y;
    outXyz[((size_t)b*S+i)*3+2] = cp.z;
  }
}

// KNN body: one wave per query, DPP argmin on packed keys (r7-proven)
template<int P>
__device__ void knn_body(int bq, const float* __restrict__ pts, const float* __restrict__ q,
                         int S, int* __restrict__ knn){
  int lane = threadIdx.x;
  int b = bq / S;
  __shared__ float d2[P];
  const float* p = pts + (size_t)b*P*3;
  float qx=q[(size_t)bq*3], qy=q[(size_t)bq*3+1], qz=q[(size_t)bq*3+2];
  for(int n=lane;n<P;n+=64) d2[n] = sqdist(qx,qy,qz,p[n*3],p[n*3+1],p[n*3+2]);
  __syncthreads();
  for(int j=0;j<KK;j++){
    unsigned long long kmin = 0xFFFFFFFFFFFFFFFFull;
    for(int n=lane;n<P;n+=64){
      unsigned long long key = ((unsigned long long)__float_as_uint(d2[n])<<32) | (unsigned)n;
      if(key<kmin) kmin=key;                  // min dist, tie -> lowest idx
    }
    kmin = wave_min_u64(kmin);
    int sel = (int)(unsigned)kmin;
    if(lane==0){ knn[(size_t)bq*KK+j]=sel; d2[sel]=FLT_MAX; }
    __syncthreads();
  }
}

// sg-block pass1 body: register-tiled outer-product GEMM; optional fused BN+ReLU on inputs.
template<int C, int P, bool BN>
__device__ void pass1_body(int bq, const float* __restrict__ feats, const int* __restrict__ knn,
                           const int* __restrict__ fpsIdx, const float* __restrict__ WT,
                           float* __restrict__ hmax, float* __restrict__ hmin,
                           float* __restrict__ part, int S,
                           const float* __restrict__ bmean, const float* __restrict__ brstd,
                           const float* __restrict__ bg, const float* __restrict__ bb){
  constexpr int O   = 2*C;
  constexpr int TPB = O/2;           // == C
  constexpr int C4  = C/4;
  constexpr int OG  = O/8;
  constexpr int LDC = C+4;
  __shared__ __align__(16) float gfp[KK*LDC];
  __shared__ __align__(16) float cf[C];
  __shared__ __align__(16) float sa[C], sbb[C];
  __shared__ float sct[O];
  __shared__ float smx[4][O], smn[4][O], ssm[4][O], ssq[4][O];
  int tid = threadIdx.x;
  int b = bq / S;
  const float* fb = feats + (size_t)b*P*C;
  int ci = fpsIdx[bq];
  const float* cfg = fb + (size_t)ci*C;
  if(BN){
    float a = brstd[tid]*bg[tid];
    float sh = bb[tid] - bmean[tid]*a;
    sa[tid]=a; sbb[tid]=sh;
    float cv = a*cfg[tid] + sh;
    cf[tid] = cv>0.f ? cv : 0.f;
    __syncthreads();                         // sa/sbb/cf visible before gather
  } else {
    cf[tid] = cfg[tid];
  }
  for(int i=tid; i<KK*C4; i+=TPB){
    int k = i/C4, d4 = i - k*C4;
    float4 g = ((const float4*)(fb + (size_t)knn[(size_t)bq*KK+k]*C))[d4];
    float4 r;
    if(BN){
      float4 a4 = *(const float4*)&sa[d4*4];
      float4 s4 = *(const float4*)&sbb[d4*4];
      float4 c4 = *(const float4*)&cf[d4*4];
      float gx = a4.x*g.x+s4.x; gx = gx>0.f?gx:0.f;
      float gy = a4.y*g.y+s4.y; gy = gy>0.f?gy:0.f;
      float gz = a4.z*g.z+s4.z; gz = gz>0.f?gz:0.f;
      float gw = a4.w*g.w+s4.w; gw = gw>0.f?gw:0.f;
      r.x=gx-c4.x; r.y=gy-c4.y; r.z=gz-c4.z; r.w=gw-c4.w;
    } else {
      float4 c4 = ((const float4*)cfg)[d4];
      r.x=g.x-c4.x; r.y=g.y-c4.y; r.z=g.z-c4.z; r.w=g.w-c4.w;
    }
    *(float4*)&gfp[k*LDC + d4*4] = r;
  }
  __syncthreads();
  {
    int o2 = tid*2;
    float ct0=0.f, ct1=0.f;
    for(int c=0;c<C;c+=4){
      float4 c4 = *(const float4*)&cf[c];
      #pragma unroll
      for(int t=0;t<4;t++){
        float cv = ((const float*)&c4)[t];
        float2 wh = *(const float2*)&WT[(size_t)(C+c+t)*O + o2];
        ct0 += cv*wh.x; ct1 += cv*wh.y;
      }
    }
    sct[o2]=ct0; sct[o2+1]=ct1;
  }
  __syncthreads();
  int kg = tid / OG;
  int og = tid % OG;
  float acc[8][8];
  #pragma unroll
  for(int a=0;a<8;a++)
    #pragma unroll
    for(int bb2=0;bb2<8;bb2++) acc[a][bb2]=0.f;
  for(int dc=0; dc<C4; dc++){
    float4 g4[8];
    #pragma unroll
    for(int jk=0;jk<8;jk++) g4[jk] = *(const float4*)&gfp[(kg*8+jk)*LDC + dc*4];
    #pragma unroll
    for(int t=0;t<4;t++){
      const float* wrow = WT + (size_t)(dc*4+t)*O + og*8;
      float4 wa = *(const float4*)wrow;
      float4 wb = *(const float4*)(wrow+4);
      #pragma unroll
      for(int jk=0;jk<8;jk++){
        float gs = ((const float*)&g4[jk])[t];
        acc[jk][0] += gs*wa.x; acc[jk][1] += gs*wa.y; acc[jk][2] += gs*wa.z; acc[jk][3] += gs*wa.w;
        acc[jk][4] += gs*wb.x; acc[jk][5] += gs*wb.y; acc[jk][6] += gs*wb.z; acc[jk][7] += gs*wb.w;
      }
    }
  }
  #pragma unroll
  for(int jo=0;jo<8;jo++){
    int o = og*8+jo;
    float ct = sct[o];
    float s=0.f,q=0.f,mx=-FLT_MAX,mn=FLT_MAX;
    #pragma unroll
    for(int jk=0;jk<8;jk++){
      float h = acc[jk][jo] + ct;
      s+=h; q+=h*h; mx=fmaxf(mx,h); mn=fminf(mn,h);
    }
    smx[kg][o]=mx; smn[kg][o]=mn; ssm[kg][o]=s; ssq[kg][o]=q;
  }
  __syncthreads();
  #pragma unroll
  for(int oo=0;oo<2;oo++){
    int o = tid*2+oo;
    float mx=smx[0][o], mn=smn[0][o], s=ssm[0][o], q=ssq[0][o];
    #pragma unroll
    for(int g=1;g<4;g++){
      mx=fmaxf(mx,smx[g][o]); mn=fminf(mn,smn[g][o]); s+=ssm[g][o]; q+=ssq[g][o];
    }
    hmax[(size_t)bq*O+o]=mx; hmin[(size_t)bq*O+o]=mn;
    part[(size_t)bq*2*O+o]=s; part[(size_t)bq*2*O+O+o]=q;
  }
}

// ================= fused kernels =================

// L1: embed1 (blocks 0..127) || weight transposes (blocks 128..447)
__global__ __launch_bounds__(256) void k_embed1_wt(const float* __restrict__ x, const float* __restrict__ w1,
                         float* __restrict__ coords, float* __restrict__ t1,
                         const float* __restrict__ wsg0, float* __restrict__ wt0,
                         const float* __restrict__ wsg1, float* __restrict__ wt1){
  if(blockIdx.x < 128) embed1_body(blockIdx.x, x, w1, coords, t1);
  else wt_body((blockIdx.x-128)*256 + threadIdx.x, wsg0, wt0, wsg1, wt1);
}

// L3: fps0 (blocks 0..15, serial ~127us) || embed2 (blocks 16..527, hidden under fps0)
__global__ __launch_bounds__(256, 1) void k_fps0_embed2(const float* __restrict__ x,
                         int* __restrict__ fps0, float* __restrict__ xyz0,
                         const float* __restrict__ t1, const float* __restrict__ w2,
                         const float* __restrict__ mean1, const float* __restrict__ rstd1,
                         const float* __restrict__ g1, const float* __restrict__ b1,
                         float* __restrict__ t2){
  if(blockIdx.x < BATCH) fps_body<NPTS,NS0,256>(blockIdx.x, x, fps0, xyz0);
  else embed2_body(blockIdx.x-BATCH, t1, w2, mean1, rstd1, g1, b1, t2);
}

// L5: fps1 single-wave (blocks 0..15) || knn0 (blocks 16..4111)
__global__ __launch_bounds__(64, 4) void k_fps1_knn0(const float* __restrict__ xyz0,
                         int* __restrict__ fps1, float* __restrict__ xyz1,
                         const float* __restrict__ coords, int* __restrict__ knn0){
  if(blockIdx.x < BATCH) fps_wave_body<NS0,NS1>(blockIdx.x, xyz0, fps1, xyz1);
  else knn_body<NPTS>(blockIdx.x-BATCH, coords, xyz0, NS0, knn0);
}

// L6: pass1a w/ fused BN (blocks 0..4095) || knn1 (blocks 4096..6143)
__global__ __launch_bounds__(64, 2) void k_pass1a_knn1(const float* __restrict__ t2,
                         const int* __restrict__ knn0, const int* __restrict__ fps0,
                         const float* __restrict__ wt0,
                         float* __restrict__ hmax0, float* __restrict__ hmin0, float* __restrict__ part0,
                         const float* __restrict__ mean2, const float* __restrict__ rstd2,
                         const float* __restrict__ g2, const float* __restrict__ b2,
                         const float* __restrict__ xyz0, const float* __restrict__ xyz1,
                         int* __restrict__ knn1){
  if(blockIdx.x < BATCH*NS0)
    pass1_body<64,NPTS,true>(blockIdx.x, t2, knn0, fps0, wt0, hmax0, hmin0, part0, NS0,
                             mean2, rstd2, g2, b2);
  else
    knn_body<NS0>(blockIdx.x-BATCH*NS0, xyz0, xyz1, NS1, knn1);
}

// L9: pass1b (no BN; f1 already activated)
__global__ __launch_bounds__(128, 2) void k_pass1b(const float* __restrict__ f1,
                         const int* __restrict__ knn1, const int* __restrict__ fps1,
                         const float* __restrict__ wt1,
                         float* __restrict__ hmax1, float* __restrict__ hmin1, float* __restrict__ part1){
  pass1_body<128,NS0,false>(blockIdx.x, f1, knn1, fps1, wt1, hmax1, hmin1, part1, NS1,
                            nullptr, nullptr, nullptr, nullptr);
}

// ================= simple kernels =================

__global__ __launch_bounds__(256) void k_stats(const float* __restrict__ t, int M, int C,
                        float* __restrict__ mean, float* __restrict__ rstd){
  int c = blockIdx.x, tid = threadIdx.x;
  float s=0.f, s2=0.f;
  for(int r=tid; r<M; r+=blockDim.x){ float v = t[(size_t)r*C+c]; s+=v; s2+=v*v; }
  __shared__ float bs[256], bq[256];
  bs[tid]=s; bq[tid]=s2; __syncthreads();
  for(int st=128; st>0; st>>=1){ if(tid<st){ bs[tid]+=bs[tid+st]; bq[tid]+=bq[tid+st]; } __syncthreads(); }
  if(tid==0){
    float m = bs[0]/M;
    float v = bq[0]/M - m*m; if(v<0.f) v=0.f;
    mean[c]=m; rstd[c]=rsqrtf(v+EPSV);
  }
}

__global__ __launch_bounds__(256) void k_reduce(const float* __restrict__ part, int nblk, int O, int M,
                         float* __restrict__ mean, float* __restrict__ rstd){
  int o = blockIdx.x, tid = threadIdx.x;
  float s=0.f, s2=0.f;
  for(int i=tid;i<nblk;i+=blockDim.x){ s += part[(size_t)i*2*O + o]; s2 += part[(size_t)i*2*O + O + o]; }
  __shared__ float bs[256], bq[256];
  bs[tid]=s; bq[tid]=s2; __syncthreads();
  for(int st=128; st>0; st>>=1){ if(tid<st){ bs[tid]+=bs[tid+st]; bq[tid]+=bq[tid+st]; } __syncthreads(); }
  if(tid==0){
    float m = bs[0]/M;
    float v = bq[0]/M - m*m; if(v<0.f) v=0.f;
    mean[o]=m; rstd[o]=rsqrtf(v+EPSV);
  }
}

__global__ __launch_bounds__(256) void k_postmax(const float* __restrict__ hmax, const float* __restrict__ hmin,
                          const float* __restrict__ mean, const float* __restrict__ rstd,
                          const float* __restrict__ g, const float* __restrict__ bb,
                          int O, int total, float* __restrict__ out){
  int i = blockIdx.x*blockDim.x + threadIdx.x;
  if(i>=total) return;
  int o = i % O;
  float sc = rstd[o]*g[o];
  float h = (sc>=0.f) ? hmax[i] : hmin[i];
  float v = (h-mean[o])*sc + bb[o];
  out[i] = v>0.f ? v : 0.f;
}

__global__ __launch_bounds__(256) void k_postmax_out(const float* __restrict__ hmax, const float* __restrict__ hmin,
                              const float* __restrict__ mean, const float* __restrict__ rstd,
                              const float* __restrict__ g, const float* __restrict__ bb,
                              float* __restrict__ out){
  int i = blockIdx.x*blockDim.x + threadIdx.x;
  if(i >= BATCH*NS1*256) return;
  int o = i & 255;
  int s = (i>>8) & (NS1-1);
  int b = i >> 15;
  float sc = rstd[o]*g[o];
  float h = (sc>=0.f) ? hmax[i] : hmin[i];
  float v = (h-mean[o])*sc + bb[o];
  v = v>0.f ? v : 0.f;
  out[((size_t)b*256 + o)*NS1 + s] = v;
}

extern "C" void kernel_launch(void* const* d_in, const int* in_sizes, int n_in,
                              void* d_out, int out_size, void* d_ws, size_t ws_size,
                              hipStream_t stream){
  const float* x    = (const float*)d_in[0];
  const float* w1   = (const float*)d_in[1];
  const float* g1   = (const float*)d_in[2];
  const float* b1   = (const float*)d_in[3];
  const float* w2   = (const float*)d_in[4];
  const float* g2   = (const float*)d_in[5];
  const float* b2   = (const float*)d_in[6];
  const float* wsg0 = (const float*)d_in[7];
  const float* gsg0 = (const float*)d_in[8];
  const float* bsg0 = (const float*)d_in[9];
  const float* wsg1 = (const float*)d_in[10];
  const float* gsg1 = (const float*)d_in[11];
  const float* bsg1 = (const float*)d_in[12];
  float* out = (float*)d_out;

  float* wsf = (float*)d_ws;
  float* coords = wsf;                    wsf += BATCH*NPTS*3;
  float* t1     = wsf;                    wsf += BATCH*NPTS*64;
  float* t2     = wsf;                    wsf += BATCH*NPTS*64;   // raw (pre-BN) embed2 output
  float* mean1=wsf;  wsf+=64;  float* rstd1=wsf;  wsf+=64;
  float* mean2=wsf;  wsf+=64;  float* rstd2=wsf;  wsf+=64;
  float* meanS0=wsf; wsf+=128; float* rstdS0=wsf; wsf+=128;
  float* meanS1=wsf; wsf+=256; float* rstdS1=wsf; wsf+=256;
  int*   fps0 = (int*)wsf;                wsf += BATCH*NS0;
  float* xyz0 = wsf;                      wsf += BATCH*NS0*3;
  int*   knn0 = (int*)wsf;                wsf += BATCH*NS0*KK;
  float* hmax0= wsf;                      wsf += BATCH*NS0*128;
  float* hmin0= wsf;                      wsf += BATCH*NS0*128;
  float* part0= wsf;                      wsf += BATCH*NS0*2*128;
  float* f1   = wsf;                      wsf += BATCH*NS0*128;
  int*   fps1 = (int*)wsf;                wsf += BATCH*NS1;
  float* xyz1 = wsf;                      wsf += BATCH*NS1*3;
  int*   knn1 = (int*)wsf;                wsf += BATCH*NS1*KK;
  float* hmax1= wsf;                      wsf += BATCH*NS1*256;
  float* hmin1= wsf;                      wsf += BATCH*NS1*256;
  float* part1= wsf;                      wsf += BATCH*NS1*2*256;
  float* wt0  = wsf;                      wsf += 128*128;
  float* wt1  = wsf;                      wsf += 256*256;

  // L1: embed1 || weight transposes
  k_embed1_wt<<<dim3(448), dim3(256), 0, stream>>>(x, w1, coords, t1, wsg0, wt0, wsg1, wt1);
  // L2: BN1 stats
  k_stats<<<dim3(64), dim3(256), 0, stream>>>(t1, BATCH*NPTS, 64, mean1, rstd1);
  // L3: fps0 (serial, 16 blocks) || embed2 (hidden under fps0)
  k_fps0_embed2<<<dim3(BATCH+512), dim3(256), 0, stream>>>(x, fps0, xyz0,
                                                           t1, w2, mean1, rstd1, g1, b1, t2);
  // L4: BN2 stats (on raw t2, per reference)
  k_stats<<<dim3(64), dim3(256), 0, stream>>>(t2, BATCH*NPTS, 64, mean2, rstd2);
  // L5: fps1 (single-wave) || knn0
  k_fps1_knn0<<<dim3(BATCH + BATCH*NS0), dim3(64), 0, stream>>>(xyz0, fps1, xyz1, coords, knn0);
  // L6: pass1a (BN2+ReLU fused into gather) || knn1
  k_pass1a_knn1<<<dim3(BATCH*NS0 + BATCH*NS1), dim3(64), 0, stream>>>(t2, knn0, fps0, wt0,
                                                                      hmax0, hmin0, part0,
                                                                      mean2, rstd2, g2, b2,
                                                                      xyz0, xyz1, knn1);
  // L7-L8: BN-S0 stats + epilogue -> f1
  k_reduce<<<dim3(128), dim3(256), 0, stream>>>(part0, BATCH*NS0, 128, BATCH*NS0*KK, meanS0, rstdS0);
  k_postmax<<<dim3(2048), dim3(256), 0, stream>>>(hmax0, hmin0, meanS0, rstdS0, gsg0, bsg0,
                                                  128, BATCH*NS0*128, f1);
  // L9: pass1b
  k_pass1b<<<dim3(BATCH*NS1), dim3(128), 0, stream>>>(f1, knn1, fps1, wt1, hmax1, hmin1, part1);
  // L10-L11: BN-S1 stats + final epilogue w/ transpose
  k_reduce<<<dim3(256), dim3(256), 0, stream>>>(part1, BATCH*NS1, 256, BATCH*NS1*KK, meanS1, rstdS1);
  k_postmax_out<<<dim3(2048), dim3(256), 0, stream>>>(hmax1, hmin1, meanS1, rstdS1, gsg1, bsg1, out);
}

// Round 9
// 498.995 us; speedup vs baseline: 5.1130x; 1.1697x over previous
//
#include <hip/hip_runtime.h>
#include <float.h>

#define BATCH 16
#define NPTS  2048
#define NS0   256
#define NS1   128
#define KK    32
#define EPSV  1e-5f

// exact numpy-order squared distance: ((dx*dx + dy*dy) + dz*dz), no FMA contraction
__device__ __forceinline__ float sqdist(float ax,float ay,float az,float bx,float by,float bz){
  float dx=__fsub_rn(ax,bx), dy=__fsub_rn(ay,by), dz=__fsub_rn(az,bz);
  return __fadd_rn(__fadd_rn(__fmul_rn(dx,dx),__fmul_rn(dy,dy)),__fmul_rn(dz,dz));
}

// ---- native f32/u32 DPP ladders (cheap wave64 reduce; winner in lane 63)
template<int CTRL,int RM>
__device__ __forceinline__ float dpp_fmax_s(float x){
  int t = __builtin_amdgcn_update_dpp((int)0xFF800000, __float_as_int(x), CTRL, RM, 0xf, false);
  return fmaxf(x, __int_as_float(t));
}
template<int CTRL,int RM>
__device__ __forceinline__ float dpp_fmin_s(float x){
  int t = __builtin_amdgcn_update_dpp(0x7F800000, __float_as_int(x), CTRL, RM, 0xf, false);
  return fminf(x, __int_as_float(t));
}
template<int CTRL,int RM>
__device__ __forceinline__ unsigned dpp_umin_s(unsigned x){
  unsigned t = (unsigned)__builtin_amdgcn_update_dpp(-1, (int)x, CTRL, RM, 0xf, false);
  return t<x ? t : x;
}
// argmax over (v,idx): max value, tie -> lowest idx (matches np.argmax first-occurrence)
__device__ __forceinline__ void wave_argmax_f32(float v, unsigned idx, float& mall, int& sel){
  float m=v;
  m=dpp_fmax_s<0x111,0xf>(m); m=dpp_fmax_s<0x112,0xf>(m); m=dpp_fmax_s<0x114,0xf>(m);
  m=dpp_fmax_s<0x118,0xf>(m); m=dpp_fmax_s<0x142,0xa>(m); m=dpp_fmax_s<0x143,0xc>(m);
  mall = __int_as_float(__builtin_amdgcn_readlane(__float_as_int(m),63));
  unsigned c = (v==mall)? idx : 0xFFFFFFFFu;
  c=dpp_umin_s<0x111,0xf>(c); c=dpp_umin_s<0x112,0xf>(c); c=dpp_umin_s<0x114,0xf>(c);
  c=dpp_umin_s<0x118,0xf>(c); c=dpp_umin_s<0x142,0xa>(c); c=dpp_umin_s<0x143,0xc>(c);
  sel = (int)(unsigned)__builtin_amdgcn_readlane((int)c,63);
}
// argmin over (v,idx): min value, tie -> lowest idx (matches stable top_k)
__device__ __forceinline__ int wave_argmin_f32(float v, unsigned idx){
  float m=v;
  m=dpp_fmin_s<0x111,0xf>(m); m=dpp_fmin_s<0x112,0xf>(m); m=dpp_fmin_s<0x114,0xf>(m);
  m=dpp_fmin_s<0x118,0xf>(m); m=dpp_fmin_s<0x142,0xa>(m); m=dpp_fmin_s<0x143,0xc>(m);
  float mall = __int_as_float(__builtin_amdgcn_readlane(__float_as_int(m),63));
  unsigned c = (v==mall)? idx : 0xFFFFFFFFu;
  c=dpp_umin_s<0x111,0xf>(c); c=dpp_umin_s<0x112,0xf>(c); c=dpp_umin_s<0x114,0xf>(c);
  c=dpp_umin_s<0x118,0xf>(c); c=dpp_umin_s<0x142,0xa>(c); c=dpp_umin_s<0x143,0xc>(c);
  return (int)(unsigned)__builtin_amdgcn_readlane((int)c,63);
}

// ================= device bodies =================

__device__ void embed1_body(int bid, const float* __restrict__ x, const float* __restrict__ w1,
                            float* __restrict__ coords, float* __restrict__ t1){
  __shared__ float w[64*3];
  int tid = threadIdx.x;
  if (tid < 192) w[tid] = w1[tid];
  __syncthreads();
  int gid = bid*256 + tid;
  int b = gid / NPTS, n = gid % NPTS;
  float cx = x[(b*3+0)*NPTS + n];
  float cy = x[(b*3+1)*NPTS + n];
  float cz = x[(b*3+2)*NPTS + n];
  coords[gid*3+0]=cx; coords[gid*3+1]=cy; coords[gid*3+2]=cz;
  float* o = t1 + (size_t)gid*64;
  #pragma unroll
  for(int j=0;j<64;j++) o[j] = cx*w[j*3+0] + cy*w[j*3+1] + cz*w[j*3+2];
}

__device__ void wt_body(int gid, const float* __restrict__ w0, float* __restrict__ wt0,
                        const float* __restrict__ w1, float* __restrict__ wt1){
  if(gid < 128*128){
    int o = gid % 128, c = gid / 128;
    wt0[gid] = w0[o*128 + c];
  } else {
    int g2 = gid - 128*128;
    if(g2 >= 256*256) return;
    int o = g2 % 256, c = g2 / 256;
    wt1[g2] = w1[o*256 + c];
  }
}

__device__ void embed2_body(int bid, const float* __restrict__ t1, const float* __restrict__ w2,
                            const float* __restrict__ mean1, const float* __restrict__ rstd1,
                            const float* __restrict__ g1, const float* __restrict__ b1,
                            float* __restrict__ t2, char* smem){
  float (*fin)[64] = (float(*)[64])smem;          // 16 KB
  float* sm = (float*)smem + 4096;
  float* sr = sm+64; float* sg = sr+64; float* sb = sg+64;
  int tid = threadIdx.x;
  if (tid<64){ sm[tid]=mean1[tid]; sr[tid]=rstd1[tid]; sg[tid]=g1[tid]; sb[tid]=b1[tid]; }
  __syncthreads();
  int base = bid*64;
  for(int i=tid;i<4096;i+=256){
    int p=i>>6, c=i&63;
    float v = t1[(size_t)(base+p)*64 + c];
    v = (v - sm[c])*sr[c]*sg[c] + sb[c];
    fin[p][c] = v>0.f ? v : 0.f;
  }
  __syncthreads();
  int o = tid & 63, p0 = tid>>6;
  float acc[16];
  #pragma unroll
  for(int i=0;i<16;i++) acc[i]=0.f;
  for(int cc=0; cc<64; cc+=4){
    float4 wv = *(const float4*)(w2 + o*64 + cc);
    #pragma unroll
    for(int i=0;i<16;i++){
      float4 f4 = *(const float4*)&fin[p0 + i*4][cc];
      acc[i] += f4.x*wv.x + f4.y*wv.y + f4.z*wv.z + f4.w*wv.w;
    }
  }
  #pragma unroll
  for(int i=0;i<16;i++) t2[(size_t)(base+p0+i*4)*64 + o] = acc[i];
}

// multi-wave FPS; reads x [B][3][P]; dyn smem: sx,sy,sz[P], sidx[S], rv64[2*NW]
template<int P, int S, int T>
__device__ void fps_body(int b, const float* __restrict__ x, int* __restrict__ outIdx,
                         float* __restrict__ outXyz, char* smem){
  constexpr int PPT = P/T;
  constexpr int NW  = T/64;
  float* sx=(float*)smem; float* sy=sx+P; float* sz=sy+P;
  int* sidx=(int*)(sz+P);
  unsigned long long* rv64=(unsigned long long*)(sidx+S);
  int tid = threadIdx.x;
  const float* xb = x + (size_t)b*3*P;
  float px[PPT], py[PPT], pz[PPT], dist[PPT];
  #pragma unroll
  for(int i=0;i<PPT;i++){
    int n = i*T + tid;
    float X=xb[n], Y=xb[P+n], Z=xb[2*P+n];
    px[i]=X; py[i]=Y; pz[i]=Z; dist[i]=1e10f;
    sx[n]=X; sy[n]=Y; sz[n]=Z;
  }
  __syncthreads();
  int cur = 0;
  float cx=sx[0], cy=sy[0], cz=sz[0];
  for(int s=0;s<S;s++){
    if(tid==0) sidx[s]=cur;
    if(s==S-1) break;
    float bv=-FLT_MAX; int bi=0;
    #pragma unroll
    for(int i=0;i<PPT;i++){
      float d = sqdist(px[i],py[i],pz[i],cx,cy,cz);
      float nd = fminf(dist[i], d);
      dist[i]=nd;
      int n = i*T + tid;                  // ascending per lane => '>' keeps lowest idx
      if(nd>bv){ bv=nd; bi=n; }
    }
    float mall; int sel;
    wave_argmax_f32(bv,(unsigned)bi,mall,sel);
    int sl = s & 1;
    if((tid&63)==0) rv64[sl*NW+(tid>>6)] = ((unsigned long long)__float_as_uint(mall)<<32)|(unsigned)(~sel);
    __syncthreads();
    unsigned long long wk = rv64[sl*NW];
    #pragma unroll
    for(int w=1;w<NW;w++){ unsigned long long t = rv64[sl*NW+w]; if(t>wk) wk=t; }
    cur = (int)(~(unsigned)wk);
    cx=sx[cur]; cy=sy[cur]; cz=sz[cur];
  }
  __syncthreads();
  for(int i=tid; i<S; i+=T){
    int id = sidx[i];
    outIdx[b*S+i] = id;
    outXyz[((size_t)b*S+i)*3+0] = sx[id];
    outXyz[((size_t)b*S+i)*3+1] = sy[id];
    outXyz[((size_t)b*S+i)*3+2] = sz[id];
  }
}

// single-wave FPS; pts [b][P][3]; dyn smem: sx,sy,sz[P], sidx[S]
template<int P, int S>
__device__ void fps_wave_body(int b, const float* __restrict__ pts, int* __restrict__ outIdx,
                              float* __restrict__ outXyz, char* smem){
  constexpr int PPT = P/64;
  float* sx=(float*)smem; float* sy=sx+P; float* sz=sy+P;
  int* sidx=(int*)(sz+P);
  int lane = threadIdx.x;
  const float* p = pts + (size_t)b*P*3;
  float px[PPT], py[PPT], pz[PPT], dist[PPT];
  #pragma unroll
  for(int i=0;i<PPT;i++){
    int n = i*64 + lane;
    float X=p[n*3], Y=p[n*3+1], Z=p[n*3+2];
    px[i]=X; py[i]=Y; pz[i]=Z; dist[i]=1e10f;
    sx[n]=X; sy[n]=Y; sz[n]=Z;
  }
  __syncthreads();
  int cur = 0;
  float cx=sx[0], cy=sy[0], cz=sz[0];
  for(int s=0;s<S;s++){
    if(lane==0) sidx[s]=cur;
    if(s==S-1) break;
    float bv=-FLT_MAX; int bi=0;
    #pragma unroll
    for(int i=0;i<PPT;i++){
      float d = sqdist(px[i],py[i],pz[i],cx,cy,cz);
      float nd = fminf(dist[i], d);
      dist[i]=nd;
      int n = i*64 + lane;
      if(nd>bv){ bv=nd; bi=n; }
    }
    float mall; int sel;
    wave_argmax_f32(bv,(unsigned)bi,mall,sel);
    cur = sel;
    cx=sx[cur]; cy=sy[cur]; cz=sz[cur];
  }
  __syncthreads();
  for(int i=lane; i<S; i+=64){
    int id = sidx[i];
    outIdx[b*S+i] = id;
    outXyz[((size_t)b*S+i)*3+0] = sx[id];
    outXyz[((size_t)b*S+i)*3+1] = sy[id];
    outXyz[((size_t)b*S+i)*3+2] = sz[id];
  }
}

// one wave per query; dyn smem: d2[P]
template<int P>
__device__ void knn_body(int bq, const float* __restrict__ pts, const float* __restrict__ q,
                         int S, int* __restrict__ knn, char* smem){
  float* d2 = (float*)smem;
  constexpr int E = P/64;
  int lane = threadIdx.x;
  int b = bq / S;
  const float* p = pts + (size_t)b*P*3;
  float qx=q[(size_t)bq*3], qy=q[(size_t)bq*3+1], qz=q[(size_t)bq*3+2];
  #pragma unroll
  for(int i=0;i<E;i++){ int n=i*64+lane; d2[n] = sqdist(qx,qy,qz,p[n*3],p[n*3+1],p[n*3+2]); }
  __syncthreads();
  for(int j=0;j<KK;j++){
    float mv=FLT_MAX; unsigned mi=0xFFFFFFFFu;
    #pragma unroll
    for(int i=0;i<E;i++){
      int n=i*64+lane;
      float v=d2[n];
      if(v<mv){ mv=v; mi=(unsigned)n; }      // ascending n => lowest idx on lane-local tie
    }
    int sel = wave_argmin_f32(mv, mi);
    if(lane==0){ knn[(size_t)bq*KK+j]=sel; d2[sel]=FLT_MAX; }
    __syncthreads();
  }
}

// register-tiled outer-product GEMM; optional fused BN+ReLU; shfl-based stats epilogue
template<int C, int P, bool BN>
__device__ void pass1_body(int bq, const float* __restrict__ feats, const int* __restrict__ knn,
                           const int* __restrict__ fpsIdx, const float* __restrict__ WT,
                           float* __restrict__ hmax, float* __restrict__ hmin,
                           float* __restrict__ part, int S,
                           const float* __restrict__ bmean, const float* __restrict__ brstd,
                           const float* __restrict__ bg, const float* __restrict__ bb){
  constexpr int O   = 2*C;
  constexpr int TPB = C;             // 64 or 128 threads
  constexpr int C4  = C/4;
  constexpr int OG  = O/8;           // 16 or 32
  constexpr int LDC = C+4;
  __shared__ __align__(16) float gfp[KK*LDC];
  __shared__ __align__(16) float cf[C];
  __shared__ __align__(16) float sa[BN?C:1], sbb[BN?C:1];
  __shared__ float sct[O];
  __shared__ float xst[(TPB>64)? 8*O : 1];   // [4 stats][2 waves][O] for 2-wave case
  int tid = threadIdx.x;
  int b = bq / S;
  const float* fb = feats + (size_t)b*P*C;
  int ci = fpsIdx[bq];
  const float* cfg = fb + (size_t)ci*C;
  if(BN){
    float a = brstd[tid]*bg[tid];
    float sh = bb[tid] - bmean[tid]*a;
    sa[tid]=a; sbb[tid]=sh;
    float cv = a*cfg[tid] + sh;
    cf[tid] = cv>0.f ? cv : 0.f;
    __syncthreads();
  } else {
    cf[tid] = cfg[tid];
  }
  for(int i=tid; i<KK*C4; i+=TPB){
    int k = i/C4, d4 = i - k*C4;
    float4 g = ((const float4*)(fb + (size_t)knn[(size_t)bq*KK+k]*C))[d4];
    float4 r;
    if(BN){
      float4 a4 = *(const float4*)&sa[d4*4];
      float4 s4 = *(const float4*)&sbb[d4*4];
      float4 c4 = *(const float4*)&cf[d4*4];
      float gx = a4.x*g.x+s4.x; gx = gx>0.f?gx:0.f;
      float gy = a4.y*g.y+s4.y; gy = gy>0.f?gy:0.f;
      float gz = a4.z*g.z+s4.z; gz = gz>0.f?gz:0.f;
      float gw = a4.w*g.w+s4.w; gw = gw>0.f?gw:0.f;
      r.x=gx-c4.x; r.y=gy-c4.y; r.z=gz-c4.z; r.w=gw-c4.w;
    } else {
      float4 c4 = ((const float4*)cfg)[d4];
      r.x=g.x-c4.x; r.y=g.y-c4.y; r.z=g.z-c4.z; r.w=g.w-c4.w;
    }
    *(float4*)&gfp[k*LDC + d4*4] = r;
  }
  __syncthreads();
  {
    int o2 = tid*2;
    float ct0=0.f, ct1=0.f;
    for(int c=0;c<C;c+=4){
      float4 c4 = *(const float4*)&cf[c];
      #pragma unroll
      for(int t=0;t<4;t++){
        float cv = ((const float*)&c4)[t];
        float2 wh = *(const float2*)&WT[(size_t)(C+c+t)*O + o2];
        ct0 += cv*wh.x; ct1 += cv*wh.y;
      }
    }
    sct[o2]=ct0; sct[o2+1]=ct1;
  }
  __syncthreads();
  int kg = tid / OG;
  int og = tid % OG;
  float acc[8][8];
  #pragma unroll
  for(int a=0;a<8;a++)
    #pragma unroll
    for(int bb2=0;bb2<8;bb2++) acc[a][bb2]=0.f;
  for(int dc=0; dc<C4; dc++){
    float4 g4[8];
    #pragma unroll
    for(int jk=0;jk<8;jk++) g4[jk] = *(const float4*)&gfp[(kg*8+jk)*LDC + dc*4];
    #pragma unroll
    for(int t=0;t<4;t++){
      const float* wrow = WT + (size_t)(dc*4+t)*O + og*8;
      float4 wa = *(const float4*)wrow;
      float4 wb = *(const float4*)(wrow+4);
      #pragma unroll
      for(int jk=0;jk<8;jk++){
        float gs = ((const float*)&g4[jk])[t];
        acc[jk][0] += gs*wa.x; acc[jk][1] += gs*wa.y; acc[jk][2] += gs*wa.z; acc[jk][3] += gs*wa.w;
        acc[jk][4] += gs*wb.x; acc[jk][5] += gs*wb.y; acc[jk][6] += gs*wb.z; acc[jk][7] += gs*wb.w;
      }
    }
  }
  // per-thread partial stats over its 8 k's for 8 o's
  float tmx[8],tmn[8],tsm[8],tsq[8];
  #pragma unroll
  for(int jo=0;jo<8;jo++){
    int o = og*8+jo;
    float ct = sct[o];
    float s=0.f,q=0.f,mx=-FLT_MAX,mn=FLT_MAX;
    #pragma unroll
    for(int jk=0;jk<8;jk++){
      float h = acc[jk][jo] + ct;
      s+=h; q+=h*h; mx=fmaxf(mx,h); mn=fminf(mn,h);
    }
    tmx[jo]=mx; tmn[jo]=mn; tsm[jo]=s; tsq[jo]=q;
  }
  if constexpr (TPB==64){
    // kg groups are lanes og, og+16, og+32, og+48: butterfly xor16 then xor32
    #pragma unroll
    for(int jo=0;jo<8;jo++){
      tmx[jo]=fmaxf(tmx[jo],__shfl_xor(tmx[jo],16)); tmx[jo]=fmaxf(tmx[jo],__shfl_xor(tmx[jo],32));
      tmn[jo]=fminf(tmn[jo],__shfl_xor(tmn[jo],16)); tmn[jo]=fminf(tmn[jo],__shfl_xor(tmn[jo],32));
      tsm[jo]+=__shfl_xor(tsm[jo],16); tsm[jo]+=__shfl_xor(tsm[jo],32);
      tsq[jo]+=__shfl_xor(tsq[jo],16); tsq[jo]+=__shfl_xor(tsq[jo],32);
    }
    if(tid<OG){
      #pragma unroll
      for(int jo=0;jo<8;jo++){
        int o = tid*8+jo;
        hmax[(size_t)bq*O+o]=tmx[jo]; hmin[(size_t)bq*O+o]=tmn[jo];
        part[(size_t)bq*2*O+o]=tsm[jo]; part[(size_t)bq*2*O+O+o]=tsq[jo];
      }
    }
  } else {
    // intra-wave: kg pairs at lane distance 32 share og
    #pragma unroll
    for(int jo=0;jo<8;jo++){
      tmx[jo]=fmaxf(tmx[jo],__shfl_xor(tmx[jo],32));
      tmn[jo]=fminf(tmn[jo],__shfl_xor(tmn[jo],32));
      tsm[jo]+=__shfl_xor(tsm[jo],32);
      tsq[jo]+=__shfl_xor(tsq[jo],32);
    }
    int wv = tid>>6;
    if((tid&63)<32){
      int og_ = tid&31;
      #pragma unroll
      for(int jo=0;jo<8;jo++){
        int o = og_*8+jo;
        xst[0*2*O + wv*O + o]=tmx[jo];
        xst[1*2*O + wv*O + o]=tmn[jo];
        xst[2*2*O + wv*O + o]=tsm[jo];
        xst[3*2*O + wv*O + o]=tsq[jo];
      }
    }
    __syncthreads();
    if(tid<32){
      #pragma unroll
      for(int jo=0;jo<8;jo++){
        int o = tid*8+jo;
        hmax[(size_t)bq*O+o]=fmaxf(xst[0*2*O+o], xst[0*2*O+O+o]);
        hmin[(size_t)bq*O+o]=fminf(xst[1*2*O+o], xst[1*2*O+O+o]);
        part[(size_t)bq*2*O+o]   = xst[2*2*O+o] + xst[2*2*O+O+o];
        part[(size_t)bq*2*O+O+o] = xst[3*2*O+o] + xst[3*2*O+O+o];
      }
    }
  }
}

// ================= kernels =================

__global__ __launch_bounds__(256) void k_embed1_wt(const float* __restrict__ x, const float* __restrict__ w1,
                         float* __restrict__ coords, float* __restrict__ t1,
                         const float* __restrict__ wsg0, float* __restrict__ wt0,
                         const float* __restrict__ wsg1, float* __restrict__ wt1){
  if(blockIdx.x < 128) embed1_body(blockIdx.x, x, w1, coords, t1);
  else wt_body((blockIdx.x-128)*256 + threadIdx.x, wsg0, wt0, wsg1, wt1);
}

__global__ __launch_bounds__(256) void k_stats(const float* __restrict__ t, int M, int C,
                        float* __restrict__ mean, float* __restrict__ rstd){
  int c = blockIdx.x, tid = threadIdx.x;
  float s=0.f, s2=0.f;
  for(int r=tid; r<M; r+=blockDim.x){ float v = t[(size_t)r*C+c]; s+=v; s2+=v*v; }
  __shared__ float bs[256], bq[256];
  bs[tid]=s; bq[tid]=s2; __syncthreads();
  for(int st=128; st>0; st>>=1){ if(tid<st){ bs[tid]+=bs[tid+st]; bq[tid]+=bq[tid+st]; } __syncthreads(); }
  if(tid==0){
    float m = bs[0]/M;
    float v = bq[0]/M - m*m; if(v<0.f) v=0.f;
    mean[c]=m; rstd[c]=rsqrtf(v+EPSV);
  }
}

// fps0 (16 blocks) || embed2 (512 blocks); dyn smem = 25664 B (union)
__global__ __launch_bounds__(256, 1) void k_fps0_embed2(const float* __restrict__ x,
                         int* __restrict__ fps0, float* __restrict__ xyz0,
                         const float* __restrict__ t1, const float* __restrict__ w2,
                         const float* __restrict__ mean1, const float* __restrict__ rstd1,
                         const float* __restrict__ g1, const float* __restrict__ b1,
                         float* __restrict__ t2){
  extern __shared__ char smem[];
  if(blockIdx.x < BATCH) fps_body<NPTS,NS0,256>(blockIdx.x, x, fps0, xyz0, smem);
  else embed2_body(blockIdx.x-BATCH, t1, w2, mean1, rstd1, g1, b1, t2, smem);
}

// fps1 single-wave (16 blocks) || knn0 (4096 blocks); dyn smem = 8192 B (union)
__global__ __launch_bounds__(64, 4) void k_fps1_knn0(const float* __restrict__ xyz0,
                         int* __restrict__ fps1, float* __restrict__ xyz1,
                         const float* __restrict__ coords, int* __restrict__ knn0){
  extern __shared__ char smem[];
  if(blockIdx.x < BATCH) fps_wave_body<NS0,NS1>(blockIdx.x, xyz0, fps1, xyz1, smem);
  else knn_body<NPTS>(blockIdx.x-BATCH, coords, xyz0, NS0, knn0, smem);
}

// pass1a w/ fused BN (4096 blocks) || knn1 (2048 blocks); dyn smem = 1024 B (knn1 d2)
__global__ __launch_bounds__(64, 2) void k_pass1a_knn1(const float* __restrict__ t2,
                         const int* __restrict__ knn0, const int* __restrict__ fps0,
                         const float* __restrict__ wt0,
                         float* __restrict__ hmax0, float* __restrict__ hmin0, float* __restrict__ part0,
                         const float* __restrict__ mean2, const float* __restrict__ rstd2,
                         const float* __restrict__ g2, const float* __restrict__ b2,
                         const float* __restrict__ xyz0, const float* __restrict__ xyz1,
                         int* __restrict__ knn1){
  extern __shared__ char smem[];
  if(blockIdx.x < BATCH*NS0)
    pass1_body<64,NPTS,true>(blockIdx.x, t2, knn0, fps0, wt0, hmax0, hmin0, part0, NS0,
                             mean2, rstd2, g2, b2);
  else
    knn_body<NS0>(blockIdx.x-BATCH*NS0, xyz0, xyz1, NS1, knn1, smem);
}

__global__ __launch_bounds__(128, 2) void k_pass1b(const float* __restrict__ f1,
                         const int* __restrict__ knn1, const int* __restrict__ fps1,
                         const float* __restrict__ wt1,
                         float* __restrict__ hmax1, float* __restrict__ hmin1, float* __restrict__ part1){
  pass1_body<128,NS0,false>(blockIdx.x, f1, knn1, fps1, wt1, hmax1, hmin1, part1, NS1,
                            nullptr, nullptr, nullptr, nullptr);
}

// merged reduce+postmax, one block per channel; f1 layout [row][O]
__global__ __launch_bounds__(256) void k_redpost0(const float* __restrict__ part,
        const float* __restrict__ hmax, const float* __restrict__ hmin,
        const float* __restrict__ g, const float* __restrict__ bb, float* __restrict__ f1){
  constexpr int O=128; constexpr int NB=BATCH*NS0;
  int o = blockIdx.x, tid = threadIdx.x;
  float s=0.f, s2=0.f;
  for(int i=tid;i<NB;i+=256){ s += part[(size_t)i*2*O+o]; s2 += part[(size_t)i*2*O+O+o]; }
  __shared__ float bs[256], bq[256];
  __shared__ float s_sc, s_sh;
  bs[tid]=s; bq[tid]=s2; __syncthreads();
  for(int st=128; st>0; st>>=1){ if(tid<st){ bs[tid]+=bs[tid+st]; bq[tid]+=bq[tid+st]; } __syncthreads(); }
  if(tid==0){
    float M = (float)(NB*KK);
    float m = bs[0]/M;
    float v = bq[0]/M - m*m; if(v<0.f) v=0.f;
    float sc = rsqrtf(v+EPSV)*g[o];
    s_sc = sc; s_sh = bb[o] - m*sc;
  }
  __syncthreads();
  float sc=s_sc, sh=s_sh;
  const float* hs = (sc>=0.f) ? hmax : hmin;
  for(int r=tid; r<NB; r+=256){
    float v = hs[(size_t)r*O+o]*sc + sh;
    f1[(size_t)r*O+o] = v>0.f ? v : 0.f;
  }
}

// merged reduce+postmax with transpose: out [B][256][NS1]
__global__ __launch_bounds__(256) void k_redpost1(const float* __restrict__ part,
        const float* __restrict__ hmax, const float* __restrict__ hmin,
        const float* __restrict__ g, const float* __restrict__ bb, float* __restrict__ out){
  constexpr int O=256; constexpr int NB=BATCH*NS1;
  int o = blockIdx.x, tid = threadIdx.x;
  float s=0.f, s2=0.f;
  for(int i=tid;i<NB;i+=256){ s += part[(size_t)i*2*O+o]; s2 += part[(size_t)i*2*O+O+o]; }
  __shared__ float bs[256], bq[256];
  __shared__ float s_sc, s_sh;
  bs[tid]=s; bq[tid]=s2; __syncthreads();
  for(int st=128; st>0; st>>=1){ if(tid<st){ bs[tid]+=bs[tid+st]; bq[tid]+=bq[tid+st]; } __syncthreads(); }
  if(tid==0){
    float M = (float)(NB*KK);
    float m = bs[0]/M;
    float v = bq[0]/M - m*m; if(v<0.f) v=0.f;
    float sc = rsqrtf(v+EPSV)*g[o];
    s_sc = sc; s_sh = bb[o] - m*sc;
  }
  __syncthreads();
  float sc=s_sc, sh=s_sh;
  const float* hs = (sc>=0.f) ? hmax : hmin;
  for(int r=tid; r<NB; r+=256){
    float v = hs[(size_t)r*O+o]*sc + sh;
    v = v>0.f ? v : 0.f;
    int b = r>>7, ss = r&(NS1-1);
    out[(size_t)b*(256*NS1) + o*NS1 + ss] = v;
  }
}

extern "C" void kernel_launch(void* const* d_in, const int* in_sizes, int n_in,
                              void* d_out, int out_size, void* d_ws, size_t ws_size,
                              hipStream_t stream){
  const float* x    = (const float*)d_in[0];
  const float* w1   = (const float*)d_in[1];
  const float* g1   = (const float*)d_in[2];
  const float* b1   = (const float*)d_in[3];
  const float* w2   = (const float*)d_in[4];
  const float* g2   = (const float*)d_in[5];
  const float* b2   = (const float*)d_in[6];
  const float* wsg0 = (const float*)d_in[7];
  const float* gsg0 = (const float*)d_in[8];
  const float* bsg0 = (const float*)d_in[9];
  const float* wsg1 = (const float*)d_in[10];
  const float* gsg1 = (const float*)d_in[11];
  const float* bsg1 = (const float*)d_in[12];
  float* out = (float*)d_out;

  float* wsf = (float*)d_ws;
  float* coords = wsf;                    wsf += BATCH*NPTS*3;
  float* t1     = wsf;                    wsf += BATCH*NPTS*64;
  float* t2     = wsf;                    wsf += BATCH*NPTS*64;   // raw (pre-BN) embed2 output
  float* mean1=wsf;  wsf+=64;  float* rstd1=wsf;  wsf+=64;
  float* mean2=wsf;  wsf+=64;  float* rstd2=wsf;  wsf+=64;
  int*   fps0 = (int*)wsf;                wsf += BATCH*NS0;
  float* xyz0 = wsf;                      wsf += BATCH*NS0*3;
  int*   knn0 = (int*)wsf;                wsf += BATCH*NS0*KK;
  float* hmax0= wsf;                      wsf += BATCH*NS0*128;
  float* hmin0= wsf;                      wsf += BATCH*NS0*128;
  float* part0= wsf;                      wsf += BATCH*NS0*2*128;
  float* f1   = wsf;                      wsf += BATCH*NS0*128;
  int*   fps1 = (int*)wsf;                wsf += BATCH*NS1;
  float* xyz1 = wsf;                      wsf += BATCH*NS1*3;
  int*   knn1 = (int*)wsf;                wsf += BATCH*NS1*KK;
  float* hmax1= wsf;                      wsf += BATCH*NS1*256;
  float* hmin1= wsf;                      wsf += BATCH*NS1*256;
  float* part1= wsf;                      wsf += BATCH*NS1*2*256;
  float* wt0  = wsf;                      wsf += 128*128;
  float* wt1  = wsf;                      wsf += 256*256;

  const int DYN_L3 = (NPTS*3 + NS0)*4 + 2*4*8;     // sx/sy/sz + sidx + rv64 = 25664
  const int DYN_L5 = NPTS*4;                        // knn0 d2 = 8192 (>= fps1's 3584+512)
  const int DYN_L6 = NS0*4;                         // knn1 d2 = 1024

  // L1: embed1 || weight transposes
  k_embed1_wt<<<dim3(448), dim3(256), 0, stream>>>(x, w1, coords, t1, wsg0, wt0, wsg1, wt1);
  // L2: BN1 stats
  k_stats<<<dim3(64), dim3(256), 0, stream>>>(t1, BATCH*NPTS, 64, mean1, rstd1);
  // L3: fps0 (serial) || embed2 (hidden under fps0)
  k_fps0_embed2<<<dim3(BATCH+512), dim3(256), DYN_L3, stream>>>(x, fps0, xyz0,
                                                  t1, w2, mean1, rstd1, g1, b1, t2);
  // L4: BN2 stats (on raw t2, per reference)
  k_stats<<<dim3(64), dim3(256), 0, stream>>>(t2, BATCH*NPTS, 64, mean2, rstd2);
  // L5: fps1 (single-wave) || knn0
  k_fps1_knn0<<<dim3(BATCH + BATCH*NS0), dim3(64), DYN_L5, stream>>>(xyz0, fps1, xyz1, coords, knn0);
  // L6: pass1a (BN2+ReLU fused into gather) || knn1
  k_pass1a_knn1<<<dim3(BATCH*NS0 + BATCH*NS1), dim3(64), DYN_L6, stream>>>(t2, knn0, fps0, wt0,
                                                  hmax0, hmin0, part0,
                                                  mean2, rstd2, g2, b2,
                                                  xyz0, xyz1, knn1);
  // L7: BN-S0 reduce + epilogue -> f1 (merged)
  k_redpost0<<<dim3(128), dim3(256), 0, stream>>>(part0, hmax0, hmin0, gsg0, bsg0, f1);
  // L8: pass1b
  k_pass1b<<<dim3(BATCH*NS1), dim3(128), 0, stream>>>(f1, knn1, fps1, wt1, hmax1, hmin1, part1);
  // L9: BN-S1 reduce + final epilogue w/ transpose (merged)
  k_redpost1<<<dim3(256), dim3(256), 0, stream>>>(part1, hmax1, hmin1, gsg1, bsg1, out);
}

// Round 10
// 492.603 us; speedup vs baseline: 5.1793x; 1.0130x over previous
//
#include <hip/hip_runtime.h>
#include <float.h>

#define BATCH 16
#define NPTS  2048
#define NS0   256
#define NS1   128
#define KK    32
#define EPSV  1e-5f
#define MROWS 32768.0f   // BATCH*NPTS

// exact numpy-order squared distance: ((dx*dx + dy*dy) + dz*dz), no FMA contraction
__device__ __forceinline__ float sqdist(float ax,float ay,float az,float bx,float by,float bz){
  float dx=__fsub_rn(ax,bx), dy=__fsub_rn(ay,by), dz=__fsub_rn(az,bz);
  return __fadd_rn(__fadd_rn(__fmul_rn(dx,dx),__fmul_rn(dy,dy)),__fmul_rn(dz,dz));
}

// ---- native f32/u32 DPP ladders (cheap wave64 reduce; winner broadcast via readlane 63)
template<int CTRL,int RM>
__device__ __forceinline__ float dpp_fmax_s(float x){
  int t = __builtin_amdgcn_update_dpp((int)0xFF800000, __float_as_int(x), CTRL, RM, 0xf, false);
  return fmaxf(x, __int_as_float(t));
}
template<int CTRL,int RM>
__device__ __forceinline__ float dpp_fmin_s(float x){
  int t = __builtin_amdgcn_update_dpp(0x7F800000, __float_as_int(x), CTRL, RM, 0xf, false);
  return fminf(x, __int_as_float(t));
}
template<int CTRL,int RM>
__device__ __forceinline__ unsigned dpp_umin_s(unsigned x){
  unsigned t = (unsigned)__builtin_amdgcn_update_dpp(-1, (int)x, CTRL, RM, 0xf, false);
  return t<x ? t : x;
}
// argmax over (v,idx): max value, tie -> lowest idx (matches np.argmax first-occurrence)
__device__ __forceinline__ void wave_argmax_f32(float v, unsigned idx, float& mall, int& sel){
  float m=v;
  m=dpp_fmax_s<0x111,0xf>(m); m=dpp_fmax_s<0x112,0xf>(m); m=dpp_fmax_s<0x114,0xf>(m);
  m=dpp_fmax_s<0x118,0xf>(m); m=dpp_fmax_s<0x142,0xa>(m); m=dpp_fmax_s<0x143,0xc>(m);
  mall = __int_as_float(__builtin_amdgcn_readlane(__float_as_int(m),63));
  unsigned c = (v==mall)? idx : 0xFFFFFFFFu;
  c=dpp_umin_s<0x111,0xf>(c); c=dpp_umin_s<0x112,0xf>(c); c=dpp_umin_s<0x114,0xf>(c);
  c=dpp_umin_s<0x118,0xf>(c); c=dpp_umin_s<0x142,0xa>(c); c=dpp_umin_s<0x143,0xc>(c);
  sel = (int)(unsigned)__builtin_amdgcn_readlane((int)c,63);
}
// argmin over (v,idx): min value, tie -> lowest idx (matches stable top_k)
__device__ __forceinline__ int wave_argmin_f32(float v, unsigned idx){
  float m=v;
  m=dpp_fmin_s<0x111,0xf>(m); m=dpp_fmin_s<0x112,0xf>(m); m=dpp_fmin_s<0x114,0xf>(m);
  m=dpp_fmin_s<0x118,0xf>(m); m=dpp_fmin_s<0x142,0xa>(m); m=dpp_fmin_s<0x143,0xc>(m);
  float mall = __int_as_float(__builtin_amdgcn_readlane(__float_as_int(m),63));
  unsigned c = (v==mall)? idx : 0xFFFFFFFFu;
  c=dpp_umin_s<0x111,0xf>(c); c=dpp_umin_s<0x112,0xf>(c); c=dpp_umin_s<0x114,0xf>(c);
  c=dpp_umin_s<0x118,0xf>(c); c=dpp_umin_s<0x142,0xa>(c); c=dpp_umin_s<0x143,0xc>(c);
  return (int)(unsigned)__builtin_amdgcn_readlane((int)c,63);
}

// ================= device bodies =================

__device__ void embed1_body(int bid, const float* __restrict__ x, const float* __restrict__ w1,
                            float* __restrict__ coords, float* __restrict__ t1){
  __shared__ float w[64*3];
  int tid = threadIdx.x;
  if (tid < 192) w[tid] = w1[tid];
  __syncthreads();
  int gid = bid*256 + tid;
  int b = gid / NPTS, n = gid % NPTS;
  float cx = x[(b*3+0)*NPTS + n];
  float cy = x[(b*3+1)*NPTS + n];
  float cz = x[(b*3+2)*NPTS + n];
  coords[gid*3+0]=cx; coords[gid*3+1]=cy; coords[gid*3+2]=cz;
  float* o = t1 + (size_t)gid*64;
  #pragma unroll
  for(int j=0;j<64;j++) o[j] = cx*w[j*3+0] + cy*w[j*3+1] + cz*w[j*3+2];
}

__device__ void wt_body(int gid, const float* __restrict__ w0, float* __restrict__ wt0,
                        const float* __restrict__ w1, float* __restrict__ wt1){
  if(gid < 128*128){
    int o = gid % 128, c = gid / 128;
    wt0[gid] = w0[o*128 + c];
  } else {
    int g2 = gid - 128*128;
    if(g2 >= 256*256) return;
    int o = g2 % 256, c = g2 / 256;
    wt1[g2] = w1[o*256 + c];
  }
}

// coalesced per-block channel sums + one atomic per channel per block (64 thr)
__device__ void statsA_body(int blk, const float* __restrict__ t,
                            float* __restrict__ accS, float* __restrict__ accQ){
  int c = threadIdx.x;            // channel 0..63
  int r0 = blk*128;
  float s=0.f, q=0.f;
  for(int r=0;r<128;r++){
    float v = t[(size_t)(r0+r)*64 + c];   // wave-load = one contiguous 256B row
    s+=v; q+=v*v;
  }
  atomicAdd(accS+c, s);
  atomicAdd(accQ+c, q);
}

// embed2: BN1 computed inline from atomic sums
__device__ void embed2_body(int bid, const float* __restrict__ t1, const float* __restrict__ w2,
                            const float* __restrict__ accS, const float* __restrict__ accQ,
                            const float* __restrict__ g1, const float* __restrict__ b1,
                            float* __restrict__ t2, char* smem){
  float (*fin)[64] = (float(*)[64])smem;          // 16 KB
  float* sm = (float*)smem + 4096;
  float* sr = sm+64; float* sg = sr+64; float* sb = sg+64;
  int tid = threadIdx.x;
  if (tid<64){
    float S=accS[tid], Q=accQ[tid];
    float m = S/MROWS, v = Q/MROWS - m*m; if(v<0.f) v=0.f;
    sm[tid]=m; sr[tid]=rsqrtf(v+EPSV); sg[tid]=g1[tid]; sb[tid]=b1[tid];
  }
  __syncthreads();
  int base = bid*64;
  for(int i=tid;i<4096;i+=256){
    int p=i>>6, c=i&63;
    float v = t1[(size_t)(base+p)*64 + c];
    v = (v - sm[c])*sr[c]*sg[c] + sb[c];
    fin[p][c] = v>0.f ? v : 0.f;
  }
  __syncthreads();
  int o = tid & 63, p0 = tid>>6;
  float acc[16];
  #pragma unroll
  for(int i=0;i<16;i++) acc[i]=0.f;
  for(int cc=0; cc<64; cc+=4){
    float4 wv = *(const float4*)(w2 + o*64 + cc);
    #pragma unroll
    for(int i=0;i<16;i++){
      float4 f4 = *(const float4*)&fin[p0 + i*4][cc];
      acc[i] += f4.x*wv.x + f4.y*wv.y + f4.z*wv.z + f4.w*wv.w;
    }
  }
  #pragma unroll
  for(int i=0;i<16;i++) t2[(size_t)(base+p0+i*4)*64 + o] = acc[i];
}

// multi-wave FPS v5: coords fused into the cross-wave exchange (no LDS point staging,
// no dependent second LDS read round). Reads x [B][3][P] directly.
template<int P, int S, int T>
__device__ void fps_body(int b, const float* __restrict__ x, int* __restrict__ outIdx,
                         float* __restrict__ outXyz, char* smem){
  constexpr int PPT = P/T;       // 8
  constexpr int NW  = T/64;      // 4
  float* ex = (float*)smem;                       // [2][NW][8]: key.hi,key.lo,x,y,z
  int* sidx = (int*)(smem + 2*NW*8*sizeof(float));
  int tid = threadIdx.x, wv = tid>>6;
  const float* xb = x + (size_t)b*3*P;
  float px[PPT], py[PPT], pz[PPT], dist[PPT];
  #pragma unroll
  for(int i=0;i<PPT;i++){
    int n = i*T + tid;                            // interleaved: coalesced
    px[i]=xb[n]; py[i]=xb[P+n]; pz[i]=xb[2*P+n];
    dist[i]=1e10f;
  }
  int cur = 0;
  float cx = xb[0], cy = xb[P], cz = xb[2*P];     // uniform broadcast load, once
  for(int s=0;s<S;s++){
    if(tid==0) sidx[s]=cur;
    if(s==S-1) break;
    float bv=-FLT_MAX; int bi=0;
    #pragma unroll
    for(int i=0;i<PPT;i++){
      float d = sqdist(px[i],py[i],pz[i],cx,cy,cz);
      float nd = fminf(dist[i], d);
      dist[i]=nd;
      int n = i*T + tid;                          // ascending per lane => '>' keeps lowest idx
      if(nd>bv){ bv=nd; bi=n; }
    }
    float mall; int sel;
    wave_argmax_f32(bv,(unsigned)bi,mall,sel);    // wave winner (uniform per wave)
    int isel = sel / T;                           // winner's slot: wave-uniform
    float wx=px[0], wy=py[0], wz=pz[0];
    #pragma unroll
    for(int i=1;i<PPT;i++){ if(isel==i){ wx=px[i]; wy=py[i]; wz=pz[i]; } }
    int sl = s & 1;
    if(tid == (sel & (T-1))){                     // owner lane writes candidate+coords
      float* e = ex + (size_t)(sl*NW + wv)*8;
      e[0] = mall;                                // dist >= 0: bit-pattern monotone
      e[1] = __uint_as_float(~(unsigned)sel);     // larger = smaller idx
      e[2] = wx; e[3] = wy; e[4] = wz;
    }
    __syncthreads();
    const float* e0 = ex + (size_t)(sl*NW)*8;     // broadcast reads, all independent
    unsigned bh = __float_as_uint(e0[0]), blo = __float_as_uint(e0[1]);
    float nx=e0[2], ny=e0[3], nz=e0[4];
    #pragma unroll
    for(int w=1;w<NW;w++){
      const float* e = e0 + (size_t)w*8;
      unsigned h = __float_as_uint(e[0]), l = __float_as_uint(e[1]);
      bool gt = (h > bh) || (h == bh && l > blo);
      if(gt){ bh=h; blo=l; nx=e[2]; ny=e[3]; nz=e[4]; }
    }
    cur = (int)(~blo);
    cx=nx; cy=ny; cz=nz;
  }
  __syncthreads();
  for(int i=tid; i<S; i+=T){
    int id = sidx[i];
    outIdx[b*S+i] = id;
    outXyz[((size_t)b*S+i)*3+0] = xb[id];
    outXyz[((size_t)b*S+i)*3+1] = xb[P+id];
    outXyz[((size_t)b*S+i)*3+2] = xb[2*P+id];
  }
}

// single-wave FPS; pts [b][P][3]; dyn smem: sx,sy,sz[P], sidx[S]
template<int P, int S>
__device__ void fps_wave_body(int b, const float* __restrict__ pts, int* __restrict__ outIdx,
                              float* __restrict__ outXyz, char* smem){
  constexpr int PPT = P/64;
  float* sx=(float*)smem; float* sy=sx+P; float* sz=sy+P;
  int* sidx=(int*)(sz+P);
  int lane = threadIdx.x;
  const float* p = pts + (size_t)b*P*3;
  float px[PPT], py[PPT], pz[PPT], dist[PPT];
  #pragma unroll
  for(int i=0;i<PPT;i++){
    int n = i*64 + lane;
    float X=p[n*3], Y=p[n*3+1], Z=p[n*3+2];
    px[i]=X; py[i]=Y; pz[i]=Z; dist[i]=1e10f;
    sx[n]=X; sy[n]=Y; sz[n]=Z;
  }
  __syncthreads();
  int cur = 0;
  float cx=sx[0], cy=sy[0], cz=sz[0];
  for(int s=0;s<S;s++){
    if(lane==0) sidx[s]=cur;
    if(s==S-1) break;
    float bv=-FLT_MAX; int bi=0;
    #pragma unroll
    for(int i=0;i<PPT;i++){
      float d = sqdist(px[i],py[i],pz[i],cx,cy,cz);
      float nd = fminf(dist[i], d);
      dist[i]=nd;
      int n = i*64 + lane;
      if(nd>bv){ bv=nd; bi=n; }
    }
    float mall; int sel;
    wave_argmax_f32(bv,(unsigned)bi,mall,sel);
    cur = sel;
    cx=sx[cur]; cy=sy[cur]; cz=sz[cur];
  }
  __syncthreads();
  for(int i=lane; i<S; i+=64){
    int id = sidx[i];
    outIdx[b*S+i] = id;
    outXyz[((size_t)b*S+i)*3+0] = sx[id];
    outXyz[((size_t)b*S+i)*3+1] = sy[id];
    outXyz[((size_t)b*S+i)*3+2] = sz[id];
  }
}

// one wave per query; dyn smem: d2[P]
template<int P>
__device__ void knn_body(int bq, const float* __restrict__ pts, const float* __restrict__ q,
                         int S, int* __restrict__ knn, char* smem){
  float* d2 = (float*)smem;
  constexpr int E = P/64;
  int lane = threadIdx.x;
  int b = bq / S;
  const float* p = pts + (size_t)b*P*3;
  float qx=q[(size_t)bq*3], qy=q[(size_t)bq*3+1], qz=q[(size_t)bq*3+2];
  #pragma unroll
  for(int i=0;i<E;i++){ int n=i*64+lane; d2[n] = sqdist(qx,qy,qz,p[n*3],p[n*3+1],p[n*3+2]); }
  __syncthreads();
  for(int j=0;j<KK;j++){
    float mv=FLT_MAX; unsigned mi=0xFFFFFFFFu;
    #pragma unroll
    for(int i=0;i<E;i++){
      int n=i*64+lane;
      float v=d2[n];
      if(v<mv){ mv=v; mi=(unsigned)n; }
    }
    int sel = wave_argmin_f32(mv, mi);
    if(lane==0){ knn[(size_t)bq*KK+j]=sel; d2[sel]=FLT_MAX; }
    __syncthreads();
  }
}

// register-tiled outer-product GEMM; optional fused BN+ReLU (stats from atomic sums)
template<int C, int P, bool BN>
__device__ void pass1_body(int bq, const float* __restrict__ feats, const int* __restrict__ knn,
                           const int* __restrict__ fpsIdx, const float* __restrict__ WT,
                           float* __restrict__ hmax, float* __restrict__ hmin,
                           float* __restrict__ part, int S,
                           const float* __restrict__ accS, const float* __restrict__ accQ,
                           const float* __restrict__ bg, const float* __restrict__ bb){
  constexpr int O   = 2*C;
  constexpr int TPB = C;
  constexpr int C4  = C/4;
  constexpr int OG  = O/8;
  constexpr int LDC = C+4;
  __shared__ __align__(16) float gfp[KK*LDC];
  __shared__ __align__(16) float cf[C];
  __shared__ __align__(16) float sa[BN?C:1], sbb[BN?C:1];
  __shared__ float sct[O];
  __shared__ float xst[(TPB>64)? 8*O : 1];
  int tid = threadIdx.x;
  int b = bq / S;
  const float* fb = feats + (size_t)b*P*C;
  int ci = fpsIdx[bq];
  const float* cfg = fb + (size_t)ci*C;
  if(BN){
    float S_=accS[tid], Q_=accQ[tid];
    float m = S_/MROWS, vv = Q_/MROWS - m*m; if(vv<0.f) vv=0.f;
    float a = rsqrtf(vv+EPSV)*bg[tid];
    float sh = bb[tid] - m*a;
    sa[tid]=a; sbb[tid]=sh;
    float cv = a*cfg[tid] + sh;
    cf[tid] = cv>0.f ? cv : 0.f;
    __syncthreads();
  } else {
    cf[tid] = cfg[tid];
  }
  for(int i=tid; i<KK*C4; i+=TPB){
    int k = i/C4, d4 = i - k*C4;
    float4 g = ((const float4*)(fb + (size_t)knn[(size_t)bq*KK+k]*C))[d4];
    float4 r;
    if(BN){
      float4 a4 = *(const float4*)&sa[d4*4];
      float4 s4 = *(const float4*)&sbb[d4*4];
      float4 c4 = *(const float4*)&cf[d4*4];
      float gx = a4.x*g.x+s4.x; gx = gx>0.f?gx:0.f;
      float gy = a4.y*g.y+s4.y; gy = gy>0.f?gy:0.f;
      float gz = a4.z*g.z+s4.z; gz = gz>0.f?gz:0.f;
      float gw = a4.w*g.w+s4.w; gw = gw>0.f?gw:0.f;
      r.x=gx-c4.x; r.y=gy-c4.y; r.z=gz-c4.z; r.w=gw-c4.w;
    } else {
      float4 c4 = ((const float4*)cfg)[d4];
      r.x=g.x-c4.x; r.y=g.y-c4.y; r.z=g.z-c4.z; r.w=g.w-c4.w;
    }
    *(float4*)&gfp[k*LDC + d4*4] = r;
  }
  __syncthreads();
  {
    int o2 = tid*2;
    float ct0=0.f, ct1=0.f;
    for(int c=0;c<C;c+=4){
      float4 c4 = *(const float4*)&cf[c];
      #pragma unroll
      for(int t=0;t<4;t++){
        float cv = ((const float*)&c4)[t];
        float2 wh = *(const float2*)&WT[(size_t)(C+c+t)*O + o2];
        ct0 += cv*wh.x; ct1 += cv*wh.y;
      }
    }
    sct[o2]=ct0; sct[o2+1]=ct1;
  }
  __syncthreads();
  int kg = tid / OG;
  int og = tid % OG;
  float acc[8][8];
  #pragma unroll
  for(int a=0;a<8;a++)
    #pragma unroll
    for(int bb2=0;bb2<8;bb2++) acc[a][bb2]=0.f;
  for(int dc=0; dc<C4; dc++){
    float4 g4[8];
    #pragma unroll
    for(int jk=0;jk<8;jk++) g4[jk] = *(const float4*)&gfp[(kg*8+jk)*LDC + dc*4];
    #pragma unroll
    for(int t=0;t<4;t++){
      const float* wrow = WT + (size_t)(dc*4+t)*O + og*8;
      float4 wa = *(const float4*)wrow;
      float4 wb = *(const float4*)(wrow+4);
      #pragma unroll
      for(int jk=0;jk<8;jk++){
        float gs = ((const float*)&g4[jk])[t];
        acc[jk][0] += gs*wa.x; acc[jk][1] += gs*wa.y; acc[jk][2] += gs*wa.z; acc[jk][3] += gs*wa.w;
        acc[jk][4] += gs*wb.x; acc[jk][5] += gs*wb.y; acc[jk][6] += gs*wb.z; acc[jk][7] += gs*wb.w;
      }
    }
  }
  float tmx[8],tmn[8],tsm[8],tsq[8];
  #pragma unroll
  for(int jo=0;jo<8;jo++){
    int o = og*8+jo;
    float ct = sct[o];
    float s=0.f,q=0.f,mx=-FLT_MAX,mn=FLT_MAX;
    #pragma unroll
    for(int jk=0;jk<8;jk++){
      float h = acc[jk][jo] + ct;
      s+=h; q+=h*h; mx=fmaxf(mx,h); mn=fminf(mn,h);
    }
    tmx[jo]=mx; tmn[jo]=mn; tsm[jo]=s; tsq[jo]=q;
  }
  if constexpr (TPB==64){
    #pragma unroll
    for(int jo=0;jo<8;jo++){
      tmx[jo]=fmaxf(tmx[jo],__shfl_xor(tmx[jo],16)); tmx[jo]=fmaxf(tmx[jo],__shfl_xor(tmx[jo],32));
      tmn[jo]=fminf(tmn[jo],__shfl_xor(tmn[jo],16)); tmn[jo]=fminf(tmn[jo],__shfl_xor(tmn[jo],32));
      tsm[jo]+=__shfl_xor(tsm[jo],16); tsm[jo]+=__shfl_xor(tsm[jo],32);
      tsq[jo]+=__shfl_xor(tsq[jo],16); tsq[jo]+=__shfl_xor(tsq[jo],32);
    }
    if(tid<OG){
      #pragma unroll
      for(int jo=0;jo<8;jo++){
        int o = tid*8+jo;
        hmax[(size_t)bq*O+o]=tmx[jo]; hmin[(size_t)bq*O+o]=tmn[jo];
        part[(size_t)bq*2*O+o]=tsm[jo]; part[(size_t)bq*2*O+O+o]=tsq[jo];
      }
    }
  } else {
    #pragma unroll
    for(int jo=0;jo<8;jo++){
      tmx[jo]=fmaxf(tmx[jo],__shfl_xor(tmx[jo],32));
      tmn[jo]=fminf(tmn[jo],__shfl_xor(tmn[jo],32));
      tsm[jo]+=__shfl_xor(tsm[jo],32);
      tsq[jo]+=__shfl_xor(tsq[jo],32);
    }
    int wv = tid>>6;
    if((tid&63)<32){
      int og_ = tid&31;
      #pragma unroll
      for(int jo=0;jo<8;jo++){
        int o = og_*8+jo;
        xst[0*2*O + wv*O + o]=tmx[jo];
        xst[1*2*O + wv*O + o]=tmn[jo];
        xst[2*2*O + wv*O + o]=tsm[jo];
        xst[3*2*O + wv*O + o]=tsq[jo];
      }
    }
    __syncthreads();
    if(tid<32){
      #pragma unroll
      for(int jo=0;jo<8;jo++){
        int o = tid*8+jo;
        hmax[(size_t)bq*O+o]=fmaxf(xst[0*2*O+o], xst[0*2*O+O+o]);
        hmin[(size_t)bq*O+o]=fminf(xst[1*2*O+o], xst[1*2*O+O+o]);
        part[(size_t)bq*2*O+o]   = xst[2*2*O+o] + xst[2*2*O+O+o];
        part[(size_t)bq*2*O+O+o] = xst[3*2*O+o] + xst[3*2*O+O+o];
      }
    }
  }
}

// ================= kernels =================

// L1: embed1 (0..127) || wt (128..447) || zero accums (448)
__global__ __launch_bounds__(256) void k_embed1_wt(const float* __restrict__ x, const float* __restrict__ w1,
                         float* __restrict__ coords, float* __restrict__ t1,
                         const float* __restrict__ wsg0, float* __restrict__ wt0,
                         const float* __restrict__ wsg1, float* __restrict__ wt1,
                         float* __restrict__ accz){
  if(blockIdx.x < 128) embed1_body(blockIdx.x, x, w1, coords, t1);
  else if(blockIdx.x < 448) wt_body((blockIdx.x-128)*256 + threadIdx.x, wsg0, wt0, wsg1, wt1);
  else accz[threadIdx.x] = 0.f;   // acc1S|acc1Q|acc2S|acc2Q = 256 floats contiguous
}

// L2: BN1 stats, coalesced + atomic
__global__ __launch_bounds__(64) void k_statsA(const float* __restrict__ t,
                         float* __restrict__ accS, float* __restrict__ accQ){
  statsA_body(blockIdx.x, t, accS, accQ);
}

// L3: fps0 (16 blocks) || embed2 (512 blocks); dyn smem = 17408 B
__global__ __launch_bounds__(256, 1) void k_fps0_embed2(const float* __restrict__ x,
                         int* __restrict__ fps0, float* __restrict__ xyz0,
                         const float* __restrict__ t1, const float* __restrict__ w2,
                         const float* __restrict__ acc1S, const float* __restrict__ acc1Q,
                         const float* __restrict__ g1, const float* __restrict__ b1,
                         float* __restrict__ t2){
  extern __shared__ char smem[];
  if(blockIdx.x < BATCH) fps_body<NPTS,NS0,256>(blockIdx.x, x, fps0, xyz0, smem);
  else embed2_body(blockIdx.x-BATCH, t1, w2, acc1S, acc1Q, g1, b1, t2, smem);
}

// L4: fps1 (16) || knn0 (4096) || stats2 (256); dyn smem = 8192 B
__global__ __launch_bounds__(64, 4) void k_fps1_knn0_st2(const float* __restrict__ xyz0,
                         int* __restrict__ fps1, float* __restrict__ xyz1,
                         const float* __restrict__ coords, int* __restrict__ knn0,
                         const float* __restrict__ t2,
                         float* __restrict__ acc2S, float* __restrict__ acc2Q){
  extern __shared__ char smem[];
  if(blockIdx.x < BATCH) fps_wave_body<NS0,NS1>(blockIdx.x, xyz0, fps1, xyz1, smem);
  else if(blockIdx.x < BATCH + BATCH*NS0) knn_body<NPTS>(blockIdx.x-BATCH, coords, xyz0, NS0, knn0, smem);
  else statsA_body(blockIdx.x - (BATCH + BATCH*NS0), t2, acc2S, acc2Q);
}

// L5: pass1a w/ fused BN (4096) || knn1 (2048); dyn smem = 1024 B
__global__ __launch_bounds__(64, 2) void k_pass1a_knn1(const float* __restrict__ t2,
                         const int* __restrict__ knn0, const int* __restrict__ fps0,
                         const float* __restrict__ wt0,
                         float* __restrict__ hmax0, float* __restrict__ hmin0, float* __restrict__ part0,
                         const float* __restrict__ acc2S, const float* __restrict__ acc2Q,
                         const float* __restrict__ g2, const float* __restrict__ b2,
                         const float* __restrict__ xyz0, const float* __restrict__ xyz1,
                         int* __restrict__ knn1){
  extern __shared__ char smem[];
  if(blockIdx.x < BATCH*NS0)
    pass1_body<64,NPTS,true>(blockIdx.x, t2, knn0, fps0, wt0, hmax0, hmin0, part0, NS0,
                             acc2S, acc2Q, g2, b2);
  else
    knn_body<NS0>(blockIdx.x-BATCH*NS0, xyz0, xyz1, NS1, knn1, smem);
}

__global__ __launch_bounds__(128, 2) void k_pass1b(const float* __restrict__ f1,
                         const int* __restrict__ knn1, const int* __restrict__ fps1,
                         const float* __restrict__ wt1,
                         float* __restrict__ hmax1, float* __restrict__ hmin1, float* __restrict__ part1){
  pass1_body<128,NS0,false>(blockIdx.x, f1, knn1, fps1, wt1, hmax1, hmin1, part1, NS1,
                            nullptr, nullptr, nullptr, nullptr);
}

// merged reduce+postmax, one block per channel; f1 layout [row][O]
__global__ __launch_bounds__(256) void k_redpost0(const float* __restrict__ part,
        const float* __restrict__ hmax, const float* __restrict__ hmin,
        const float* __restrict__ g, const float* __restrict__ bb, float* __restrict__ f1){
  constexpr int O=128; constexpr int NB=BATCH*NS0;
  int o = blockIdx.x, tid = threadIdx.x;
  float s=0.f, s2=0.f;
  for(int i=tid;i<NB;i+=256){ s += part[(size_t)i*2*O+o]; s2 += part[(size_t)i*2*O+O+o]; }
  __shared__ float bs[256], bq[256];
  __shared__ float s_sc, s_sh;
  bs[tid]=s; bq[tid]=s2; __syncthreads();
  for(int st=128; st>0; st>>=1){ if(tid<st){ bs[tid]+=bs[tid+st]; bq[tid]+=bq[tid+st]; } __syncthreads(); }
  if(tid==0){
    float M = (float)(NB*KK);
    float m = bs[0]/M;
    float v = bq[0]/M - m*m; if(v<0.f) v=0.f;
    float sc = rsqrtf(v+EPSV)*g[o];
    s_sc = sc; s_sh = bb[o] - m*sc;
  }
  __syncthreads();
  float sc=s_sc, sh=s_sh;
  const float* hs = (sc>=0.f) ? hmax : hmin;
  for(int r=tid; r<NB; r+=256){
    float v = hs[(size_t)r*O+o]*sc + sh;
    f1[(size_t)r*O+o] = v>0.f ? v : 0.f;
  }
}

// merged reduce+postmax with transpose: out [B][256][NS1]
__global__ __launch_bounds__(256) void k_redpost1(const float* __restrict__ part,
        const float* __restrict__ hmax, const float* __restrict__ hmin,
        const float* __restrict__ g, const float* __restrict__ bb, float* __restrict__ out){
  constexpr int O=256; constexpr int NB=BATCH*NS1;
  int o = blockIdx.x, tid = threadIdx.x;
  float s=0.f, s2=0.f;
  for(int i=tid;i<NB;i+=256){ s += part[(size_t)i*2*O+o]; s2 += part[(size_t)i*2*O+O+o]; }
  __shared__ float bs[256], bq[256];
  __shared__ float s_sc, s_sh;
  bs[tid]=s; bq[tid]=s2; __syncthreads();
  for(int st=128; st>0; st>>=1){ if(tid<st){ bs[tid]+=bs[tid+st]; bq[tid]+=bq[tid+st]; } __syncthreads(); }
  if(tid==0){
    float M = (float)(NB*KK);
    float m = bs[0]/M;
    float v = bq[0]/M - m*m; if(v<0.f) v=0.f;
    float sc = rsqrtf(v+EPSV)*g[o];
    s_sc = sc; s_sh = bb[o] - m*sc;
  }
  __syncthreads();
  float sc=s_sc, sh=s_sh;
  const float* hs = (sc>=0.f) ? hmax : hmin;
  for(int r=tid; r<NB; r+=256){
    float v = hs[(size_t)r*O+o]*sc + sh;
    v = v>0.f ? v : 0.f;
    int b = r>>7, ss = r&(NS1-1);
    out[(size_t)b*(256*NS1) + o*NS1 + ss] = v;
  }
}

extern "C" void kernel_launch(void* const* d_in, const int* in_sizes, int n_in,
                              void* d_out, int out_size, void* d_ws, size_t ws_size,
                              hipStream_t stream){
  const float* x    = (const float*)d_in[0];
  const float* w1   = (const float*)d_in[1];
  const float* g1   = (const float*)d_in[2];
  const float* b1   = (const float*)d_in[3];
  const float* w2   = (const float*)d_in[4];
  const float* g2   = (const float*)d_in[5];
  const float* b2   = (const float*)d_in[6];
  const float* wsg0 = (const float*)d_in[7];
  const float* gsg0 = (const float*)d_in[8];
  const float* bsg0 = (const float*)d_in[9];
  const float* wsg1 = (const float*)d_in[10];
  const float* gsg1 = (const float*)d_in[11];
  const float* bsg1 = (const float*)d_in[12];
  float* out = (float*)d_out;

  float* wsf = (float*)d_ws;
  float* coords = wsf;                    wsf += BATCH*NPTS*3;
  float* t1     = wsf;                    wsf += BATCH*NPTS*64;
  float* t2     = wsf;                    wsf += BATCH*NPTS*64;   // raw (pre-BN) embed2 output
  float* acc1S=wsf; wsf+=64;  float* acc1Q=wsf; wsf+=64;          // contiguous 256-float accum block
  float* acc2S=wsf; wsf+=64;  float* acc2Q=wsf; wsf+=64;
  int*   fps0 = (int*)wsf;                wsf += BATCH*NS0;
  float* xyz0 = wsf;                      wsf += BATCH*NS0*3;
  int*   knn0 = (int*)wsf;                wsf += BATCH*NS0*KK;
  float* hmax0= wsf;                      wsf += BATCH*NS0*128;
  float* hmin0= wsf;                      wsf += BATCH*NS0*128;
  float* part0= wsf;                      wsf += BATCH*NS0*2*128;
  float* f1   = wsf;                      wsf += BATCH*NS0*128;
  int*   fps1 = (int*)wsf;                wsf += BATCH*NS1;
  float* xyz1 = wsf;                      wsf += BATCH*NS1*3;
  int*   knn1 = (int*)wsf;                wsf += BATCH*NS1*KK;
  float* hmax1= wsf;                      wsf += BATCH*NS1*256;
  float* hmin1= wsf;                      wsf += BATCH*NS1*256;
  float* part1= wsf;                      wsf += BATCH*NS1*2*256;
  float* wt0  = wsf;                      wsf += 128*128;
  float* wt1  = wsf;                      wsf += 256*256;

  const int DYN_L3 = 4352*4;                  // embed2 fin+bn arrays (>= fps0's 1.3KB)
  const int DYN_L4 = NPTS*4;                  // knn0 d2 = 8192 (>= fps1's 3.6KB)
  const int DYN_L5 = NS0*4;                   // knn1 d2 = 1024

  // L1: embed1 || weight transposes || zero stats accumulators
  k_embed1_wt<<<dim3(449), dim3(256), 0, stream>>>(x, w1, coords, t1, wsg0, wt0, wsg1, wt1, acc1S);
  // L2: BN1 stats (coalesced + atomic)
  k_statsA<<<dim3(256), dim3(64), 0, stream>>>(t1, acc1S, acc1Q);
  // L3: fps0 (serial, exchange-fused) || embed2 (BN1 from sums, hidden under fps0)
  k_fps0_embed2<<<dim3(BATCH+512), dim3(256), DYN_L3, stream>>>(x, fps0, xyz0,
                                                  t1, w2, acc1S, acc1Q, g1, b1, t2);
  // L4: fps1 || knn0 || BN2 stats
  k_fps1_knn0_st2<<<dim3(BATCH + BATCH*NS0 + 256), dim3(64), DYN_L4, stream>>>(
                                                  xyz0, fps1, xyz1, coords, knn0, t2, acc2S, acc2Q);
  // L5: pass1a (BN2+ReLU fused, stats from sums) || knn1
  k_pass1a_knn1<<<dim3(BATCH*NS0 + BATCH*NS1), dim3(64), DYN_L5, stream>>>(t2, knn0, fps0, wt0,
                                                  hmax0, hmin0, part0,
                                                  acc2S, acc2Q, g2, b2,
                                                  xyz0, xyz1, knn1);
  // L6: BN-S0 reduce + epilogue -> f1
  k_redpost0<<<dim3(128), dim3(256), 0, stream>>>(part0, hmax0, hmin0, gsg0, bsg0, f1);
  // L7: pass1b
  k_pass1b<<<dim3(BATCH*NS1), dim3(128), 0, stream>>>(f1, knn1, fps1, wt1, hmax1, hmin1, part1);
  // L8: BN-S1 reduce + final epilogue w/ transpose
  k_redpost1<<<dim3(256), dim3(256), 0, stream>>>(part1, hmax1, hmin1, gsg1, bsg1, out);
}

// Round 11
// 415.489 us; speedup vs baseline: 6.1406x; 1.1856x over previous
//
#include <hip/hip_runtime.h>
#include <float.h>

#define BATCH 16
#define NPTS  2048
#define NS0   256
#define NS1   128
#define KK    32
#define EPSV  1e-5f
#define MROWS 32768.0f   // BATCH*NPTS

// exact numpy-order squared distance: ((dx*dx + dy*dy) + dz*dz), no FMA contraction
__device__ __forceinline__ float sqdist(float ax,float ay,float az,float bx,float by,float bz){
  float dx=__fsub_rn(ax,bx), dy=__fsub_rn(ay,by), dz=__fsub_rn(az,bz);
  return __fadd_rn(__fadd_rn(__fmul_rn(dx,dx),__fmul_rn(dy,dy)),__fmul_rn(dz,dz));
}

// ---- native f32/u32 DPP ladders (cheap wave64 reduce; winner broadcast via readlane 63)
template<int CTRL,int RM>
__device__ __forceinline__ float dpp_fmax_s(float x){
  int t = __builtin_amdgcn_update_dpp((int)0xFF800000, __float_as_int(x), CTRL, RM, 0xf, false);
  return fmaxf(x, __int_as_float(t));
}
template<int CTRL,int RM>
__device__ __forceinline__ float dpp_fmin_s(float x){
  int t = __builtin_amdgcn_update_dpp(0x7F800000, __float_as_int(x), CTRL, RM, 0xf, false);
  return fminf(x, __int_as_float(t));
}
template<int CTRL,int RM>
__device__ __forceinline__ unsigned dpp_umin_s(unsigned x){
  unsigned t = (unsigned)__builtin_amdgcn_update_dpp(-1, (int)x, CTRL, RM, 0xf, false);
  return t<x ? t : x;
}
// argmax over (v,idx): max value, tie -> lowest idx (matches np.argmax first-occurrence)
__device__ __forceinline__ void wave_argmax_f32(float v, unsigned idx, float& mall, int& sel){
  float m=v;
  m=dpp_fmax_s<0x111,0xf>(m); m=dpp_fmax_s<0x112,0xf>(m); m=dpp_fmax_s<0x114,0xf>(m);
  m=dpp_fmax_s<0x118,0xf>(m); m=dpp_fmax_s<0x142,0xa>(m); m=dpp_fmax_s<0x143,0xc>(m);
  mall = __int_as_float(__builtin_amdgcn_readlane(__float_as_int(m),63));
  unsigned c = (v==mall)? idx : 0xFFFFFFFFu;
  c=dpp_umin_s<0x111,0xf>(c); c=dpp_umin_s<0x112,0xf>(c); c=dpp_umin_s<0x114,0xf>(c);
  c=dpp_umin_s<0x118,0xf>(c); c=dpp_umin_s<0x142,0xa>(c); c=dpp_umin_s<0x143,0xc>(c);
  sel = (int)(unsigned)__builtin_amdgcn_readlane((int)c,63);
}
// argmin over (v,idx): min value, tie -> lowest idx (matches stable top_k)
__device__ __forceinline__ int wave_argmin_f32(float v, unsigned idx){
  float m=v;
  m=dpp_fmin_s<0x111,0xf>(m); m=dpp_fmin_s<0x112,0xf>(m); m=dpp_fmin_s<0x114,0xf>(m);
  m=dpp_fmin_s<0x118,0xf>(m); m=dpp_fmin_s<0x142,0xa>(m); m=dpp_fmin_s<0x143,0xc>(m);
  float mall = __int_as_float(__builtin_amdgcn_readlane(__float_as_int(m),63));
  unsigned c = (v==mall)? idx : 0xFFFFFFFFu;
  c=dpp_umin_s<0x111,0xf>(c); c=dpp_umin_s<0x112,0xf>(c); c=dpp_umin_s<0x114,0xf>(c);
  c=dpp_umin_s<0x118,0xf>(c); c=dpp_umin_s<0x142,0xa>(c); c=dpp_umin_s<0x143,0xc>(c);
  return (int)(unsigned)__builtin_amdgcn_readlane((int)c,63);
}

// ================= device bodies =================

__device__ void embed1_body(int bid, const float* __restrict__ x, const float* __restrict__ w1,
                            float* __restrict__ coords, float* __restrict__ t1){
  __shared__ float w[64*3];
  int tid = threadIdx.x;
  if (tid < 192) w[tid] = w1[tid];
  __syncthreads();
  int gid = bid*256 + tid;
  int b = gid / NPTS, n = gid % NPTS;
  float cx = x[(b*3+0)*NPTS + n];
  float cy = x[(b*3+1)*NPTS + n];
  float cz = x[(b*3+2)*NPTS + n];
  coords[gid*3+0]=cx; coords[gid*3+1]=cy; coords[gid*3+2]=cz;
  float* o = t1 + (size_t)gid*64;
  #pragma unroll
  for(int j=0;j<64;j++) o[j] = cx*w[j*3+0] + cy*w[j*3+1] + cz*w[j*3+2];
}

__device__ void wt_body(int gid, const float* __restrict__ w0, float* __restrict__ wt0,
                        const float* __restrict__ w1, float* __restrict__ wt1){
  if(gid < 128*128){
    int o = gid % 128, c = gid / 128;
    wt0[gid] = w0[o*128 + c];
  } else {
    int g2 = gid - 128*128;
    if(g2 >= 256*256) return;
    int o = g2 % 256, c = g2 / 256;
    wt1[g2] = w1[o*256 + c];
  }
}

// coalesced per-block channel sums + one atomic per channel per block (64 thr)
__device__ void statsA_body(int blk, const float* __restrict__ t,
                            float* __restrict__ accS, float* __restrict__ accQ){
  int c = threadIdx.x;            // channel 0..63
  int r0 = blk*128;
  float s=0.f, q=0.f;
  for(int r=0;r<128;r++){
    float v = t[(size_t)(r0+r)*64 + c];   // wave-load = one contiguous 256B row
    s+=v; q+=v*v;
  }
  atomicAdd(accS+c, s);
  atomicAdd(accQ+c, q);
}

// embed2: BN1 computed inline from atomic sums
__device__ void embed2_body(int bid, const float* __restrict__ t1, const float* __restrict__ w2,
                            const float* __restrict__ accS, const float* __restrict__ accQ,
                            const float* __restrict__ g1, const float* __restrict__ b1,
                            float* __restrict__ t2, char* smem){
  float (*fin)[64] = (float(*)[64])smem;          // 16 KB
  float* sm = (float*)smem + 4096;
  float* sr = sm+64; float* sg = sr+64; float* sb = sg+64;
  int tid = threadIdx.x;
  if (tid<64){
    float S=accS[tid], Q=accQ[tid];
    float m = S/MROWS, v = Q/MROWS - m*m; if(v<0.f) v=0.f;
    sm[tid]=m; sr[tid]=rsqrtf(v+EPSV); sg[tid]=g1[tid]; sb[tid]=b1[tid];
  }
  __syncthreads();
  int base = bid*64;
  for(int i=tid;i<4096;i+=256){
    int p=i>>6, c=i&63;
    float v = t1[(size_t)(base+p)*64 + c];
    v = (v - sm[c])*sr[c]*sg[c] + sb[c];
    fin[p][c] = v>0.f ? v : 0.f;
  }
  __syncthreads();
  int o = tid & 63, p0 = tid>>6;
  float acc[16];
  #pragma unroll
  for(int i=0;i<16;i++) acc[i]=0.f;
  for(int cc=0; cc<64; cc+=4){
    float4 wv = *(const float4*)(w2 + o*64 + cc);
    #pragma unroll
    for(int i=0;i<16;i++){
      float4 f4 = *(const float4*)&fin[p0 + i*4][cc];
      acc[i] += f4.x*wv.x + f4.y*wv.y + f4.z*wv.z + f4.w*wv.w;
    }
  }
  #pragma unroll
  for(int i=0;i<16;i++) t2[(size_t)(base+p0+i*4)*64 + o] = acc[i];
}

// multi-wave FPS v4 (reverted to the round-9-measured 124us structure):
// points staged in LDS; u64 per-wave exchange; centroid via LDS reads.
// Reads x [B][3][P] directly (coalesced staging).
template<int P, int S, int T>
__device__ void fps_body(int b, const float* __restrict__ x, int* __restrict__ outIdx,
                         float* __restrict__ outXyz, char* smem){
  constexpr int PPT = P/T;
  constexpr int NW  = T/64;
  float* sx=(float*)smem; float* sy=sx+P; float* sz=sy+P;
  int* sidx=(int*)(sz+P);
  unsigned long long* rv64=(unsigned long long*)(sidx+S);
  int tid = threadIdx.x;
  const float* xb = x + (size_t)b*3*P;
  float px[PPT], py[PPT], pz[PPT], dist[PPT];
  #pragma unroll
  for(int i=0;i<PPT;i++){
    int n = i*T + tid;
    float X=xb[n], Y=xb[P+n], Z=xb[2*P+n];
    px[i]=X; py[i]=Y; pz[i]=Z; dist[i]=1e10f;
    sx[n]=X; sy[n]=Y; sz[n]=Z;
  }
  __syncthreads();
  int cur = 0;
  float cx=sx[0], cy=sy[0], cz=sz[0];
  for(int s=0;s<S;s++){
    if(tid==0) sidx[s]=cur;
    if(s==S-1) break;
    float bv=-FLT_MAX; int bi=0;
    #pragma unroll
    for(int i=0;i<PPT;i++){
      float d = sqdist(px[i],py[i],pz[i],cx,cy,cz);
      float nd = fminf(dist[i], d);
      dist[i]=nd;
      int n = i*T + tid;                  // ascending per lane => '>' keeps lowest idx
      if(nd>bv){ bv=nd; bi=n; }
    }
    float mall; int sel;
    wave_argmax_f32(bv,(unsigned)bi,mall,sel);
    int sl = s & 1;
    if((tid&63)==0) rv64[sl*NW+(tid>>6)] = ((unsigned long long)__float_as_uint(mall)<<32)|(unsigned)(~sel);
    __syncthreads();
    unsigned long long wk = rv64[sl*NW];
    #pragma unroll
    for(int w=1;w<NW;w++){ unsigned long long t = rv64[sl*NW+w]; if(t>wk) wk=t; }
    cur = (int)(~(unsigned)wk);
    cx=sx[cur]; cy=sy[cur]; cz=sz[cur];
  }
  __syncthreads();
  for(int i=tid; i<S; i+=T){
    int id = sidx[i];
    outIdx[b*S+i] = id;
    outXyz[((size_t)b*S+i)*3+0] = sx[id];
    outXyz[((size_t)b*S+i)*3+1] = sy[id];
    outXyz[((size_t)b*S+i)*3+2] = sz[id];
  }
}

// single-wave FPS; pts [b][P][3]; dyn smem: sx,sy,sz[P], sidx[S]
template<int P, int S>
__device__ void fps_wave_body(int b, const float* __restrict__ pts, int* __restrict__ outIdx,
                              float* __restrict__ outXyz, char* smem){
  constexpr int PPT = P/64;
  float* sx=(float*)smem; float* sy=sx+P; float* sz=sy+P;
  int* sidx=(int*)(sz+P);
  int lane = threadIdx.x;
  const float* p = pts + (size_t)b*P*3;
  float px[PPT], py[PPT], pz[PPT], dist[PPT];
  #pragma unroll
  for(int i=0;i<PPT;i++){
    int n = i*64 + lane;
    float X=p[n*3], Y=p[n*3+1], Z=p[n*3+2];
    px[i]=X; py[i]=Y; pz[i]=Z; dist[i]=1e10f;
    sx[n]=X; sy[n]=Y; sz[n]=Z;
  }
  __syncthreads();
  int cur = 0;
  float cx=sx[0], cy=sy[0], cz=sz[0];
  for(int s=0;s<S;s++){
    if(lane==0) sidx[s]=cur;
    if(s==S-1) break;
    float bv=-FLT_MAX; int bi=0;
    #pragma unroll
    for(int i=0;i<PPT;i++){
      float d = sqdist(px[i],py[i],pz[i],cx,cy,cz);
      float nd = fminf(dist[i], d);
      dist[i]=nd;
      int n = i*64 + lane;
      if(nd>bv){ bv=nd; bi=n; }
    }
    float mall; int sel;
    wave_argmax_f32(bv,(unsigned)bi,mall,sel);
    cur = sel;
    cx=sx[cur]; cy=sy[cur]; cz=sz[cur];
  }
  __syncthreads();
  for(int i=lane; i<S; i+=64){
    int id = sidx[i];
    outIdx[b*S+i] = id;
    outXyz[((size_t)b*S+i)*3+0] = sx[id];
    outXyz[((size_t)b*S+i)*3+1] = sy[id];
    outXyz[((size_t)b*S+i)*3+2] = sz[id];
  }
}

// one wave per query; dyn smem: d2[P]
template<int P>
__device__ void knn_body(int bq, const float* __restrict__ pts, const float* __restrict__ q,
                         int S, int* __restrict__ knn, char* smem){
  float* d2 = (float*)smem;
  constexpr int E = P/64;
  int lane = threadIdx.x;
  int b = bq / S;
  const float* p = pts + (size_t)b*P*3;
  float qx=q[(size_t)bq*3], qy=q[(size_t)bq*3+1], qz=q[(size_t)bq*3+2];
  #pragma unroll
  for(int i=0;i<E;i++){ int n=i*64+lane; d2[n] = sqdist(qx,qy,qz,p[n*3],p[n*3+1],p[n*3+2]); }
  __syncthreads();
  for(int j=0;j<KK;j++){
    float mv=FLT_MAX; unsigned mi=0xFFFFFFFFu;
    #pragma unroll
    for(int i=0;i<E;i++){
      int n=i*64+lane;
      float v=d2[n];
      if(v<mv){ mv=v; mi=(unsigned)n; }
    }
    int sel = wave_argmin_f32(mv, mi);
    if(lane==0){ knn[(size_t)bq*KK+j]=sel; d2[sel]=FLT_MAX; }
    __syncthreads();
  }
}

// register-tiled outer-product GEMM; optional fused BN+ReLU (stats from atomic sums)
template<int C, int P, bool BN>
__device__ void pass1_body(int bq, const float* __restrict__ feats, const int* __restrict__ knn,
                           const int* __restrict__ fpsIdx, const float* __restrict__ WT,
                           float* __restrict__ hmax, float* __restrict__ hmin,
                           float* __restrict__ part, int S,
                           const float* __restrict__ accS, const float* __restrict__ accQ,
                           const float* __restrict__ bg, const float* __restrict__ bb){
  constexpr int O   = 2*C;
  constexpr int TPB = C;
  constexpr int C4  = C/4;
  constexpr int OG  = O/8;
  constexpr int LDC = C+4;
  __shared__ __align__(16) float gfp[KK*LDC];
  __shared__ __align__(16) float cf[C];
  __shared__ __align__(16) float sa[BN?C:1], sbb[BN?C:1];
  __shared__ float sct[O];
  __shared__ float xst[(TPB>64)? 8*O : 1];
  int tid = threadIdx.x;
  int b = bq / S;
  const float* fb = feats + (size_t)b*P*C;
  int ci = fpsIdx[bq];
  const float* cfg = fb + (size_t)ci*C;
  if(BN){
    float S_=accS[tid], Q_=accQ[tid];
    float m = S_/MROWS, vv = Q_/MROWS - m*m; if(vv<0.f) vv=0.f;
    float a = rsqrtf(vv+EPSV)*bg[tid];
    float sh = bb[tid] - m*a;
    sa[tid]=a; sbb[tid]=sh;
    float cv = a*cfg[tid] + sh;
    cf[tid] = cv>0.f ? cv : 0.f;
    __syncthreads();
  } else {
    cf[tid] = cfg[tid];
  }
  for(int i=tid; i<KK*C4; i+=TPB){
    int k = i/C4, d4 = i - k*C4;
    float4 g = ((const float4*)(fb + (size_t)knn[(size_t)bq*KK+k]*C))[d4];
    float4 r;
    if(BN){
      float4 a4 = *(const float4*)&sa[d4*4];
      float4 s4 = *(const float4*)&sbb[d4*4];
      float4 c4 = *(const float4*)&cf[d4*4];
      float gx = a4.x*g.x+s4.x; gx = gx>0.f?gx:0.f;
      float gy = a4.y*g.y+s4.y; gy = gy>0.f?gy:0.f;
      float gz = a4.z*g.z+s4.z; gz = gz>0.f?gz:0.f;
      float gw = a4.w*g.w+s4.w; gw = gw>0.f?gw:0.f;
      r.x=gx-c4.x; r.y=gy-c4.y; r.z=gz-c4.z; r.w=gw-c4.w;
    } else {
      float4 c4 = ((const float4*)cfg)[d4];
      r.x=g.x-c4.x; r.y=g.y-c4.y; r.z=g.z-c4.z; r.w=g.w-c4.w;
    }
    *(float4*)&gfp[k*LDC + d4*4] = r;
  }
  __syncthreads();
  {
    int o2 = tid*2;
    float ct0=0.f, ct1=0.f;
    for(int c=0;c<C;c+=4){
      float4 c4 = *(const float4*)&cf[c];
      #pragma unroll
      for(int t=0;t<4;t++){
        float cv = ((const float*)&c4)[t];
        float2 wh = *(const float2*)&WT[(size_t)(C+c+t)*O + o2];
        ct0 += cv*wh.x; ct1 += cv*wh.y;
      }
    }
    sct[o2]=ct0; sct[o2+1]=ct1;
  }
  __syncthreads();
  int kg = tid / OG;
  int og = tid % OG;
  float acc[8][8];
  #pragma unroll
  for(int a=0;a<8;a++)
    #pragma unroll
    for(int bb2=0;bb2<8;bb2++) acc[a][bb2]=0.f;
  for(int dc=0; dc<C4; dc++){
    float4 g4[8];
    #pragma unroll
    for(int jk=0;jk<8;jk++) g4[jk] = *(const float4*)&gfp[(kg*8+jk)*LDC + dc*4];
    #pragma unroll
    for(int t=0;t<4;t++){
      const float* wrow = WT + (size_t)(dc*4+t)*O + og*8;
      float4 wa = *(const float4*)wrow;
      float4 wb = *(const float4*)(wrow+4);
      #pragma unroll
      for(int jk=0;jk<8;jk++){
        float gs = ((const float*)&g4[jk])[t];
        acc[jk][0] += gs*wa.x; acc[jk][1] += gs*wa.y; acc[jk][2] += gs*wa.z; acc[jk][3] += gs*wa.w;
        acc[jk][4] += gs*wb.x; acc[jk][5] += gs*wb.y; acc[jk][6] += gs*wb.z; acc[jk][7] += gs*wb.w;
      }
    }
  }
  float tmx[8],tmn[8],tsm[8],tsq[8];
  #pragma unroll
  for(int jo=0;jo<8;jo++){
    int o = og*8+jo;
    float ct = sct[o];
    float s=0.f,q=0.f,mx=-FLT_MAX,mn=FLT_MAX;
    #pragma unroll
    for(int jk=0;jk<8;jk++){
      float h = acc[jk][jo] + ct;
      s+=h; q+=h*h; mx=fmaxf(mx,h); mn=fminf(mn,h);
    }
    tmx[jo]=mx; tmn[jo]=mn; tsm[jo]=s; tsq[jo]=q;
  }
  if constexpr (TPB==64){
    #pragma unroll
    for(int jo=0;jo<8;jo++){
      tmx[jo]=fmaxf(tmx[jo],__shfl_xor(tmx[jo],16)); tmx[jo]=fmaxf(tmx[jo],__shfl_xor(tmx[jo],32));
      tmn[jo]=fminf(tmn[jo],__shfl_xor(tmn[jo],16)); tmn[jo]=fminf(tmn[jo],__shfl_xor(tmn[jo],32));
      tsm[jo]+=__shfl_xor(tsm[jo],16); tsm[jo]+=__shfl_xor(tsm[jo],32);
      tsq[jo]+=__shfl_xor(tsq[jo],16); tsq[jo]+=__shfl_xor(tsq[jo],32);
    }
    if(tid<OG){
      #pragma unroll
      for(int jo=0;jo<8;jo++){
        int o = tid*8+jo;
        hmax[(size_t)bq*O+o]=tmx[jo]; hmin[(size_t)bq*O+o]=tmn[jo];
        part[(size_t)bq*2*O+o]=tsm[jo]; part[(size_t)bq*2*O+O+o]=tsq[jo];
      }
    }
  } else {
    #pragma unroll
    for(int jo=0;jo<8;jo++){
      tmx[jo]=fmaxf(tmx[jo],__shfl_xor(tmx[jo],32));
      tmn[jo]=fminf(tmn[jo],__shfl_xor(tmn[jo],32));
      tsm[jo]+=__shfl_xor(tsm[jo],32);
      tsq[jo]+=__shfl_xor(tsq[jo],32);
    }
    int wv = tid>>6;
    if((tid&63)<32){
      int og_ = tid&31;
      #pragma unroll
      for(int jo=0;jo<8;jo++){
        int o = og_*8+jo;
        xst[0*2*O + wv*O + o]=tmx[jo];
        xst[1*2*O + wv*O + o]=tmn[jo];
        xst[2*2*O + wv*O + o]=tsm[jo];
        xst[3*2*O + wv*O + o]=tsq[jo];
      }
    }
    __syncthreads();
    if(tid<32){
      #pragma unroll
      for(int jo=0;jo<8;jo++){
        int o = tid*8+jo;
        hmax[(size_t)bq*O+o]=fmaxf(xst[0*2*O+o], xst[0*2*O+O+o]);
        hmin[(size_t)bq*O+o]=fminf(xst[1*2*O+o], xst[1*2*O+O+o]);
        part[(size_t)bq*2*O+o]   = xst[2*2*O+o] + xst[2*2*O+O+o];
        part[(size_t)bq*2*O+O+o] = xst[3*2*O+o] + xst[3*2*O+O+o];
      }
    }
  }
}

// ================= kernels =================

// L1: embed1 (0..127) || wt (128..447) || zero accums (448)
__global__ __launch_bounds__(256) void k_embed1_wt(const float* __restrict__ x, const float* __restrict__ w1,
                         float* __restrict__ coords, float* __restrict__ t1,
                         const float* __restrict__ wsg0, float* __restrict__ wt0,
                         const float* __restrict__ wsg1, float* __restrict__ wt1,
                         float* __restrict__ accz){
  if(blockIdx.x < 128) embed1_body(blockIdx.x, x, w1, coords, t1);
  else if(blockIdx.x < 448) wt_body((blockIdx.x-128)*256 + threadIdx.x, wsg0, wt0, wsg1, wt1);
  else accz[threadIdx.x] = 0.f;   // acc1S|acc1Q|acc2S|acc2Q = 256 floats contiguous
}

// L2: BN1 stats, coalesced + atomic
__global__ __launch_bounds__(64) void k_statsA(const float* __restrict__ t,
                         float* __restrict__ accS, float* __restrict__ accQ){
  statsA_body(blockIdx.x, t, accS, accQ);
}

// L3: fps0 (16 blocks) || embed2 (512 blocks); dyn smem = 25664 B (union)
__global__ __launch_bounds__(256, 1) void k_fps0_embed2(const float* __restrict__ x,
                         int* __restrict__ fps0, float* __restrict__ xyz0,
                         const float* __restrict__ t1, const float* __restrict__ w2,
                         const float* __restrict__ acc1S, const float* __restrict__ acc1Q,
                         const float* __restrict__ g1, const float* __restrict__ b1,
                         float* __restrict__ t2){
  extern __shared__ char smem[];
  if(blockIdx.x < BATCH) fps_body<NPTS,NS0,256>(blockIdx.x, x, fps0, xyz0, smem);
  else embed2_body(blockIdx.x-BATCH, t1, w2, acc1S, acc1Q, g1, b1, t2, smem);
}

// L4: fps1 (16) || knn0 (4096) || stats2 (256); dyn smem = 8192 B
__global__ __launch_bounds__(64, 4) void k_fps1_knn0_st2(const float* __restrict__ xyz0,
                         int* __restrict__ fps1, float* __restrict__ xyz1,
                         const float* __restrict__ coords, int* __restrict__ knn0,
                         const float* __restrict__ t2,
                         float* __restrict__ acc2S, float* __restrict__ acc2Q){
  extern __shared__ char smem[];
  if(blockIdx.x < BATCH) fps_wave_body<NS0,NS1>(blockIdx.x, xyz0, fps1, xyz1, smem);
  else if(blockIdx.x < BATCH + BATCH*NS0) knn_body<NPTS>(blockIdx.x-BATCH, coords, xyz0, NS0, knn0, smem);
  else statsA_body(blockIdx.x - (BATCH + BATCH*NS0), t2, acc2S, acc2Q);
}

// L5: pass1a w/ fused BN (4096) || knn1 (2048); dyn smem = 1024 B
__global__ __launch_bounds__(64, 2) void k_pass1a_knn1(const float* __restrict__ t2,
                         const int* __restrict__ knn0, const int* __restrict__ fps0,
                         const float* __restrict__ wt0,
                         float* __restrict__ hmax0, float* __restrict__ hmin0, float* __restrict__ part0,
                         const float* __restrict__ acc2S, const float* __restrict__ acc2Q,
                         const float* __restrict__ g2, const float* __restrict__ b2,
                         const float* __restrict__ xyz0, const float* __restrict__ xyz1,
                         int* __restrict__ knn1){
  extern __shared__ char smem[];
  if(blockIdx.x < BATCH*NS0)
    pass1_body<64,NPTS,true>(blockIdx.x, t2, knn0, fps0, wt0, hmax0, hmin0, part0, NS0,
                             acc2S, acc2Q, g2, b2);
  else
    knn_body<NS0>(blockIdx.x-BATCH*NS0, xyz0, xyz1, NS1, knn1, smem);
}

__global__ __launch_bounds__(128, 2) void k_pass1b(const float* __restrict__ f1,
                         const int* __restrict__ knn1, const int* __restrict__ fps1,
                         const float* __restrict__ wt1,
                         float* __restrict__ hmax1, float* __restrict__ hmin1, float* __restrict__ part1){
  pass1_body<128,NS0,false>(blockIdx.x, f1, knn1, fps1, wt1, hmax1, hmin1, part1, NS1,
                            nullptr, nullptr, nullptr, nullptr);
}

// merged reduce+postmax, one block per channel; f1 layout [row][O]
__global__ __launch_bounds__(256) void k_redpost0(const float* __restrict__ part,
        const float* __restrict__ hmax, const float* __restrict__ hmin,
        const float* __restrict__ g, const float* __restrict__ bb, float* __restrict__ f1){
  constexpr int O=128; constexpr int NB=BATCH*NS0;
  int o = blockIdx.x, tid = threadIdx.x;
  float s=0.f, s2=0.f;
  for(int i=tid;i<NB;i+=256){ s += part[(size_t)i*2*O+o]; s2 += part[(size_t)i*2*O+O+o]; }
  __shared__ float bs[256], bq[256];
  __shared__ float s_sc, s_sh;
  bs[tid]=s; bq[tid]=s2; __syncthreads();
  for(int st=128; st>0; st>>=1){ if(tid<st){ bs[tid]+=bs[tid+st]; bq[tid]+=bq[tid+st]; } __syncthreads(); }
  if(tid==0){
    float M = (float)(NB*KK);
    float m = bs[0]/M;
    float v = bq[0]/M - m*m; if(v<0.f) v=0.f;
    float sc = rsqrtf(v+EPSV)*g[o];
    s_sc = sc; s_sh = bb[o] - m*sc;
  }
  __syncthreads();
  float sc=s_sc, sh=s_sh;
  const float* hs = (sc>=0.f) ? hmax : hmin;
  for(int r=tid; r<NB; r+=256){
    float v = hs[(size_t)r*O+o]*sc + sh;
    f1[(size_t)r*O+o] = v>0.f ? v : 0.f;
  }
}

// merged reduce+postmax with transpose: out [B][256][NS1]
__global__ __launch_bounds__(256) void k_redpost1(const float* __restrict__ part,
        const float* __restrict__ hmax, const float* __restrict__ hmin,
        const float* __restrict__ g, const float* __restrict__ bb, float* __restrict__ out){
  constexpr int O=256; constexpr int NB=BATCH*NS1;
  int o = blockIdx.x, tid = threadIdx.x;
  float s=0.f, s2=0.f;
  for(int i=tid;i<NB;i+=256){ s += part[(size_t)i*2*O+o]; s2 += part[(size_t)i*2*O+O+o]; }
  __shared__ float bs[256], bq[256];
  __shared__ float s_sc, s_sh;
  bs[tid]=s; bq[tid]=s2; __syncthreads();
  for(int st=128; st>0; st>>=1){ if(tid<st){ bs[tid]+=bs[tid+st]; bq[tid]+=bq[tid+st]; } __syncthreads(); }
  if(tid==0){
    float M = (float)(NB*KK);
    float m = bs[0]/M;
    float v = bq[0]/M - m*m; if(v<0.f) v=0.f;
    float sc = rsqrtf(v+EPSV)*g[o];
    s_sc = sc; s_sh = bb[o] - m*sc;
  }
  __syncthreads();
  float sc=s_sc, sh=s_sh;
  const float* hs = (sc>=0.f) ? hmax : hmin;
  for(int r=tid; r<NB; r+=256){
    float v = hs[(size_t)r*O+o]*sc + sh;
    v = v>0.f ? v : 0.f;
    int b = r>>7, ss = r&(NS1-1);
    out[(size_t)b*(256*NS1) + o*NS1 + ss] = v;
  }
}

extern "C" void kernel_launch(void* const* d_in, const int* in_sizes, int n_in,
                              void* d_out, int out_size, void* d_ws, size_t ws_size,
                              hipStream_t stream){
  const float* x    = (const float*)d_in[0];
  const float* w1   = (const float*)d_in[1];
  const float* g1   = (const float*)d_in[2];
  const float* b1   = (const float*)d_in[3];
  const float* w2   = (const float*)d_in[4];
  const float* g2   = (const float*)d_in[5];
  const float* b2   = (const float*)d_in[6];
  const float* wsg0 = (const float*)d_in[7];
  const float* gsg0 = (const float*)d_in[8];
  const float* bsg0 = (const float*)d_in[9];
  const float* wsg1 = (const float*)d_in[10];
  const float* gsg1 = (const float*)d_in[11];
  const float* bsg1 = (const float*)d_in[12];
  float* out = (float*)d_out;

  float* wsf = (float*)d_ws;
  float* coords = wsf;                    wsf += BATCH*NPTS*3;
  float* t1     = wsf;                    wsf += BATCH*NPTS*64;
  float* t2     = wsf;                    wsf += BATCH*NPTS*64;   // raw (pre-BN) embed2 output
  float* acc1S=wsf; wsf+=64;  float* acc1Q=wsf; wsf+=64;          // contiguous 256-float accum block
  float* acc2S=wsf; wsf+=64;  float* acc2Q=wsf; wsf+=64;
  int*   fps0 = (int*)wsf;                wsf += BATCH*NS0;
  float* xyz0 = wsf;                      wsf += BATCH*NS0*3;
  int*   knn0 = (int*)wsf;                wsf += BATCH*NS0*KK;
  float* hmax0= wsf;                      wsf += BATCH*NS0*128;
  float* hmin0= wsf;                      wsf += BATCH*NS0*128;
  float* part0= wsf;                      wsf += BATCH*NS0*2*128;
  float* f1   = wsf;                      wsf += BATCH*NS0*128;
  int*   fps1 = (int*)wsf;                wsf += BATCH*NS1;
  float* xyz1 = wsf;                      wsf += BATCH*NS1*3;
  int*   knn1 = (int*)wsf;                wsf += BATCH*NS1*KK;
  float* hmax1= wsf;                      wsf += BATCH*NS1*256;
  float* hmin1= wsf;                      wsf += BATCH*NS1*256;
  float* part1= wsf;                      wsf += BATCH*NS1*2*256;
  float* wt0  = wsf;                      wsf += 128*128;
  float* wt1  = wsf;                      wsf += 256*256;

  const int DYN_L3 = (NPTS*3 + NS0)*4 + 2*4*8;   // fps0: sx/sy/sz + sidx + rv64 = 25664 (>= embed2 17408)
  const int DYN_L4 = NPTS*4;                     // knn0 d2 = 8192 (>= fps1's 3.6KB)
  const int DYN_L5 = NS0*4;                      // knn1 d2 = 1024

  // L1: embed1 || weight transposes || zero stats accumulators
  k_embed1_wt<<<dim3(449), dim3(256), 0, stream>>>(x, w1, coords, t1, wsg0, wt0, wsg1, wt1, acc1S);
  // L2: BN1 stats (coalesced + atomic)
  k_statsA<<<dim3(256), dim3(64), 0, stream>>>(t1, acc1S, acc1Q);
  // L3: fps0 (serial, v4 structure) || embed2 (BN1 from sums, hidden under fps0)
  k_fps0_embed2<<<dim3(BATCH+512), dim3(256), DYN_L3, stream>>>(x, fps0, xyz0,
                                                  t1, w2, acc1S, acc1Q, g1, b1, t2);
  // L4: fps1 || knn0 || BN2 stats
  k_fps1_knn0_st2<<<dim3(BATCH + BATCH*NS0 + 256), dim3(64), DYN_L4, stream>>>(
                                                  xyz0, fps1, xyz1, coords, knn0, t2, acc2S, acc2Q);
  // L5: pass1a (BN2+ReLU fused, stats from sums) || knn1
  k_pass1a_knn1<<<dim3(BATCH*NS0 + BATCH*NS1), dim3(64), DYN_L5, stream>>>(t2, knn0, fps0, wt0,
                                                  hmax0, hmin0, part0,
                                                  acc2S, acc2Q, g2, b2,
                                                  xyz0, xyz1, knn1);
  // L6: BN-S0 reduce + epilogue -> f1
  k_redpost0<<<dim3(128), dim3(256), 0, stream>>>(part0, hmax0, hmin0, gsg0, bsg0, f1);
  // L7: pass1b
  k_pass1b<<<dim3(BATCH*NS1), dim3(128), 0, stream>>>(f1, knn1, fps1, wt1, hmax1, hmin1, part1);
  // L8: BN-S1 reduce + final epilogue w/ transpose
  k_redpost1<<<dim3(256), dim3(256), 0, stream>>>(part1, hmax1, hmin1, gsg1, bsg1, out);
}

// Round 12
// 410.301 us; speedup vs baseline: 6.2182x; 1.0126x over previous
//
#include <hip/hip_runtime.h>
#include <float.h>

#define BATCH 16
#define NPTS  2048
#define NS0   256
#define NS1   128
#define KK    32
#define EPSV  1e-5f
#define MROWS 32768.0f   // BATCH*NPTS

// exact numpy-order squared distance: ((dx*dx + dy*dy) + dz*dz), no FMA contraction
__device__ __forceinline__ float sqdist(float ax,float ay,float az,float bx,float by,float bz){
  float dx=__fsub_rn(ax,bx), dy=__fsub_rn(ay,by), dz=__fsub_rn(az,bz);
  return __fadd_rn(__fadd_rn(__fmul_rn(dx,dx),__fmul_rn(dy,dy)),__fmul_rn(dz,dz));
}

// ---- native f32/u32 DPP ladders (cheap wave64 reduce; winner broadcast via readlane 63)
template<int CTRL,int RM>
__device__ __forceinline__ float dpp_fmax_s(float x){
  int t = __builtin_amdgcn_update_dpp((int)0xFF800000, __float_as_int(x), CTRL, RM, 0xf, false);
  return fmaxf(x, __int_as_float(t));
}
template<int CTRL,int RM>
__device__ __forceinline__ float dpp_fmin_s(float x){
  int t = __builtin_amdgcn_update_dpp(0x7F800000, __float_as_int(x), CTRL, RM, 0xf, false);
  return fminf(x, __int_as_float(t));
}
template<int CTRL,int RM>
__device__ __forceinline__ unsigned dpp_umin_s(unsigned x){
  unsigned t = (unsigned)__builtin_amdgcn_update_dpp(-1, (int)x, CTRL, RM, 0xf, false);
  return t<x ? t : x;
}
// argmax over (v,idx): max value, tie -> lowest idx (matches np.argmax first-occurrence)
__device__ __forceinline__ void wave_argmax_f32(float v, unsigned idx, float& mall, int& sel){
  float m=v;
  m=dpp_fmax_s<0x111,0xf>(m); m=dpp_fmax_s<0x112,0xf>(m); m=dpp_fmax_s<0x114,0xf>(m);
  m=dpp_fmax_s<0x118,0xf>(m); m=dpp_fmax_s<0x142,0xa>(m); m=dpp_fmax_s<0x143,0xc>(m);
  mall = __int_as_float(__builtin_amdgcn_readlane(__float_as_int(m),63));
  unsigned c = (v==mall)? idx : 0xFFFFFFFFu;
  c=dpp_umin_s<0x111,0xf>(c); c=dpp_umin_s<0x112,0xf>(c); c=dpp_umin_s<0x114,0xf>(c);
  c=dpp_umin_s<0x118,0xf>(c); c=dpp_umin_s<0x142,0xa>(c); c=dpp_umin_s<0x143,0xc>(c);
  sel = (int)(unsigned)__builtin_amdgcn_readlane((int)c,63);
}
// argmin over (v,idx): min value, tie -> lowest idx (matches stable top_k)
__device__ __forceinline__ int wave_argmin_f32(float v, unsigned idx){
  float m=v;
  m=dpp_fmin_s<0x111,0xf>(m); m=dpp_fmin_s<0x112,0xf>(m); m=dpp_fmin_s<0x114,0xf>(m);
  m=dpp_fmin_s<0x118,0xf>(m); m=dpp_fmin_s<0x142,0xa>(m); m=dpp_fmin_s<0x143,0xc>(m);
  float mall = __int_as_float(__builtin_amdgcn_readlane(__float_as_int(m),63));
  unsigned c = (v==mall)? idx : 0xFFFFFFFFu;
  c=dpp_umin_s<0x111,0xf>(c); c=dpp_umin_s<0x112,0xf>(c); c=dpp_umin_s<0x114,0xf>(c);
  c=dpp_umin_s<0x118,0xf>(c); c=dpp_umin_s<0x142,0xa>(c); c=dpp_umin_s<0x143,0xc>(c);
  return (int)(unsigned)__builtin_amdgcn_readlane((int)c,63);
}

// ================= device bodies =================

// embed1 v2: 64 points per block, LDS-staged so t1 writes are fully coalesced.
__device__ void embed1_body(int bid, const float* __restrict__ x, const float* __restrict__ w1,
                            float* __restrict__ coords, float* __restrict__ t1){
  __shared__ float w[192];
  __shared__ float xs[3][64];
  __shared__ float fin[64][65];          // +1 pad: banks spread for fin[p][c] writes
  int tid = threadIdx.x;
  if (tid < 192) w[tid] = w1[tid];
  int base = bid*64;
  int b = base / NPTS, n0 = base % NPTS;
  if (tid < 192){
    int ch = tid>>6, i = tid&63;
    xs[ch][i] = x[((size_t)b*3+ch)*NPTS + n0 + i];
  }
  __syncthreads();
  if (tid < 64){
    coords[(size_t)(base+tid)*3+0]=xs[0][tid];
    coords[(size_t)(base+tid)*3+1]=xs[1][tid];
    coords[(size_t)(base+tid)*3+2]=xs[2][tid];
  }
  int p = tid>>2, c0 = (tid&3)<<4;
  float cx=xs[0][p], cy=xs[1][p], cz=xs[2][p];
  #pragma unroll
  for(int j=0;j<16;j++){
    int c = c0+j;
    fin[p][c] = cx*w[c*3+0] + cy*w[c*3+1] + cz*w[c*3+2];
  }
  __syncthreads();
  for(int i=tid;i<4096;i+=256){
    int pp=i>>6, c=i&63;
    t1[(size_t)base*64 + i] = fin[pp][c];     // coalesced 1KB wave-stores
  }
}

__device__ void wt_body(int gid, const float* __restrict__ w0, float* __restrict__ wt0,
                        const float* __restrict__ w1, float* __restrict__ wt1){
  if(gid < 128*128){
    int o = gid % 128, c = gid / 128;
    wt0[gid] = w0[o*128 + c];
  } else {
    int g2 = gid - 128*128;
    if(g2 >= 256*256) return;
    int o = g2 % 256, c = g2 / 256;
    wt1[g2] = w1[o*256 + c];
  }
}

// coalesced per-block channel sums + one atomic per channel per block (64 thr)
__device__ void statsA_body(int blk, const float* __restrict__ t,
                            float* __restrict__ accS, float* __restrict__ accQ){
  int c = threadIdx.x;            // channel 0..63
  int r0 = blk*128;
  float s=0.f, q=0.f;
  for(int r=0;r<128;r++){
    float v = t[(size_t)(r0+r)*64 + c];   // wave-load = one contiguous 256B row
    s+=v; q+=v*v;
  }
  atomicAdd(accS+c, s);
  atomicAdd(accQ+c, q);
}

// embed2: BN1 computed inline from atomic sums (unchanged; measured-good)
__device__ void embed2_body(int bid, const float* __restrict__ t1, const float* __restrict__ w2,
                            const float* __restrict__ accS, const float* __restrict__ accQ,
                            const float* __restrict__ g1, const float* __restrict__ b1,
                            float* __restrict__ t2, char* smem){
  float (*fin)[64] = (float(*)[64])smem;          // 16 KB
  float* sm = (float*)smem + 4096;
  float* sr = sm+64; float* sg = sr+64; float* sb = sg+64;
  int tid = threadIdx.x;
  if (tid<64){
    float S=accS[tid], Q=accQ[tid];
    float m = S/MROWS, v = Q/MROWS - m*m; if(v<0.f) v=0.f;
    sm[tid]=m; sr[tid]=rsqrtf(v+EPSV); sg[tid]=g1[tid]; sb[tid]=b1[tid];
  }
  __syncthreads();
  int base = bid*64;
  for(int i=tid;i<4096;i+=256){
    int p=i>>6, c=i&63;
    float v = t1[(size_t)(base+p)*64 + c];
    v = (v - sm[c])*sr[c]*sg[c] + sb[c];
    fin[p][c] = v>0.f ? v : 0.f;
  }
  __syncthreads();
  int o = tid & 63, p0 = tid>>6;
  float acc[16];
  #pragma unroll
  for(int i=0;i<16;i++) acc[i]=0.f;
  for(int cc=0; cc<64; cc+=4){
    float4 wv = *(const float4*)(w2 + o*64 + cc);
    #pragma unroll
    for(int i=0;i<16;i++){
      float4 f4 = *(const float4*)&fin[p0 + i*4][cc];
      acc[i] += f4.x*wv.x + f4.y*wv.y + f4.z*wv.z + f4.w*wv.w;
    }
  }
  #pragma unroll
  for(int i=0;i<16;i++) t2[(size_t)(base+p0+i*4)*64 + o] = acc[i];
}

// multi-wave FPS v4 (FROZEN: round-11-measured 124us). Do not restructure.
template<int P, int S, int T>
__device__ void fps_body(int b, const float* __restrict__ x, int* __restrict__ outIdx,
                         float* __restrict__ outXyz, char* smem){
  constexpr int PPT = P/T;
  constexpr int NW  = T/64;
  float* sx=(float*)smem; float* sy=sx+P; float* sz=sy+P;
  int* sidx=(int*)(sz+P);
  unsigned long long* rv64=(unsigned long long*)(sidx+S);
  int tid = threadIdx.x;
  const float* xb = x + (size_t)b*3*P;
  float px[PPT], py[PPT], pz[PPT], dist[PPT];
  #pragma unroll
  for(int i=0;i<PPT;i++){
    int n = i*T + tid;
    float X=xb[n], Y=xb[P+n], Z=xb[2*P+n];
    px[i]=X; py[i]=Y; pz[i]=Z; dist[i]=1e10f;
    sx[n]=X; sy[n]=Y; sz[n]=Z;
  }
  __syncthreads();
  int cur = 0;
  float cx=sx[0], cy=sy[0], cz=sz[0];
  for(int s=0;s<S;s++){
    if(tid==0) sidx[s]=cur;
    if(s==S-1) break;
    float bv=-FLT_MAX; int bi=0;
    #pragma unroll
    for(int i=0;i<PPT;i++){
      float d = sqdist(px[i],py[i],pz[i],cx,cy,cz);
      float nd = fminf(dist[i], d);
      dist[i]=nd;
      int n = i*T + tid;                  // ascending per lane => '>' keeps lowest idx
      if(nd>bv){ bv=nd; bi=n; }
    }
    float mall; int sel;
    wave_argmax_f32(bv,(unsigned)bi,mall,sel);
    int sl = s & 1;
    if((tid&63)==0) rv64[sl*NW+(tid>>6)] = ((unsigned long long)__float_as_uint(mall)<<32)|(unsigned)(~sel);
    __syncthreads();
    unsigned long long wk = rv64[sl*NW];
    #pragma unroll
    for(int w=1;w<NW;w++){ unsigned long long t = rv64[sl*NW+w]; if(t>wk) wk=t; }
    cur = (int)(~(unsigned)wk);
    cx=sx[cur]; cy=sy[cur]; cz=sz[cur];
  }
  __syncthreads();
  for(int i=tid; i<S; i+=T){
    int id = sidx[i];
    outIdx[b*S+i] = id;
    outXyz[((size_t)b*S+i)*3+0] = sx[id];
    outXyz[((size_t)b*S+i)*3+1] = sy[id];
    outXyz[((size_t)b*S+i)*3+2] = sz[id];
  }
}

// single-wave FPS; float4-packed LDS point store (one ds_read_b128 for centroid)
template<int P, int S>
__device__ void fps_wave_body(int b, const float* __restrict__ pts, int* __restrict__ outIdx,
                              float* __restrict__ outXyz, char* smem){
  constexpr int PPT = P/64;
  float4* sp = (float4*)smem;
  int* sidx = (int*)(smem + P*sizeof(float4));
  int lane = threadIdx.x;
  const float* p = pts + (size_t)b*P*3;
  float px[PPT], py[PPT], pz[PPT], dist[PPT];
  #pragma unroll
  for(int i=0;i<PPT;i++){
    int n = i*64 + lane;
    float X=p[n*3], Y=p[n*3+1], Z=p[n*3+2];
    px[i]=X; py[i]=Y; pz[i]=Z; dist[i]=1e10f;
    sp[n] = make_float4(X,Y,Z,0.f);
  }
  __syncthreads();
  int cur = 0;
  float cx=sp[0].x, cy=sp[0].y, cz=sp[0].z;
  for(int s=0;s<S;s++){
    if(lane==0) sidx[s]=cur;
    if(s==S-1) break;
    float bv=-FLT_MAX; int bi=0;
    #pragma unroll
    for(int i=0;i<PPT;i++){
      float d = sqdist(px[i],py[i],pz[i],cx,cy,cz);
      float nd = fminf(dist[i], d);
      dist[i]=nd;
      int n = i*64 + lane;
      if(nd>bv){ bv=nd; bi=n; }
    }
    float mall; int sel;
    wave_argmax_f32(bv,(unsigned)bi,mall,sel);
    cur = sel;
    float4 cp = sp[cur];
    cx=cp.x; cy=cp.y; cz=cp.z;
  }
  __syncthreads();
  for(int i=lane; i<S; i+=64){
    int id = sidx[i];
    float4 cp = sp[id];
    outIdx[b*S+i] = id;
    outXyz[((size_t)b*S+i)*3+0] = cp.x;
    outXyz[((size_t)b*S+i)*3+1] = cp.y;
    outXyz[((size_t)b*S+i)*3+2] = cp.z;
  }
}

// KNN tournament: d2 register-resident, incremental per-lane (mv,mi); only the owner
// lane rescans after a removal. No LDS, no barriers. Selection semantics identical.
template<int P>
__device__ void knn_body(int bq, const float* __restrict__ pts, const float* __restrict__ q,
                         int S, int* __restrict__ knn){
  constexpr int E = P/64;
  int lane = threadIdx.x;
  int b = bq / S;
  const float* p = pts + (size_t)b*P*3;
  float qx=q[(size_t)bq*3], qy=q[(size_t)bq*3+1], qz=q[(size_t)bq*3+2];
  float dl[E];
  float mv = FLT_MAX; unsigned mi = 0xFFFFFFFFu;
  #pragma unroll
  for(int i=0;i<E;i++){
    int n = i*64 + lane;
    float v = sqdist(qx,qy,qz,p[n*3],p[n*3+1],p[n*3+2]);
    dl[i] = v;
    if(v<mv){ mv=v; mi=(unsigned)n; }       // ascending n => lowest idx on lane-local tie
  }
  for(int j=0;j<KK;j++){
    int sel = wave_argmin_f32(mv, mi);
    if(lane==0) knn[(size_t)bq*KK+j] = sel;
    if((sel & 63) == lane){                 // owner removes + rescans its slots
      int slot = sel >> 6;                  // wave-uniform SGPR
      #pragma unroll
      for(int i=0;i<E;i++) if(i==slot) dl[i]=FLT_MAX;
      mv = FLT_MAX; mi = 0xFFFFFFFFu;
      #pragma unroll
      for(int i=0;i<E;i++){
        int n=i*64+lane;
        if(dl[i]<mv){ mv=dl[i]; mi=(unsigned)n; }
      }
    }
  }
}

// register-tiled outer-product GEMM; optional fused BN+ReLU (stats from atomic sums).
// TPB==128 (pass1b): per-wave stats written to DOUBLED rows (bq*2+wave); no xst LDS.
template<int C, int P, bool BN>
__device__ void pass1_body(int bq, const float* __restrict__ feats, const int* __restrict__ knn,
                           const int* __restrict__ fpsIdx, const float* __restrict__ WT,
                           float* __restrict__ hmax, float* __restrict__ hmin,
                           float* __restrict__ part, int S,
                           const float* __restrict__ accS, const float* __restrict__ accQ,
                           const float* __restrict__ bg, const float* __restrict__ bb){
  constexpr int O   = 2*C;
  constexpr int TPB = C;
  constexpr int C4  = C/4;
  constexpr int OG  = O/8;
  constexpr int LDC = C+4;
  __shared__ __align__(16) float gfp[KK*LDC];
  __shared__ __align__(16) float cf[C];
  __shared__ __align__(16) float sa[BN?C:1], sbb[BN?C:1];
  __shared__ float sct[O];
  int tid = threadIdx.x;
  int b = bq / S;
  const float* fb = feats + (size_t)b*P*C;
  int ci = fpsIdx[bq];
  const float* cfg = fb + (size_t)ci*C;
  if(BN){
    float S_=accS[tid], Q_=accQ[tid];
    float m = S_/MROWS, vv = Q_/MROWS - m*m; if(vv<0.f) vv=0.f;
    float a = rsqrtf(vv+EPSV)*bg[tid];
    float sh = bb[tid] - m*a;
    sa[tid]=a; sbb[tid]=sh;
    float cv = a*cfg[tid] + sh;
    cf[tid] = cv>0.f ? cv : 0.f;
    __syncthreads();
  } else {
    cf[tid] = cfg[tid];
  }
  for(int i=tid; i<KK*C4; i+=TPB){
    int k = i/C4, d4 = i - k*C4;
    float4 g = ((const float4*)(fb + (size_t)knn[(size_t)bq*KK+k]*C))[d4];
    float4 r;
    if(BN){
      float4 a4 = *(const float4*)&sa[d4*4];
      float4 s4 = *(const float4*)&sbb[d4*4];
      float4 c4 = *(const float4*)&cf[d4*4];
      float gx = a4.x*g.x+s4.x; gx = gx>0.f?gx:0.f;
      float gy = a4.y*g.y+s4.y; gy = gy>0.f?gy:0.f;
      float gz = a4.z*g.z+s4.z; gz = gz>0.f?gz:0.f;
      float gw = a4.w*g.w+s4.w; gw = gw>0.f?gw:0.f;
      r.x=gx-c4.x; r.y=gy-c4.y; r.z=gz-c4.z; r.w=gw-c4.w;
    } else {
      float4 c4 = ((const float4*)cfg)[d4];
      r.x=g.x-c4.x; r.y=g.y-c4.y; r.z=g.z-c4.z; r.w=g.w-c4.w;
    }
    *(float4*)&gfp[k*LDC + d4*4] = r;
  }
  __syncthreads();
  {
    int o2 = tid*2;
    float ct0=0.f, ct1=0.f;
    for(int c=0;c<C;c+=4){
      float4 c4 = *(const float4*)&cf[c];
      #pragma unroll
      for(int t=0;t<4;t++){
        float cv = ((const float*)&c4)[t];
        float2 wh = *(const float2*)&WT[(size_t)(C+c+t)*O + o2];
        ct0 += cv*wh.x; ct1 += cv*wh.y;
      }
    }
    sct[o2]=ct0; sct[o2+1]=ct1;
  }
  __syncthreads();
  int kg = tid / OG;
  int og = tid % OG;
  float acc[8][8];
  #pragma unroll
  for(int a=0;a<8;a++)
    #pragma unroll
    for(int bb2=0;bb2<8;bb2++) acc[a][bb2]=0.f;
  for(int dc=0; dc<C4; dc++){
    float4 g4[8];
    #pragma unroll
    for(int jk=0;jk<8;jk++) g4[jk] = *(const float4*)&gfp[(kg*8+jk)*LDC + dc*4];
    #pragma unroll
    for(int t=0;t<4;t++){
      const float* wrow = WT + (size_t)(dc*4+t)*O + og*8;
      float4 wa = *(const float4*)wrow;
      float4 wb = *(const float4*)(wrow+4);
      #pragma unroll
      for(int jk=0;jk<8;jk++){
        float gs = ((const float*)&g4[jk])[t];
        acc[jk][0] += gs*wa.x; acc[jk][1] += gs*wa.y; acc[jk][2] += gs*wa.z; acc[jk][3] += gs*wa.w;
        acc[jk][4] += gs*wb.x; acc[jk][5] += gs*wb.y; acc[jk][6] += gs*wb.z; acc[jk][7] += gs*wb.w;
      }
    }
  }
  float tmx[8],tmn[8],tsm[8],tsq[8];
  #pragma unroll
  for(int jo=0;jo<8;jo++){
    int o = og*8+jo;
    float ct = sct[o];
    float s=0.f,q=0.f,mx=-FLT_MAX,mn=FLT_MAX;
    #pragma unroll
    for(int jk=0;jk<8;jk++){
      float h = acc[jk][jo] + ct;
      s+=h; q+=h*h; mx=fmaxf(mx,h); mn=fminf(mn,h);
    }
    tmx[jo]=mx; tmn[jo]=mn; tsm[jo]=s; tsq[jo]=q;
  }
  if constexpr (TPB==64){
    #pragma unroll
    for(int jo=0;jo<8;jo++){
      tmx[jo]=fmaxf(tmx[jo],__shfl_xor(tmx[jo],16)); tmx[jo]=fmaxf(tmx[jo],__shfl_xor(tmx[jo],32));
      tmn[jo]=fminf(tmn[jo],__shfl_xor(tmn[jo],16)); tmn[jo]=fminf(tmn[jo],__shfl_xor(tmn[jo],32));
      tsm[jo]+=__shfl_xor(tsm[jo],16); tsm[jo]+=__shfl_xor(tsm[jo],32);
      tsq[jo]+=__shfl_xor(tsq[jo],16); tsq[jo]+=__shfl_xor(tsq[jo],32);
    }
    if(tid<OG){
      #pragma unroll
      for(int jo=0;jo<8;jo++){
        int o = tid*8+jo;
        hmax[(size_t)bq*O+o]=tmx[jo]; hmin[(size_t)bq*O+o]=tmn[jo];
        part[(size_t)bq*2*O+o]=tsm[jo]; part[(size_t)bq*2*O+O+o]=tsq[jo];
      }
    }
  } else {
    #pragma unroll
    for(int jo=0;jo<8;jo++){
      tmx[jo]=fmaxf(tmx[jo],__shfl_xor(tmx[jo],32));
      tmn[jo]=fminf(tmn[jo],__shfl_xor(tmn[jo],32));
      tsm[jo]+=__shfl_xor(tsm[jo],32);
      tsq[jo]+=__shfl_xor(tsq[jo],32);
    }
    int wv = tid>>6;
    if((tid&63)<32){
      int og_ = tid&31;
      size_t rb = (size_t)bq*2 + wv;        // doubled row per wave; combined downstream
      #pragma unroll
      for(int jo=0;jo<8;jo++){
        int o = og_*8+jo;
        hmax[rb*O+o]=tmx[jo]; hmin[rb*O+o]=tmn[jo];
        part[rb*2*O+o]=tsm[jo]; part[rb*2*O+O+o]=tsq[jo];
      }
    }
  }
}

// ================= kernels =================

// L1: embed1 (0..511) || wt (512..831) || zero accums (832)
__global__ __launch_bounds__(256) void k_embed1_wt(const float* __restrict__ x, const float* __restrict__ w1,
                         float* __restrict__ coords, float* __restrict__ t1,
                         const float* __restrict__ wsg0, float* __restrict__ wt0,
                         const float* __restrict__ wsg1, float* __restrict__ wt1,
                         float* __restrict__ accz){
  if(blockIdx.x < 512) embed1_body(blockIdx.x, x, w1, coords, t1);
  else if(blockIdx.x < 832) wt_body((blockIdx.x-512)*256 + threadIdx.x, wsg0, wt0, wsg1, wt1);
  else {
    int tid = threadIdx.x;
    accz[tid]=0.f; accz[tid+256]=0.f; accz[tid+512]=0.f; accz[tid+768]=0.f;  // 1024 accum floats
  }
}

// L2: BN1 stats, coalesced + atomic
__global__ __launch_bounds__(64) void k_statsA(const float* __restrict__ t,
                         float* __restrict__ accS, float* __restrict__ accQ){
  statsA_body(blockIdx.x, t, accS, accQ);
}

// L3: fps0 (16 blocks) || embed2 (512 blocks); dyn smem = 25664 B (union)
__global__ __launch_bounds__(256, 1) void k_fps0_embed2(const float* __restrict__ x,
                         int* __restrict__ fps0, float* __restrict__ xyz0,
                         const float* __restrict__ t1, const float* __restrict__ w2,
                         const float* __restrict__ acc1S, const float* __restrict__ acc1Q,
                         const float* __restrict__ g1, const float* __restrict__ b1,
                         float* __restrict__ t2){
  extern __shared__ char smem[];
  if(blockIdx.x < BATCH) fps_body<NPTS,NS0,256>(blockIdx.x, x, fps0, xyz0, smem);
  else embed2_body(blockIdx.x-BATCH, t1, w2, acc1S, acc1Q, g1, b1, t2, smem);
}

// L4: fps1 (16) || knn0 (4096, no LDS) || stats2 (256); dyn smem = 4608 B (fps1 only)
__global__ __launch_bounds__(64, 4) void k_fps1_knn0_st2(const float* __restrict__ xyz0,
                         int* __restrict__ fps1, float* __restrict__ xyz1,
                         const float* __restrict__ coords, int* __restrict__ knn0,
                         const float* __restrict__ t2,
                         float* __restrict__ acc2S, float* __restrict__ acc2Q){
  extern __shared__ char smem[];
  if(blockIdx.x < BATCH) fps_wave_body<NS0,NS1>(blockIdx.x, xyz0, fps1, xyz1, smem);
  else if(blockIdx.x < BATCH + BATCH*NS0) knn_body<NPTS>(blockIdx.x-BATCH, coords, xyz0, NS0, knn0);
  else statsA_body(blockIdx.x - (BATCH + BATCH*NS0), t2, acc2S, acc2Q);
}

// L5: pass1a w/ fused BN (4096) || knn1 (2048, no LDS)
__global__ __launch_bounds__(64, 2) void k_pass1a_knn1(const float* __restrict__ t2,
                         const int* __restrict__ knn0, const int* __restrict__ fps0,
                         const float* __restrict__ wt0,
                         float* __restrict__ hmax0, float* __restrict__ hmin0, float* __restrict__ part0,
                         const float* __restrict__ acc2S, const float* __restrict__ acc2Q,
                         const float* __restrict__ g2, const float* __restrict__ b2,
                         const float* __restrict__ xyz0, const float* __restrict__ xyz1,
                         int* __restrict__ knn1){
  if(blockIdx.x < BATCH*NS0)
    pass1_body<64,NPTS,true>(blockIdx.x, t2, knn0, fps0, wt0, hmax0, hmin0, part0, NS0,
                             acc2S, acc2Q, g2, b2);
  else
    knn_body<NS0>(blockIdx.x-BATCH*NS0, xyz0, xyz1, NS1, knn1);
}

__global__ __launch_bounds__(128, 2) void k_pass1b(const float* __restrict__ f1,
                         const int* __restrict__ knn1, const int* __restrict__ fps1,
                         const float* __restrict__ wt1,
                         float* __restrict__ hmax1, float* __restrict__ hmin1, float* __restrict__ part1){
  pass1_body<128,NS0,false>(blockIdx.x, f1, knn1, fps1, wt1, hmax1, hmin1, part1, NS1,
                            nullptr, nullptr, nullptr, nullptr);
}

// row-coalesced partial-sum reduce: block = 64 rows; thread = column(s); one atomic per column
__global__ __launch_bounds__(256) void k_statsB(const float* __restrict__ part, int W,
                                                float* __restrict__ acc){
  int tid = threadIdx.x;
  int r0 = blockIdx.x*64;
  for(int c=tid; c<W; c+=256){
    float a=0.f;
    for(int r=0;r<64;r++) a += part[(size_t)(r0+r)*W + c];   // coalesced rows
    atomicAdd(acc+c, a);
  }
}

// row-coalesced postmax for stage 0: f1[idx] = relu(h*sc+sh), idx row-major
__global__ __launch_bounds__(256) void k_postmax0(const float* __restrict__ hmax, const float* __restrict__ hmin,
        const float* __restrict__ aS, const float* __restrict__ aQ,
        const float* __restrict__ g, const float* __restrict__ bb, float* __restrict__ f1){
  __shared__ float ssc[128], ssh[128];
  int tid = threadIdx.x;
  if(tid<128){
    float M = (float)(BATCH*NS0*KK);
    float m = aS[tid]/M, v = aQ[tid]/M - m*m; if(v<0.f) v=0.f;
    float sc = rsqrtf(v+EPSV)*g[tid];
    ssc[tid]=sc; ssh[tid]=bb[tid]-m*sc;
  }
  __syncthreads();
  int idx = blockIdx.x*256 + tid;            // grid 2048 covers BATCH*NS0*128
  int o = idx & 127;
  float sc=ssc[o];
  float h = (sc>=0.f) ? hmax[idx] : hmin[idx];
  float v = h*sc + ssh[o];
  f1[idx] = v>0.f ? v : 0.f;
}

// stage-1 postmax + transpose via LDS tile; combines the doubled stat rows.
// block = (batch, 64-channel chunk): 16*4 = 64 blocks
__global__ __launch_bounds__(256) void k_post1tr(const float* __restrict__ hmax, const float* __restrict__ hmin,
        const float* __restrict__ aS, const float* __restrict__ aQ,
        const float* __restrict__ g, const float* __restrict__ bb, float* __restrict__ out){
  __shared__ float ssc[64], ssh[64];
  __shared__ float tile[64][129];
  int tid = threadIdx.x;
  int blk = blockIdx.x; int b = blk>>2; int c0 = (blk&3)*64;
  if(tid<64){
    int o = c0+tid;
    float M = (float)(BATCH*NS1*KK);
    float m = aS[o]/M, v = aQ[o]/M - m*m; if(v<0.f) v=0.f;
    float sc = rsqrtf(v+EPSV)*g[o];
    ssc[tid]=sc; ssh[tid]=bb[o]-m*sc;
  }
  __syncthreads();
  for(int i=tid; i<128*64; i+=256){
    int r=i>>6, ch=i&63;
    size_t rb = (size_t)(b*NS1+r)*2;
    float sc = ssc[ch];
    float va = hmax[rb*256 + c0+ch], vb = hmax[(rb+1)*256 + c0+ch];
    float wa = hmin[rb*256 + c0+ch], wb = hmin[(rb+1)*256 + c0+ch];
    float h = (sc>=0.f) ? fmaxf(va,vb) : fminf(wa,wb);
    float v = h*sc + ssh[ch];
    tile[ch][r] = v>0.f ? v : 0.f;
  }
  __syncthreads();
  for(int i=tid; i<64*128; i+=256){
    int ch=i>>7, s=i&127;
    out[(size_t)b*(256*NS1) + (size_t)(c0+ch)*NS1 + s] = tile[ch][s];
  }
}

extern "C" void kernel_launch(void* const* d_in, const int* in_sizes, int n_in,
                              void* d_out, int out_size, void* d_ws, size_t ws_size,
                              hipStream_t stream){
  const float* x    = (const float*)d_in[0];
  const float* w1   = (const float*)d_in[1];
  const float* g1   = (const float*)d_in[2];
  const float* b1   = (const float*)d_in[3];
  const float* w2   = (const float*)d_in[4];
  const float* g2   = (const float*)d_in[5];
  const float* b2   = (const float*)d_in[6];
  const float* wsg0 = (const float*)d_in[7];
  const float* gsg0 = (const float*)d_in[8];
  const float* bsg0 = (const float*)d_in[9];
  const float* wsg1 = (const float*)d_in[10];
  const float* gsg1 = (const float*)d_in[11];
  const float* bsg1 = (const float*)d_in[12];
  float* out = (float*)d_out;

  float* wsf = (float*)d_ws;
  float* coords = wsf;                    wsf += BATCH*NPTS*3;
  float* t1     = wsf;                    wsf += BATCH*NPTS*64;   // ALIASED: part1 after L3
  float* t2     = wsf;                    wsf += BATCH*NPTS*64;   // ALIASED: hmax1|hmin1 after L5
  float* acc1S=wsf; wsf+=64;  float* acc1Q=wsf; wsf+=64;          // contiguous 1024-float accum block
  float* acc2S=wsf; wsf+=64;  float* acc2Q=wsf; wsf+=64;
  float* accB0=wsf; wsf+=256;                                      // [S x128][Q x128]
  float* accB1=wsf; wsf+=512;                                      // [S x256][Q x256]
  int*   fps0 = (int*)wsf;                wsf += BATCH*NS0;
  float* xyz0 = wsf;                      wsf += BATCH*NS0*3;
  int*   knn0 = (int*)wsf;                wsf += BATCH*NS0*KK;
  float* hmax0= wsf;                      wsf += BATCH*NS0*128;
  float* hmin0= wsf;                      wsf += BATCH*NS0*128;
  float* part0= wsf;                      wsf += BATCH*NS0*2*128;
  float* f1   = wsf;                      wsf += BATCH*NS0*128;
  int*   fps1 = (int*)wsf;                wsf += BATCH*NS1;
  float* xyz1 = wsf;                      wsf += BATCH*NS1*3;
  int*   knn1 = (int*)wsf;                wsf += BATCH*NS1*KK;
  float* wt0  = wsf;                      wsf += 128*128;
  float* wt1  = wsf;                      wsf += 256*256;
  // aliases (lifetimes verified: t1 dead after L3; t2 dead after L5)
  float* part1 = t1;                      // NB*2 rows x 512 = 2,097,152 floats == |t1|
  float* hmax1 = t2;                      // NB*2 x 256 = 1,048,576
  float* hmin1 = t2 + BATCH*NS1*2*256;    // second half of t2

  const int DYN_L3 = (NPTS*3 + NS0)*4 + 2*4*8;     // fps0 union (>= embed2 17408)
  const int DYN_L4 = NS0*16 + NS1*4;               // fps1 float4 sp + sidx = 4608

  // L1: embed1 (coalesced) || weight transposes || zero stats accumulators
  k_embed1_wt<<<dim3(833), dim3(256), 0, stream>>>(x, w1, coords, t1, wsg0, wt0, wsg1, wt1, acc1S);
  // L2: BN1 stats
  k_statsA<<<dim3(256), dim3(64), 0, stream>>>(t1, acc1S, acc1Q);
  // L3: fps0 (FROZEN v4) || embed2
  k_fps0_embed2<<<dim3(BATCH+512), dim3(256), DYN_L3, stream>>>(x, fps0, xyz0,
                                                  t1, w2, acc1S, acc1Q, g1, b1, t2);
  // L4: fps1 || knn0 (tournament) || BN2 stats
  k_fps1_knn0_st2<<<dim3(BATCH + BATCH*NS0 + 256), dim3(64), DYN_L4, stream>>>(
                                                  xyz0, fps1, xyz1, coords, knn0, t2, acc2S, acc2Q);
  // L5: pass1a (BN fused) || knn1 (tournament)
  k_pass1a_knn1<<<dim3(BATCH*NS0 + BATCH*NS1), dim3(64), 0, stream>>>(t2, knn0, fps0, wt0,
                                                  hmax0, hmin0, part0,
                                                  acc2S, acc2Q, g2, b2,
                                                  xyz0, xyz1, knn1);
  // L6: row-coalesced reduce of part0 -> accB0
  k_statsB<<<dim3(64), dim3(256), 0, stream>>>(part0, 256, accB0);
  // L7: row-coalesced postmax -> f1
  k_postmax0<<<dim3(2048), dim3(256), 0, stream>>>(hmax0, hmin0, accB0, accB0+128, gsg0, bsg0, f1);
  // L8: pass1b (split-stat doubled rows)
  k_pass1b<<<dim3(BATCH*NS1), dim3(128), 0, stream>>>(f1, knn1, fps1, wt1, hmax1, hmin1, part1);
  // L9: row-coalesced reduce of part1 -> accB1
  k_statsB<<<dim3(64), dim3(256), 0, stream>>>(part1, 512, accB1);
  // L10: postmax + transpose -> out
  k_post1tr<<<dim3(64), dim3(256), 0, stream>>>(hmax1, hmin1, accB1, accB1+256, gsg1, bsg1, out);
}